// Round 14
// baseline (1959.612 us; speedup 1.0000x reference)
//
#include <hip/hip_runtime.h>
#include <stdint.h>
#include <float.h>

// ---------------------------------------------------------------------------
// Net_57604101374728: GCN(x3)+BN -> maxpool | 6x belief-prop -> diffpool ->
// dense GCN(x3)+BN -> maxpool -> FC. Full fp32 port of the JAX reference.
//
// R14: last-block completion fusion: k_colsum_field computes field (same
// ascending-chunk tree -> bit-exact) + stage-1 bnw in its final block
// (removes 10 k_field launches); k_y2 runs bnw in its final block (removes
// 3 k_bnw launches). BP compute kernels byte-identical to R13.
// ---------------------------------------------------------------------------

constexpr int NN    = 65536;    // total nodes
constexpr int NEDGE = 524288;   // edges
constexpr int NBG   = 64;       // graphs

__constant__ int cQS[6]   = {2,4,8,16,32,64};

// ---------------- threefry2x32 (20 rounds) ----------------
__device__ __forceinline__ void tf2x32(uint32_t k0, uint32_t k1, uint32_t x0, uint32_t x1,
                                       uint32_t& o0, uint32_t& o1){
  uint32_t ks[3] = {k0, k1, k0 ^ k1 ^ 0x1BD11BDAu};
  x0 += ks[0]; x1 += ks[1];
  const int RA[4] = {13,15,26,6}, RB[4] = {17,29,16,24};
  #pragma unroll
  for (int i=0;i<5;i++){
    const int* r = (i&1)? RB : RA;
    #pragma unroll
    for (int j=0;j<4;j++){
      x0 += x1;
      x1 = (x1 << r[j]) | (x1 >> (32 - r[j]));
      x1 ^= x0;
    }
    x0 += ks[(i+1)%3];
    x1 += ks[(i+2)%3] + (uint32_t)(i+1);
  }
  o0 = x0; o1 = x1;
}

// ---------------- XLA ErfInv32 (Giles), contraction off ----------------
__device__ __forceinline__ float erfinv32(float xx){
  #pragma clang fp contract(off)
  float w = -log1pf(-xx*xx);
  float p;
  if (w < 5.0f){
    w = w - 2.5f;
    p = 2.81022636e-08f;
    p = 3.43273939e-07f  + p*w;
    p = -3.5233877e-06f  + p*w;
    p = -4.39150654e-06f + p*w;
    p = 0.00021858087f   + p*w;
    p = -0.00125372503f  + p*w;
    p = -0.00417768164f  + p*w;
    p = 0.246640727f     + p*w;
    p = 1.50140941f      + p*w;
  } else {
    w = sqrtf(w) - 3.0f;
    p = -0.000200214257f;
    p = 0.000100950558f  + p*w;
    p = 0.00134934322f   + p*w;
    p = -0.00367342844f  + p*w;
    p = 0.00573950773f   + p*w;
    p = -0.0076224613f   + p*w;
    p = 0.00943887047f   + p*w;
    p = 1.00167406f      + p*w;
    p = 2.83297682f      + p*w;
  }
  return p*xx;
}

// ---------------- CSR construction (fused pairs via blockIdx.y) ----------
__global__ __launch_bounds__(256) void k_count(const int* __restrict__ src, const int* __restrict__ dst,
                                               int* __restrict__ degi, int* __restrict__ dego){
  int e = blockIdx.x*256 + threadIdx.x;
  if (e >= NEDGE) return;
  atomicAdd(&degi[dst[e]], 1);
  atomicAdd(&dego[src[e]], 1);
}

__global__ __launch_bounds__(256) void k_scan1(const int* __restrict__ degi, const int* __restrict__ dego,
                                               int* __restrict__ rpi, int* __restrict__ rpo,
                                               int* __restrict__ bsum){
  __shared__ int lds[256];
  const int* deg = blockIdx.y? dego : degi;
  int* rp = blockIdx.y? rpo : rpi;
  int* bs = bsum + blockIdx.y*256;
  int b = blockIdx.x, t = threadIdx.x;
  lds[t] = deg[b*256 + t];
  __syncthreads();
  for (int s=1;s<256;s<<=1){
    int add = (t>=s)? lds[t-s] : 0;
    __syncthreads();
    lds[t] += add;
    __syncthreads();
  }
  rp[b*256 + t + 1] = lds[t];
  if (t==0 && b==0) rp[0] = 0;
  if (t==255) bs[b] = lds[255];
}

__global__ __launch_bounds__(256) void k_scan2(int* __restrict__ bsum){
  __shared__ int lds[256];
  int* bs = bsum + blockIdx.x*256;
  int t = threadIdx.x;
  lds[t] = bs[t];
  __syncthreads();
  for (int s=1;s<256;s<<=1){
    int add = (t>=s)? lds[t-s] : 0;
    __syncthreads();
    lds[t] += add;
    __syncthreads();
  }
  bs[t] = (t==0)? 0 : lds[t-1];
}

__global__ __launch_bounds__(256) void k_scan3(int* __restrict__ rpi, int* __restrict__ rpo,
                                               const int* __restrict__ bsum){
  int* rp = blockIdx.y? rpo : rpi;
  const int* bs = bsum + blockIdx.y*256;
  int b = blockIdx.x, t = threadIdx.x;
  rp[b*256 + t + 1] += bs[b];
}

__global__ __launch_bounds__(256) void k_fill(const int* __restrict__ src, const int* __restrict__ dst,
                                              const int* __restrict__ rpi, const int* __restrict__ rpo,
                                              int* __restrict__ cntA, int* __restrict__ cntB,
                                              int* __restrict__ colI, int* __restrict__ colO){
  int e = blockIdx.x*256 + threadIdx.x;
  if (e >= NEDGE) return;
  if (blockIdx.y == 0){
    int d = dst[e];
    int p = atomicAdd(&cntA[d], 1);
    colI[rpi[d] + p] = e;
  } else {
    int d = src[e];
    int p = atomicAdd(&cntB[d], 1);
    colO[rpo[d] + p] = e;
  }
}

__global__ __launch_bounds__(256) void k_sortrow(const int* __restrict__ rpi, const int* __restrict__ rpo,
                                                 int* __restrict__ colI, int* __restrict__ colO,
                                                 const int* __restrict__ src, const int* __restrict__ dst,
                                                 const int* __restrict__ degi, float* __restrict__ dinv){
  const int* rp = blockIdx.y? rpo : rpi;
  int* colbuf   = blockIdx.y? colO : colI;
  const int* other = blockIdx.y? dst : src;
  int v = blockIdx.x*256 + threadIdx.x;
  if (v >= NN) return;
  int s0 = rp[v], s1 = rp[v+1];
  for (int i=s0+1;i<s1;i++){
    int key = colbuf[i]; int j = i-1;
    while (j>=s0 && colbuf[j]>key){ colbuf[j+1]=colbuf[j]; j--; }
    colbuf[j+1] = key;
  }
  for (int i=s0;i<s1;i++) colbuf[i] = other[colbuf[i]];
  if (blockIdx.y == 0) dinv[v] = 1.0f / sqrtf((float)(degi[v] + 1));
}

// ---------------- GEMM helpers ----------------
template<int CIN>
__global__ __launch_bounds__(256) void k_mm30(const float* __restrict__ x, const float* __restrict__ w,
                                              float* __restrict__ h, int nrow){
  __shared__ float ws[CIN*30];
  int t = threadIdx.x;
  for (int i=t;i<CIN*30;i+=256) ws[i] = w[i];
  __syncthreads();
  int id = blockIdx.x*256 + t;
  if (id >= nrow*30) return;
  int v = id/30, j = id - v*30;
  const float* xr = x + v*CIN;
  float acc = 0.f;
  #pragma unroll
  for (int k=0;k<CIN;k++) acc += xr[k]*ws[k*30+j];
  h[id] = acc;
}

__global__ __launch_bounds__(256) void k_mm30c(const float* __restrict__ x, const float* __restrict__ wfold,
                                               const float* __restrict__ cvec, float* __restrict__ h, int nrow){
  __shared__ float ws[900];
  __shared__ float cl[30];
  int t = threadIdx.x;
  for (int i=t;i<900;i+=256) ws[i] = wfold[i];
  if (t < 30) cl[t] = cvec[t];
  __syncthreads();
  int id = blockIdx.x*256 + t;
  if (id >= nrow*30) return;
  int v = id/30, j = id - v*30;
  const float* xr = x + v*30;
  float acc = cl[j];
  #pragma unroll
  for (int k=0;k<30;k++) acc += xr[k]*ws[k*30+j];
  h[id] = acc;
}

// ---------------- belief propagation (col-vectorized, XCD-resident) -------
__device__ __forceinline__ void bp_decode2(int b, int& graph, int& run, int& jj){
  int xcd = b & 7, i = b >> 3;
  int gs = i >> 7, j = i & 127;
  if      (j <   4){ run=0; jj=j;    }
  else if (j <   8){ run=1; jj=j-4;  }
  else if (j <  16){ run=2; jj=j-8;  }
  else if (j <  32){ run=3; jj=j-16; }
  else if (j <  64){ run=4; jj=j-32; }
  else             { run=5; jj=j-64; }
  graph = gs*8 + xcd;
}

template<int TPR>
__device__ __forceinline__ void bfly_max4(float& m0, float& m1, float& m2, float& m3){
  if constexpr (TPR > 1){
    #pragma unroll
    for (int lm = TPR>>1; lm; lm >>= 1){
      float p0=__shfl_xor(m0,lm,64), p1=__shfl_xor(m1,lm,64);
      float p2=__shfl_xor(m2,lm,64), p3=__shfl_xor(m3,lm,64);
      m0=fmaxf(m0,p0); m1=fmaxf(m1,p1); m2=fmaxf(m2,p2); m3=fmaxf(m3,p3);
    }
  }
  { float t0=fmaxf(m0,m2), t1=fmaxf(m1,m3), t2=fmaxf(m2,m0), t3=fmaxf(m3,m1);
    m0=t0; m1=t1; m2=t2; m3=t3; }
  { float t0=fmaxf(m0,m1), t1=fmaxf(m1,m0), t2=fmaxf(m2,m3), t3=fmaxf(m3,m2);
    m0=t0; m1=t1; m2=t2; m3=t3; }
}

template<int TPR>
__device__ __forceinline__ void bfly_sum4(float& s0, float& s1, float& s2, float& s3){
  if constexpr (TPR > 1){
    #pragma unroll
    for (int lm = TPR>>1; lm; lm >>= 1){
      float p0=__shfl_xor(s0,lm,64), p1=__shfl_xor(s1,lm,64);
      float p2=__shfl_xor(s2,lm,64), p3=__shfl_xor(s3,lm,64);
      s0 += p0; s1 += p1; s2 += p2; s3 += p3;
    }
  }
  { float t0=s0+s2, t1=s1+s3, t2=s2+s0, t3=s3+s1;
    s0=t0; s1=t1; s2=t2; s3=t3; }
  { float t0=s0+s1, t1=s1+s0, t2=s2+s3, t3=s3+s2;
    s0=t0; s1=t1; s2=t2; s3=t3; }
}

template<int Q, int CO, int TPR, int L2T>
__device__ __forceinline__ void bp_first_elem2(int graph, int jj, float* __restrict__ psi_pk,
                                               float* __restrict__ lg, float eb,
                                               uint32_t k0, uint32_t k1){
  int idx = jj*256 + (int)threadIdx.x;
  if constexpr (Q == 2){
    int row = graph*1024 + idx;
    float z[2];
    #pragma unroll
    for (int r=0;r<2;r++){
      uint32_t b0,b1;
      tf2x32(k0,k1, 0u, (uint32_t)(row*2 + r), b0,b1);
      uint32_t bits = b0 ^ b1;
      float f = __uint_as_float((bits>>9) | 0x3F800000u) - 1.0f;
      const float lo = __uint_as_float(0xBF7FFFFFu);
      float u = fmaxf(lo, f*2.0f + lo);
      z[r] = __uint_as_float(0x3FB504F3u) * erfinv32(u);
    }
    float m0=fmaxf(z[0],z[1]), m1=fmaxf(z[1],z[0]);
    float e0=expf(z[0]-m0), e1=expf(z[1]-m1);
    float s0=e0+e1, s1=e1+e0;
    float p0=e0/s0, p1=e1/s1;
    ((float2*)(psi_pk + (size_t)NN*CO))[row] = make_float2(p0,p1);
    ((float2*)(lg     + (size_t)NN*CO))[row] = make_float2(log1pf(eb*p0), log1pf(eb*p1));
  } else {
    int rw = idx >> L2T, ct = idx & (TPR-1);
    int row = graph*1024 + rw;
    float z[4];
    #pragma unroll
    for (int r=0;r<4;r++){
      uint32_t b0,b1;
      tf2x32(k0,k1, 0u, (uint32_t)(row*Q + 4*ct + r), b0,b1);
      uint32_t bits = b0 ^ b1;
      float f = __uint_as_float((bits>>9) | 0x3F800000u) - 1.0f;
      const float lo = __uint_as_float(0xBF7FFFFFu);
      float u = fmaxf(lo, f*2.0f + lo);
      z[r] = __uint_as_float(0x3FB504F3u) * erfinv32(u);
    }
    float m0=z[0],m1=z[1],m2=z[2],m3=z[3];
    bfly_max4<TPR>(m0,m1,m2,m3);
    float e0=expf(z[0]-m0), e1=expf(z[1]-m1), e2=expf(z[2]-m2), e3=expf(z[3]-m3);
    float s0=e0,s1=e1,s2=e2,s3=e3;
    bfly_sum4<TPR>(s0,s1,s2,s3);
    float p0=e0/s0, p1=e1/s1, p2=e2/s2, p3=e3/s3;
    ((float4*)(psi_pk + (size_t)NN*CO))[(size_t)row*TPR + ct] = make_float4(p0,p1,p2,p3);
    ((float4*)(lg     + (size_t)NN*CO))[(size_t)row*TPR + ct] =
        make_float4(log1pf(eb*p0), log1pf(eb*p1), log1pf(eb*p2), log1pf(eb*p3));
  }
}

// bp_first + aux mm30<3> (blocks >= 8192)
__global__ __launch_bounds__(256) void k_bp_first(float* __restrict__ psi_pk, float* __restrict__ lg,
                                                  const float* __restrict__ betas,
                                                  const float* __restrict__ xin,
                                                  const float* __restrict__ w11,
                                                  float* __restrict__ hbuf){
  if (blockIdx.x >= 8192){
    __shared__ float ws[90];
    int t = threadIdx.x;
    for (int i=t;i<90;i+=256) ws[i] = w11[i];
    __syncthreads();
    int id = ((int)blockIdx.x - 8192)*256 + t;
    if (id >= NN*30) return;
    int v = id/30, j = id - v*30;
    const float* xr = xin + v*3;
    float acc = 0.f;
    #pragma unroll
    for (int k=0;k<3;k++) acc += xr[k]*ws[k*30+j];
    hbuf[id] = acc;
    return;
  }
  int graph, run, jj;
  bp_decode2(blockIdx.x, graph, run, jj);
  uint32_t k0, k1;
  tf2x32(0u, 42u, 0u, (uint32_t)run, k0, k1);
  float eb = expm1f(betas[run]);
  switch(run){
    case 0: bp_first_elem2< 2, 0, 1,0>(graph, jj, psi_pk, lg, eb, k0, k1); break;
    case 1: bp_first_elem2< 4, 2, 1,0>(graph, jj, psi_pk, lg, eb, k0, k1); break;
    case 2: bp_first_elem2< 8, 6, 2,1>(graph, jj, psi_pk, lg, eb, k0, k1); break;
    case 3: bp_first_elem2<16,14, 4,2>(graph, jj, psi_pk, lg, eb, k0, k1); break;
    case 4: bp_first_elem2<32,30, 8,3>(graph, jj, psi_pk, lg, eb, k0, k1); break;
    default:bp_first_elem2<64,62,16,4>(graph, jj, psi_pk, lg, eb, k0, k1); break;
  }
}

template<int Q, int CO, int TPR, int L2T>
__device__ __forceinline__ void bp_step_elem2(int graph, int run, int jj,
    const float* __restrict__ lcur, float* __restrict__ nxt, float* __restrict__ lnxt,
    const int* __restrict__ rp, const int* __restrict__ col,
    const float* __restrict__ field, float eb, int fin){
  int idx = jj*256 + (int)threadIdx.x;
  if constexpr (Q == 2){
    int row = graph*1024 + idx;
    const float2* B2 = (const float2*)(lcur + (size_t)NN*CO);
    float a0=0.f, a1=0.f;
    int a = rp[row], b2 = rp[row+1];
    for (; a+8<=b2; a+=8){
      int s0=col[a],s1=col[a+1],s2=col[a+2],s3=col[a+3];
      int s4=col[a+4],s5=col[a+5],s6=col[a+6],s7=col[a+7];
      float2 u0=B2[s0], u1=B2[s1], u2=B2[s2], u3=B2[s3];
      float2 u4=B2[s4], u5=B2[s5], u6=B2[s6], u7=B2[s7];
      a0+=u0.x; a1+=u0.y; a0+=u1.x; a1+=u1.y;
      a0+=u2.x; a1+=u2.y; a0+=u3.x; a1+=u3.y;
      a0+=u4.x; a1+=u4.y; a0+=u5.x; a1+=u5.y;
      a0+=u6.x; a1+=u6.y; a0+=u7.x; a1+=u7.y;
    }
    for (; a+4<=b2; a+=4){
      int s0=col[a],s1=col[a+1],s2=col[a+2],s3=col[a+3];
      float2 u0=B2[s0], u1=B2[s1], u2=B2[s2], u3=B2[s3];
      a0+=u0.x; a1+=u0.y; a0+=u1.x; a1+=u1.y;
      a0+=u2.x; a1+=u2.y; a0+=u3.x; a1+=u3.y;
    }
    for (; a<b2; ++a){ float2 u=B2[col[a]]; a0+=u.x; a1+=u.y; }
    float v0 = a0 - field[run*64 + 0];
    float v1 = a1 - field[run*64 + 1];
    float m0=fmaxf(v0,v1), m1=fmaxf(v1,v0);
    float e0=expf(v0-m0), e1=expf(v1-m1);
    float s0=e0+e1, s1=e1+e0;
    float p0=e0/s0, p1=e1/s1;
    if (fin){
      float* o = nxt + (size_t)row*126 + CO;
      o[0]=p0; o[1]=p1;
    } else {
      ((float2*)(nxt  + (size_t)NN*CO))[row] = make_float2(p0,p1);
      ((float2*)(lnxt + (size_t)NN*CO))[row] = make_float2(log1pf(eb*p0), log1pf(eb*p1));
    }
  } else {
    int rw = idx >> L2T, ct = idx & (TPR-1);
    int row = graph*1024 + rw;
    const float4* B4 = (const float4*)(lcur + (size_t)NN*CO);
    float a0=0.f,a1=0.f,a2=0.f,a3=0.f;
    int a = rp[row], b2 = rp[row+1];
    for (; a+8<=b2; a+=8){
      int s0=col[a],s1=col[a+1],s2=col[a+2],s3=col[a+3];
      int s4=col[a+4],s5=col[a+5],s6=col[a+6],s7=col[a+7];
      float4 u0=B4[(size_t)s0*TPR+ct], u1=B4[(size_t)s1*TPR+ct];
      float4 u2=B4[(size_t)s2*TPR+ct], u3=B4[(size_t)s3*TPR+ct];
      float4 u4=B4[(size_t)s4*TPR+ct], u5=B4[(size_t)s5*TPR+ct];
      float4 u6=B4[(size_t)s6*TPR+ct], u7=B4[(size_t)s7*TPR+ct];
      a0+=u0.x; a1+=u0.y; a2+=u0.z; a3+=u0.w;
      a0+=u1.x; a1+=u1.y; a2+=u1.z; a3+=u1.w;
      a0+=u2.x; a1+=u2.y; a2+=u2.z; a3+=u2.w;
      a0+=u3.x; a1+=u3.y; a2+=u3.z; a3+=u3.w;
      a0+=u4.x; a1+=u4.y; a2+=u4.z; a3+=u4.w;
      a0+=u5.x; a1+=u5.y; a2+=u5.z; a3+=u5.w;
      a0+=u6.x; a1+=u6.y; a2+=u6.z; a3+=u6.w;
      a0+=u7.x; a1+=u7.y; a2+=u7.z; a3+=u7.w;
    }
    for (; a+4<=b2; a+=4){
      int s0=col[a],s1=col[a+1],s2=col[a+2],s3=col[a+3];
      float4 u0=B4[(size_t)s0*TPR+ct], u1=B4[(size_t)s1*TPR+ct];
      float4 u2=B4[(size_t)s2*TPR+ct], u3=B4[(size_t)s3*TPR+ct];
      a0+=u0.x; a1+=u0.y; a2+=u0.z; a3+=u0.w;
      a0+=u1.x; a1+=u1.y; a2+=u1.z; a3+=u1.w;
      a0+=u2.x; a1+=u2.y; a2+=u2.z; a3+=u2.w;
      a0+=u3.x; a1+=u3.y; a2+=u3.z; a3+=u3.w;
    }
    for (; a<b2; ++a){
      float4 u = B4[(size_t)col[a]*TPR+ct];
      a0+=u.x; a1+=u.y; a2+=u.z; a3+=u.w;
    }
    const float4 fld = *(const float4*)(field + run*64 + 4*ct);
    float v0 = a0 - fld.x, v1 = a1 - fld.y, v2 = a2 - fld.z, v3 = a3 - fld.w;
    float m0=v0,m1=v1,m2=v2,m3=v3;
    bfly_max4<TPR>(m0,m1,m2,m3);
    float e0=expf(v0-m0), e1=expf(v1-m1), e2=expf(v2-m2), e3=expf(v3-m3);
    float s0=e0,s1=e1,s2=e2,s3=e3;
    bfly_sum4<TPR>(s0,s1,s2,s3);
    float p0=e0/s0, p1=e1/s1, p2=e2/s2, p3=e3/s3;
    if (fin){
      float* o = nxt + (size_t)row*126 + CO + 4*ct;
      o[0]=p0; o[1]=p1; o[2]=p2; o[3]=p3;
    } else {
      ((float4*)(nxt  + (size_t)NN*CO))[(size_t)row*TPR+ct] = make_float4(p0,p1,p2,p3);
      ((float4*)(lnxt + (size_t)NN*CO))[(size_t)row*TPR+ct] =
          make_float4(log1pf(eb*p0), log1pf(eb*p1), log1pf(eb*p2), log1pf(eb*p3));
    }
  }
}

// bp_step + aux blocks (>= 8192): 1=gcn_agg, 2=mm30c, 3=pool(stage-1)
__global__ __launch_bounds__(256) void k_bp_step(
    float* __restrict__ nxt, const float* __restrict__ lcur, float* __restrict__ lnxt,
    const int* __restrict__ rp, const int* __restrict__ col,
    const float* __restrict__ field, const float* __restrict__ betas, int fin,
    int auxType, const float* __restrict__ aA, const float* __restrict__ aB,
    const float* __restrict__ aC, float* __restrict__ aO,
    float* __restrict__ agS, float* __restrict__ agQ,
    const float* __restrict__ adinv, const float* __restrict__ asfc,
    float* __restrict__ aconv){
  if (blockIdx.x >= 8192){
    __shared__ float smem[960];
    int ab = (int)blockIdx.x - 8192;
    int t = threadIdx.x;
    if (auxType == 1){
      float* binS = smem; float* binQ = smem + 32;
      if (t < 30){ binS[t]=0.f; binQ[t]=0.f; }
      __syncthreads();
      int xcd = ab & 7, i = ab >> 3;
      int gs = i/60, j = i - gs*60;
      int graph = gs*8 + xcd;
      int idwg = j*256 + t;
      int rw = idwg/15, pr = idwg - rw*15;
      int v = graph*1024 + rw;
      float dv = adinv[v];
      float accx = 0.f, accy = 0.f;
      int a = rp[v], e = rp[v+1];
      for (; a+4<=e; a+=4){
        int s0=col[a], s1=col[a+1], s2=col[a+2], s3=col[a+3];
        float d0=adinv[s0], d1=adinv[s1], d2=adinv[s2], d3=adinv[s3];
        float2 h0=*(const float2*)(aA+s0*30+2*pr), h1=*(const float2*)(aA+s1*30+2*pr);
        float2 h2=*(const float2*)(aA+s2*30+2*pr), h3=*(const float2*)(aA+s3*30+2*pr);
        accx += h0.x*(d0*dv); accy += h0.y*(d0*dv);
        accx += h1.x*(d1*dv); accy += h1.y*(d1*dv);
        accx += h2.x*(d2*dv); accy += h2.y*(d2*dv);
        accx += h3.x*(d3*dv); accy += h3.y*(d3*dv);
      }
      for (; a<e; ++a){
        int s = col[a];
        float w = adinv[s]*dv;
        float2 hv = *(const float2*)(aA+s*30+2*pr);
        accx += hv.x*w; accy += hv.y*w;
      }
      float2 hs = *(const float2*)(aA + v*30 + 2*pr);
      float w2 = dv*dv;
      accx += hs.x*w2; accy += hs.y*w2;   // self loop last (JAX concat order)
      float2 o; o.x = accx + aB[2*pr]; o.y = accy + aB[2*pr+1];
      *(float2*)(aO + v*30 + 2*pr) = o;
      atomicAdd(&binS[2*pr],   o.x); atomicAdd(&binQ[2*pr],   o.x*o.x);
      atomicAdd(&binS[2*pr+1], o.y); atomicAdd(&binQ[2*pr+1], o.y*o.y);
      __syncthreads();
      if (t < 30){
        int slot = (ab & 63)*30 + t;
        atomicAdd(&agS[slot], binS[t]);
        atomicAdd(&agQ[slot], binQ[t]);
      }
    } else if (auxType == 2){
      float* ws = smem; float* cl = smem + 904;
      for (int i=t;i<900;i+=256) ws[i] = aB[i];
      if (t < 30) cl[t] = aC[t];
      __syncthreads();
      int id = ab*256 + t;
      if (id < NN*30){
        int v = id/30, j = id - v*30;
        const float* xr = aA + v*30;
        float acc = cl[j];
        #pragma unroll
        for (int k=0;k<30;k++) acc += xr[k]*ws[k*30+j];
        aO[id] = acc;
      }
    } else if (auxType == 3){
      int b2 = ab & 63, a = ab >> 6;
      const float* X = (a==0)? aA : ((a==1)? aB : aC);
      const float* sf = asfc + a*64;
      float acc[30];
      #pragma unroll
      for (int f=0;f<30;f++) acc[f] = -FLT_MAX;
      for (int r=t; r<1024; r+=256){
        const float* xr = X + (size_t)(b2*1024 + r)*30;
        #pragma unroll
        for (int f=0;f<30;f++) acc[f] = fmaxf(acc[f], sf[f]*xr[f] + sf[32+f]);
      }
      #pragma unroll
      for (int off=32; off; off>>=1){
        #pragma unroll
        for (int f=0;f<30;f++) acc[f] = fmaxf(acc[f], __shfl_xor(acc[f], off, 64));
      }
      int w = t>>6, lane = t&63;
      if (lane == 0){
        #pragma unroll
        for (int f=0;f<30;f++) smem[w*30+f] = acc[f];
      }
      __syncthreads();
      if (t < 30)
        aconv[b2*180 + a*30 + t] =
          fmaxf(fmaxf(smem[t], smem[30+t]), fmaxf(smem[60+t], smem[90+t]));
    }
    return;
  }
  int graph, run, jj;
  bp_decode2(blockIdx.x, graph, run, jj);
  float eb = expm1f(betas[run]);
  switch(run){
    case 0: bp_step_elem2< 2, 0, 1,0>(graph, run, jj, lcur, nxt, lnxt, rp, col, field, eb, fin); break;
    case 1: bp_step_elem2< 4, 2, 1,0>(graph, run, jj, lcur, nxt, lnxt, rp, col, field, eb, fin); break;
    case 2: bp_step_elem2< 8, 6, 2,1>(graph, run, jj, lcur, nxt, lnxt, rp, col, field, eb, fin); break;
    case 3: bp_step_elem2<16,14, 4,2>(graph, run, jj, lcur, nxt, lnxt, rp, col, field, eb, fin); break;
    case 4: bp_step_elem2<32,30, 8,3>(graph, run, jj, lcur, nxt, lnxt, rp, col, field, eb, fin); break;
    default:bp_step_elem2<64,62,16,4>(graph, run, jj, lcur, nxt, lnxt, rp, col, field, eb, fin); break;
  }
}

// colsum + fused field (last-block, same ascending-chunk tree -> bit-exact)
// + optional stage-1 bnw fold in the last block.
__global__ __launch_bounds__(64) void k_colsum_field(const float* __restrict__ psi_pk,
    float* __restrict__ part, const float* __restrict__ betas, float* __restrict__ field,
    int* __restrict__ sync,
    int auxFold, float* __restrict__ gS, float* __restrict__ gQ, float n,
    const float* __restrict__ g, const float* __restrict__ be,
    const float* __restrict__ wnext, float* __restrict__ sfc,
    float* __restrict__ wfold, float* __restrict__ cvec){
  int b = blockIdx.x;
  int xcd = b & 7, i = b >> 3;
  int gs = i/24, rem = i - gs*24;
  int run = rem >> 2, cg = rem & 3;
  int graph = gs*8 + xcd;
  int chunk = graph*4 + cg;
  int q = cQS[run];
  int co = (run==0)?0:(run==1)?2:(run==2)?6:(run==3)?14:(run==4)?30:62;
  int c = threadIdx.x;
  if (q >= 4){
    int nq = q >> 2;
    if (c < nq){
      const float4* p4 = (const float4*)(psi_pk + (size_t)NN*co + (size_t)chunk*256*q) + c;
      float s0=0.f,s1=0.f,s2=0.f,s3=0.f;
      #pragma unroll 8
      for (int r=0;r<256;r++){
        float4 u = p4[(size_t)r*nq];
        s0+=u.x; s1+=u.y; s2+=u.z; s3+=u.w;
      }
      float* o = part + (run*256 + chunk)*64 + 4*c;
      o[0]=s0; o[1]=s1; o[2]=s2; o[3]=s3;
    }
  } else {
    if (c < q){
      float s = 0.f;
      const float* p = psi_pk + (size_t)NN*co + (size_t)chunk*256*q + c;
      #pragma unroll 8
      for (int r=0;r<256;r++) s += p[r*q];
      part[(run*256 + chunk)*64 + c] = s;
    }
  }
  // last-block completion: compute field (+ optional bnw)
  __shared__ int lastFlag;
  __threadfence();
  __syncthreads();
  if (threadIdx.x == 0){
    int done = atomicAdd(sync, 1);
    lastFlag = (done == 1535);
  }
  __syncthreads();
  if (!lastFlag) return;
  __threadfence();
  for (int id = threadIdx.x; id < 384; id += 64){
    int rr = id >> 6, cc = id & 63;
    if (cc < cQS[rr]){
      float s = 0.f;
      for (int bb=0;bb<256;bb++) s += part[(rr*256 + bb)*64 + cc];
      field[id] = s * (3.8f*betas[rr]/65536.0f);
    }
  }
  if (auxFold >= 0){
    __shared__ float s_l[30], c_l[30];
    if (threadIdx.x < 30){
      int t = threadIdx.x;
      float s=0.f, qq=0.f;
      for (int u=0;u<64;u++){ s += gS[u*30+t]; qq += gQ[u*30+t]; }
      float m = s/n;
      float var = qq/n - m*m;
      float sc = g[t]*(1.0f/sqrtf(var+1e-5f));
      float c0 = be[t] - sc*m;
      s_l[t]=sc; c_l[t]=c0;
      sfc[t]=sc; sfc[32+t]=c0;
      for (int u=0;u<64;u++){ gS[u*30+t]=0.f; gQ[u*30+t]=0.f; }
    }
    __syncthreads();
    if (auxFold == 1){
      for (int i2=threadIdx.x;i2<900;i2+=64) wfold[i2] = s_l[i2/30]*wnext[i2];
      if (threadIdx.x < 30){
        int t = threadIdx.x;
        float cacc=0.f;
        for (int k=0;k<30;k++) cacc += c_l[k]*wnext[k*30+t];
        cvec[t]=cacc;
      }
    }
  }
  if (threadIdx.x == 0) atomicExch(sync, 0);
}

// ---------------- diff-pool ----------------
__global__ __launch_bounds__(256) void k_catT(const float* __restrict__ cat, float* __restrict__ catT){
  __shared__ float tile[64*127];
  int b = blockIdx.x, t = threadIdx.x;
  const float* src = cat + (size_t)b*64*126;
  for (int i=t;i<8064;i+=256){
    int r = i/126, k = i - r*126;
    tile[r*127 + k] = src[i];
  }
  __syncthreads();
  for (int i=t;i<8064;i+=256){
    int k = i>>6, r = i&63;
    catT[(size_t)k*65536 + b*64 + r] = tile[r*127 + k];
  }
}

__global__ __launch_bounds__(256) void k_s1t(const float* __restrict__ catT, const float* __restrict__ pw,
                                             const float* __restrict__ pb, float* __restrict__ s1){
  __shared__ float wl[12600];
  __shared__ float pbl[100];
  __shared__ float redM[2][128];
  __shared__ float redS[2][128];
  int t = threadIdx.x;
  for (int i=t;i<12600;i+=256) wl[i] = pw[i];
  if (t < 100) pbl[t] = pb[t];
  int w = t>>6, lane = t&63;
  int rh = w&1, chh = w>>1;
  int ch = chh*50;
  int row = blockIdx.x*128 + rh*64 + lane;
  __syncthreads();
  float acc[50];
  #pragma unroll
  for (int j=0;j<50;j++) acc[j] = pbl[ch+j];
  for (int k=0;k<126;k++){
    float xv = catT[(size_t)k*65536 + row];
    const float* wr = &wl[k*100 + ch];
    #pragma unroll
    for (int j=0;j<50;j+=2){
      float2 wv = *(const float2*)&wr[j];
      acc[j]   += xv*wv.x;
      acc[j+1] += xv*wv.y;
    }
  }
  float m = acc[0];
  #pragma unroll
  for (int j=1;j<50;j++) m = fmaxf(m, acc[j]);
  redM[chh][rh*64 + lane] = m;
  __syncthreads();
  float mm = fmaxf(redM[0][rh*64 + lane], redM[1][rh*64 + lane]);
  float s = 0.f;
  #pragma unroll
  for (int j=0;j<50;j++){ acc[j] = expf(acc[j]-mm); s += acc[j]; }
  redS[chh][rh*64 + lane] = s;
  __syncthreads();
  float tot = redS[0][rh*64 + lane] + redS[1][rh*64 + lane];
  float* o = s1 + (size_t)row*100 + ch;
  #pragma unroll
  for (int j=0;j<50;j+=2){
    float2 ov; ov.x = acc[j]/tot; ov.y = acc[j+1]/tot;
    *(float2*)&o[j] = ov;
  }
}

__global__ __launch_bounds__(256) void k_T(const float* __restrict__ s1, const int* __restrict__ rp,
                                           const int* __restrict__ col, float* __restrict__ T){
  int b = blockIdx.x;
  int xcd = b & 7, i = b >> 3;
  int gs = i/100, j = i - gs*100;
  int graph = gs*8 + xcd;
  int idwg = j*256 + threadIdx.x;
  int rw = idwg/25, quad = idwg - rw*25;
  int v = graph*1024 + rw;
  float a0=0.f,a1=0.f,a2=0.f,a3=0.f;
  const float4* S4 = (const float4*)s1;
  int a = rp[v], e = rp[v+1];
  for (; a+8<=e; a+=8){
    int s0=col[a], s1_=col[a+1], s2=col[a+2], s3=col[a+3];
    int s4=col[a+4], s5=col[a+5], s6=col[a+6], s7=col[a+7];
    float4 u0=S4[(size_t)s0*25+quad], u1=S4[(size_t)s1_*25+quad];
    float4 u2=S4[(size_t)s2*25+quad], u3=S4[(size_t)s3*25+quad];
    float4 u4=S4[(size_t)s4*25+quad], u5=S4[(size_t)s5*25+quad];
    float4 u6=S4[(size_t)s6*25+quad], u7=S4[(size_t)s7*25+quad];
    a0+=u0.x; a1+=u0.y; a2+=u0.z; a3+=u0.w;
    a0+=u1.x; a1+=u1.y; a2+=u1.z; a3+=u1.w;
    a0+=u2.x; a1+=u2.y; a2+=u2.z; a3+=u2.w;
    a0+=u3.x; a1+=u3.y; a2+=u3.z; a3+=u3.w;
    a0+=u4.x; a1+=u4.y; a2+=u4.z; a3+=u4.w;
    a0+=u5.x; a1+=u5.y; a2+=u5.z; a3+=u5.w;
    a0+=u6.x; a1+=u6.y; a2+=u6.z; a3+=u6.w;
    a0+=u7.x; a1+=u7.y; a2+=u7.z; a3+=u7.w;
  }
  for (; a+4<=e; a+=4){
    int s0=col[a], s1_=col[a+1], s2=col[a+2], s3=col[a+3];
    float4 u0=S4[(size_t)s0*25+quad], u1=S4[(size_t)s1_*25+quad];
    float4 u2=S4[(size_t)s2*25+quad], u3=S4[(size_t)s3*25+quad];
    a0+=u0.x; a1+=u0.y; a2+=u0.z; a3+=u0.w;
    a0+=u1.x; a1+=u1.y; a2+=u1.z; a3+=u1.w;
    a0+=u2.x; a1+=u2.y; a2+=u2.z; a3+=u2.w;
    a0+=u3.x; a1+=u3.y; a2+=u3.z; a3+=u3.w;
  }
  for (; a<e; ++a){
    float4 u = S4[(size_t)col[a]*25+quad];
    a0+=u.x; a1+=u.y; a2+=u.z; a3+=u.w;
  }
  ((float4*)T)[(size_t)v*25 + quad] = make_float4(a0,a1,a2,a3);
}

// merged split-K: blocks 0..255 = p1adj, 256..511 = p1x (BN affine on fill)
__global__ __launch_bounds__(512) void k_p1ax(const float* __restrict__ s1, const float* __restrict__ T,
                                              const float* __restrict__ y3, const float* __restrict__ sfc,
                                              float* __restrict__ partA, float* __restrict__ partX){
  __shared__ float sS[6400];
  __shared__ float sT[6400];
  int t = threadIdx.x;
  if (blockIdx.x < 256){
    int blk = blockIdx.x;
    int b = blk >> 2, qtr = blk & 3;
    int tk = t/20, tl = t - tk*20;
    bool act = t < 500;
    int k0 = tk*4, l0 = tl*5;
    float acc[4][5];
    #pragma unroll
    for (int i=0;i<4;i++)
      #pragma unroll
      for (int j=0;j<5;j++) acc[i][j] = 0.f;
    const float* s1b = s1 + (size_t)b*102400;
    const float* Tb  = T  + (size_t)b*102400;
    for (int c=qtr*4; c<qtr*4+4; c++){
      for (int i=t;i<6400;i+=512){ sS[i] = s1b[c*6400+i]; sT[i] = Tb[c*6400+i]; }
      __syncthreads();
      if (act){
        #pragma unroll 2
        for (int n=0;n<64;n++){
          const float* sr = &sS[n*100 + k0];
          const float* tr = &sT[n*100 + l0];
          float s0=sr[0], s1v=sr[1], s2=sr[2], s3=sr[3];
          float t0=tr[0], t1=tr[1], t2=tr[2], t3=tr[3], t4=tr[4];
          acc[0][0]+=s0*t0; acc[0][1]+=s0*t1; acc[0][2]+=s0*t2; acc[0][3]+=s0*t3; acc[0][4]+=s0*t4;
          acc[1][0]+=s1v*t0; acc[1][1]+=s1v*t1; acc[1][2]+=s1v*t2; acc[1][3]+=s1v*t3; acc[1][4]+=s1v*t4;
          acc[2][0]+=s2*t0; acc[2][1]+=s2*t1; acc[2][2]+=s2*t2; acc[2][3]+=s2*t3; acc[2][4]+=s2*t4;
          acc[3][0]+=s3*t0; acc[3][1]+=s3*t1; acc[3][2]+=s3*t2; acc[3][3]+=s3*t3; acc[3][4]+=s3*t4;
        }
      }
      __syncthreads();
    }
    if (act){
      float* pp = partA + (size_t)qtr*640000 + (size_t)b*10000;
      #pragma unroll
      for (int i=0;i<4;i++){
        float* o = pp + (k0+i)*100 + l0;
        #pragma unroll
        for (int j=0;j<5;j++) o[j] = acc[i][j];
      }
    }
  } else {
    int blk = blockIdx.x - 256;
    int b = blk >> 2, qtr = blk & 3;
    float* sX = sT;
    int tk = t/10, tl = t - tk*10;
    bool act = t < 250;
    int k0 = tk*4, d0 = tl*3;
    float acc[4][3];
    #pragma unroll
    for (int i=0;i<4;i++)
      #pragma unroll
      for (int j=0;j<3;j++) acc[i][j] = 0.f;
    const float* s1b = s1 + (size_t)b*102400;
    const float* xb  = y3 + (size_t)b*30720;
    for (int c=qtr*4; c<qtr*4+4; c++){
      for (int i=t;i<6400;i+=512) sS[i] = s1b[c*6400+i];
      for (int i=t;i<1920;i+=512){
        int f = i % 30;
        sX[i] = sfc[f]*xb[c*1920+i] + sfc[32+f];
      }
      __syncthreads();
      if (act){
        #pragma unroll 2
        for (int n=0;n<64;n++){
          const float* sr = &sS[n*100 + k0];
          const float* xr = &sX[n*30 + d0];
          float s0=sr[0], s1v=sr[1], s2=sr[2], s3=sr[3];
          float x0=xr[0], x1=xr[1], x2=xr[2];
          acc[0][0]+=s0*x0; acc[0][1]+=s0*x1; acc[0][2]+=s0*x2;
          acc[1][0]+=s1v*x0; acc[1][1]+=s1v*x1; acc[1][2]+=s1v*x2;
          acc[2][0]+=s2*x0; acc[2][1]+=s2*x1; acc[2][2]+=s2*x2;
          acc[3][0]+=s3*x0; acc[3][1]+=s3*x1; acc[3][2]+=s3*x2;
        }
      }
      __syncthreads();
    }
    if (act){
      float* pp = partX + (size_t)qtr*192000 + (size_t)b*3000;
      #pragma unroll
      for (int i=0;i<4;i++){
        float* o = pp + (k0+i)*30 + d0;
        #pragma unroll
        for (int j=0;j<3;j++) o[j] = acc[i][j];
      }
    }
  }
}

// blocks 0..63: reduce padj parts + normalize -> An; 64..813: px reduce
__global__ __launch_bounds__(256) void k_anpx(const float* __restrict__ pA, const float* __restrict__ pX,
                                              float* __restrict__ An, float* __restrict__ px){
  if (blockIdx.x < 64){
    __shared__ float pj[10000];
    __shared__ float dv[100];
    int b = blockIdx.x, t = threadIdx.x;
    size_t base = (size_t)b*10000;
    for (int i=t;i<10000;i+=256)
      pj[i] = pA[base+i] + pA[640000+base+i] + pA[1280000+base+i] + pA[1920000+base+i];
    __syncthreads();
    if (t < 100){
      const float* r = pj + t*100;
      float s = 0.f;
      for (int l=0;l<100;l++){
        float v = r[l];
        if (l==t) v += 1.0f;
        s += v;
      }
      dv[t] = 1.0f/sqrtf(s);
    }
    __syncthreads();
    for (int i=t;i<10000;i+=256){
      int k = i/100, l = i - k*100;
      float a = pj[i] + ((k==l)? 1.0f : 0.0f);
      An[base + i] = (dv[k]*a)*dv[l];
    }
  } else {
    int id = ((int)blockIdx.x - 64)*256 + threadIdx.x;
    if (id < 192000)
      px[id] = pX[id] + pX[192000+id] + pX[384000+id] + pX[576000+id];
  }
}

// ---------------- stage-2 dense GCN (y2 + fused last-block bnw) ----------
__global__ __launch_bounds__(256) void k_y2(const float* __restrict__ An, const float* __restrict__ h,
    const float* __restrict__ bias, float* __restrict__ y,
    float* __restrict__ gS, float* __restrict__ gQ, int* __restrict__ sync,
    int fold, const float* __restrict__ g, const float* __restrict__ be,
    const float* __restrict__ wnext, float* __restrict__ sfc,
    float* __restrict__ wfold, float* __restrict__ cvec){
  __shared__ float binS[30], binQ[30];
  int t = threadIdx.x;
  if (t < 30){ binS[t]=0.f; binQ[t]=0.f; }
  __syncthreads();
  int id = blockIdx.x*256 + t;
  if (id < NBG*100*30){
    int d = id % 30;
    int bk = id / 30;
    int b = bk / 100;
    const float* Ar = An + bk*100;
    const float* hb = h + b*100*30;
    float acc = 0.f;
    for (int l=0;l<100;l++) acc += Ar[l]*hb[l*30+d];
    float val = acc + bias[d];
    y[id] = val;
    atomicAdd(&binS[d], val);
    atomicAdd(&binQ[d], val*val);
  }
  __syncthreads();
  if (t < 30){
    int slot = (blockIdx.x & 63)*30 + t;
    atomicAdd(&gS[slot], binS[t]);
    atomicAdd(&gQ[slot], binQ[t]);
  }
  // last-block bnw
  __shared__ int lastFlag;
  __threadfence();
  __syncthreads();
  if (t == 0){
    int done = atomicAdd(sync, 1);
    lastFlag = (done == 749);
  }
  __syncthreads();
  if (!lastFlag) return;
  __threadfence();
  __shared__ float s_l[30], c_l[30];
  if (t < 30){
    float s=0.f, q=0.f;
    for (int u=0;u<64;u++){ s += gS[u*30+t]; q += gQ[u*30+t]; }
    float m = s/6400.0f;
    float var = q/6400.0f - m*m;
    float sc = g[t]*(1.0f/sqrtf(var+1e-5f));
    float c0 = be[t] - sc*m;
    s_l[t]=sc; c_l[t]=c0;
    sfc[t]=sc; sfc[32+t]=c0;
    for (int u=0;u<64;u++){ gS[u*30+t]=0.f; gQ[u*30+t]=0.f; }
  }
  __syncthreads();
  if (fold){
    for (int i=t;i<900;i+=256) wfold[i] = s_l[i/30]*wnext[i];
    if (t<30){
      float c=0.f;
      for (int k=0;k<30;k++) c += c_l[k]*wnext[k*30+t];
      cvec[t]=c;
    }
  }
  if (t == 0) atomicExch(sync, 0);
}

// stage-2 pool (big-LDS variant, separate launch)
__global__ __launch_bounds__(256) void k_pool2(const float* __restrict__ A,
    const float* __restrict__ Bv, const float* __restrict__ Cv,
    const float* __restrict__ sfcBase,
    int rows, float* __restrict__ conv, int coff){
  __shared__ float lds[256*31];
  int b = blockIdx.x, a = blockIdx.y, t = threadIdx.x;
  const float* X = (a==0)? A : ((a==1)? Bv : Cv);
  const float* sf = sfcBase + a*64;
  float acc[30];
  #pragma unroll
  for (int f=0;f<30;f++) acc[f] = -FLT_MAX;
  for (int r=t; r<rows; r+=256){
    const float* xr = X + (size_t)(b*rows + r)*30;
    #pragma unroll
    for (int f=0;f<30;f++) acc[f] = fmaxf(acc[f], sf[f]*xr[f] + sf[32+f]);
  }
  #pragma unroll
  for (int f=0;f<30;f++) lds[t*31+f] = acc[f];
  __syncthreads();
  for (int s=128;s>0;s>>=1){
    if (t<s){
      #pragma unroll
      for (int f=0;f<30;f++) lds[t*31+f] = fmaxf(lds[t*31+f], lds[(t+s)*31+f]);
    }
    __syncthreads();
  }
  if (t<30) conv[b*180 + coff + a*30 + t] = lds[t];
}

__global__ __launch_bounds__(64) void k_fc(const float* __restrict__ conv,
    const float* __restrict__ w1, const float* __restrict__ b1,
    const float* __restrict__ w2, const float* __restrict__ b2, float* __restrict__ out){
  __shared__ float row[180];
  __shared__ float hid[50];
  int b = blockIdx.x, t = threadIdx.x;
  for (int i=t;i<180;i+=64) row[i] = conv[b*180+i];
  __syncthreads();
  if (t < 50){
    float a = b1[t];
    for (int i=0;i<180;i++) a += row[i]*w1[i*50+t];
    hid[t] = fmaxf(a, 0.f);
  }
  __syncthreads();
  if (t < 6){
    float a = b2[t];
    for (int i=0;i<50;i++) a += hid[i]*w2[i*6+t];
    out[b*6+t] = a;
  }
  if (b==0 && t==63) out[NBG*6] = 0.0f;
}

// ---------------------------------------------------------------------------
extern "C" void kernel_launch(void* const* d_in, const int* in_sizes, int n_in,
                              void* d_out, int out_size, void* d_ws, size_t ws_size,
                              hipStream_t stream)
{
  (void)in_sizes; (void)n_in; (void)out_size; (void)ws_size;
  const float* x   = (const float*)d_in[0];
  const int*   src = (const int*)d_in[1];
  const int*   dst = src + NEDGE;
  const float* w11=(const float*)d_in[3],  *b11=(const float*)d_in[4],  *g11=(const float*)d_in[5],  *be11=(const float*)d_in[6];
  const float* w12=(const float*)d_in[7],  *b12=(const float*)d_in[8],  *g12=(const float*)d_in[9],  *be12=(const float*)d_in[10];
  const float* w13=(const float*)d_in[11], *b13=(const float*)d_in[12], *g13=(const float*)d_in[13], *be13=(const float*)d_in[14];
  const float* w21=(const float*)d_in[15], *b21=(const float*)d_in[16], *g21=(const float*)d_in[17], *be21=(const float*)d_in[18];
  const float* w22=(const float*)d_in[19], *b22=(const float*)d_in[20], *g22=(const float*)d_in[21], *be22=(const float*)d_in[22];
  const float* w23=(const float*)d_in[23], *b23=(const float*)d_in[24], *g23=(const float*)d_in[25], *be23=(const float*)d_in[26];
  const float* betas=(const float*)d_in[27];
  const float* poolw=(const float*)d_in[28], *poolb=(const float*)d_in[29];
  const float* fc1w=(const float*)d_in[30], *fc1b=(const float*)d_in[31];
  const float* fc2w=(const float*)d_in[32], *fc2b=(const float*)d_in[33];
  float* out = (float*)d_out;

  uint8_t* basep = (uint8_t*)d_ws;
  size_t off = 0;
  auto take = [&](size_t bytes)->void*{
    void* p = basep + off;
    off = (off + bytes + 255) & ~(size_t)255;
    return p;
  };
  int* degi    = (int*)take((size_t)NN*4);
  int* dego    = (int*)take((size_t)NN*4);
  int* cntA    = (int*)take((size_t)NN*4);
  int* cntB    = (int*)take((size_t)NN*4);
  float* gS    = (float*)take(64*30*4);     // BN stat slots (zeroed by memset)
  float* gQ    = (float*)take(64*30*4);
  int* syncc   = (int*)take(256);           // completion counters (zeroed)
  int* rp_in   = (int*)take((size_t)(NN+1)*4);
  int* rp_out  = (int*)take((size_t)(NN+1)*4);
  int* bsum    = (int*)take(512*4);
  int* col_in  = (int*)take((size_t)NEDGE*4);
  int* col_out = (int*)take((size_t)NEDGE*4);
  float* dinv  = (float*)take((size_t)NN*4);
  float* hbuf  = (float*)take((size_t)NN*30*4);
  float* X1    = (float*)take((size_t)NN*30*4);   // pre-BN y1
  float* X2    = (float*)take((size_t)NN*30*4);   // pre-BN y2
  float* X3    = (float*)take((size_t)NN*30*4);   // pre-BN y3
  float* bufA  = (float*)take((size_t)NN*126*4);
  float* bufB  = (float*)take((size_t)NN*126*4);
  float* logA  = (float*)take((size_t)NN*126*4);
  float* logB  = (float*)take((size_t)NN*126*4);
  float* partCS= (float*)take((size_t)6*256*64*4);
  float* fieldv= (float*)take(384*4);
  float* sfcAll= (float*)take(6*64*4);
  float* wfold = (float*)take(960*4);
  float* cvec  = (float*)take(32*4);
  float* px    = (float*)take(192000*4);
  float* An    = (float*)take(640000*4);
  float* h2    = (float*)take(192000*4);
  float* X21   = (float*)take(192000*4);  // pre-BN
  float* X22   = (float*)take(192000*4);
  float* X23   = (float*)take(192000*4);
  float* conv  = (float*)take(64*180*4);

  // post-BP scratch reuse: catT -> logA; split-K partials -> logB
  float* catT     = logA;
  float* pAdjPart = logB;               // 4*640000 floats
  float* pPxPart  = logB + 2560000;     // 4*192000 floats

  // ---- CSR + stat/counter zero (degi..syncc contiguous -> single memset) --
  hipMemsetAsync(degi, 0, (size_t)4*NN*4 + 2*64*30*4 + 256, stream);
  k_count<<<2048,256,0,stream>>>(src,dst,degi,dego);
  k_scan1<<<dim3(256,2),256,0,stream>>>(degi, dego, rp_in, rp_out, bsum);
  k_scan2<<<2,256,0,stream>>>(bsum);
  k_scan3<<<dim3(256,2),256,0,stream>>>(rp_in, rp_out, bsum);
  k_fill<<<dim3(2048,2),256,0,stream>>>(src, dst, rp_in, rp_out, cntA, cntB, col_in, col_out);
  k_sortrow<<<dim3(256,2),256,0,stream>>>(rp_in, rp_out, col_in, col_out, src, dst, degi, dinv);

  // ---- BP with stage-1 hidden as aux blocks ----
  k_bp_first<<<15872,256,0,stream>>>(bufA, logA, betas, x, w11, hbuf);  // + mm30<3>

  float* cur = bufA;  float* nxt = bufB;
  float* lcur = logA; float* lnxt = logB;
  for (int it=0; it<10; ++it){
    int fold = (it==1||it==3)? 1 : ((it==5)? 0 : -1);
    const float* gg = (it==1)? g11 : ((it==3)? g12 : g13);
    const float* bb = (it==1)? be11: ((it==3)? be12: be13);
    const float* wn = (it==1)? w12 : ((it==3)? w13 : nullptr);
    float* sfc = (it==1)? sfcAll : ((it==3)? sfcAll+64 : sfcAll+128);
    k_colsum_field<<<1536,64,0,stream>>>(cur, partCS, betas, fieldv, syncc,
                                         fold, gS, gQ, 65536.f, gg, bb, wn, sfc, wfold, cvec);
    int fin = (it==9);
    int auxType = 0, auxN = 0;
    const float *aA=nullptr, *aB=nullptr, *aC=nullptr; float *aO=nullptr;
    if      (it==0){ auxType=1; auxN=3840; aA=hbuf; aB=b11; aO=X1; }
    else if (it==1){ auxType=2; auxN=7680; aA=X1; aB=wfold; aC=cvec; aO=hbuf; }
    else if (it==2){ auxType=1; auxN=3840; aA=hbuf; aB=b12; aO=X2; }
    else if (it==3){ auxType=2; auxN=7680; aA=X2; aB=wfold; aC=cvec; aO=hbuf; }
    else if (it==4){ auxType=1; auxN=3840; aA=hbuf; aB=b13; aO=X3; }
    else if (it==5){ auxType=3; auxN=192;  aA=X1; aB=X2; aC=X3; }
    k_bp_step<<<8192+auxN,256,0,stream>>>(nxt, lcur, lnxt, rp_in, col_in, fieldv, betas, fin,
        auxType, aA, aB, aC, aO, gS, gQ, dinv, sfcAll, conv);
    float* tp = cur;  cur = nxt;   nxt = tp;
    float* tl = lcur; lcur = lnxt; lnxt = tl;
  }
  // final concatenated psi [NN][126] now in bufA

  // ---- diff-pool ----
  k_catT<<<1024,256,0,stream>>>(bufA, catT);
  k_s1t<<<512,256,0,stream>>>(catT, poolw, poolb, bufB);
  k_T<<<6400,256,0,stream>>>(bufB, rp_out, col_out, bufA);
  k_p1ax<<<512,512,0,stream>>>(bufB, bufA, X3, sfcAll+128, pAdjPart, pPxPart);
  k_anpx<<<814,256,0,stream>>>(pAdjPart, pPxPart, An, px);

  // ---- stage 2: dense GCN x3 with folded BN (bnw fused into y2) ----
  k_mm30<30><<<750,256,0,stream>>>(px, w21, h2, NBG*100);
  k_y2<<<750,256,0,stream>>>(An, h2, b21, X21, gS, gQ, syncc+1,
                             1, g21, be21, w22, sfcAll+192, wfold, cvec);
  k_mm30c<<<750,256,0,stream>>>(X21, wfold, cvec, h2, NBG*100);
  k_y2<<<750,256,0,stream>>>(An, h2, b22, X22, gS, gQ, syncc+1,
                             1, g22, be22, w23, sfcAll+256, wfold, cvec);
  k_mm30c<<<750,256,0,stream>>>(X22, wfold, cvec, h2, NBG*100);
  k_y2<<<750,256,0,stream>>>(An, h2, b23, X23, gS, gQ, syncc+1,
                             0, g23, be23, nullptr, sfcAll+320, wfold, cvec);
  k_pool2<<<dim3(NBG,3),256,0,stream>>>(X21, X22, X23, sfcAll+192, 100, conv, 90);

  // ---- FC head ----
  k_fc<<<64,64,0,stream>>>(conv, fc1w, fc1b, fc2w, fc2b, out);
}

// Round 15
// 1232.138 us; speedup vs baseline: 1.5904x; 1.5904x over previous
//
#include <hip/hip_runtime.h>
#include <stdint.h>
#include <float.h>

// ---------------------------------------------------------------------------
// Net_57604101374728: GCN(x3)+BN -> maxpool | 6x belief-prop -> diffpool ->
// dense GCN(x3)+BN -> maxpool -> FC. Full fp32 port of the JAX reference.
//
// R15 = revert to R13 (best known: 1237us). R14's last-block completion
// fusion (__threadfence + atomic counter) stalled every colsum block ~90us
// (device-scope fence = cross-XCD L2 flush on gfx950) -> reverted. Stage-1
// hidden under BP via aux blocks; k_field block1 carries bnw; BP bit-exact.
// ---------------------------------------------------------------------------

constexpr int NN    = 65536;    // total nodes
constexpr int NEDGE = 524288;   // edges
constexpr int NBG   = 64;       // graphs

__constant__ int cQS[6]   = {2,4,8,16,32,64};

// ---------------- threefry2x32 (20 rounds) ----------------
__device__ __forceinline__ void tf2x32(uint32_t k0, uint32_t k1, uint32_t x0, uint32_t x1,
                                       uint32_t& o0, uint32_t& o1){
  uint32_t ks[3] = {k0, k1, k0 ^ k1 ^ 0x1BD11BDAu};
  x0 += ks[0]; x1 += ks[1];
  const int RA[4] = {13,15,26,6}, RB[4] = {17,29,16,24};
  #pragma unroll
  for (int i=0;i<5;i++){
    const int* r = (i&1)? RB : RA;
    #pragma unroll
    for (int j=0;j<4;j++){
      x0 += x1;
      x1 = (x1 << r[j]) | (x1 >> (32 - r[j]));
      x1 ^= x0;
    }
    x0 += ks[(i+1)%3];
    x1 += ks[(i+2)%3] + (uint32_t)(i+1);
  }
  o0 = x0; o1 = x1;
}

// ---------------- XLA ErfInv32 (Giles), contraction off ----------------
__device__ __forceinline__ float erfinv32(float xx){
  #pragma clang fp contract(off)
  float w = -log1pf(-xx*xx);
  float p;
  if (w < 5.0f){
    w = w - 2.5f;
    p = 2.81022636e-08f;
    p = 3.43273939e-07f  + p*w;
    p = -3.5233877e-06f  + p*w;
    p = -4.39150654e-06f + p*w;
    p = 0.00021858087f   + p*w;
    p = -0.00125372503f  + p*w;
    p = -0.00417768164f  + p*w;
    p = 0.246640727f     + p*w;
    p = 1.50140941f      + p*w;
  } else {
    w = sqrtf(w) - 3.0f;
    p = -0.000200214257f;
    p = 0.000100950558f  + p*w;
    p = 0.00134934322f   + p*w;
    p = -0.00367342844f  + p*w;
    p = 0.00573950773f   + p*w;
    p = -0.0076224613f   + p*w;
    p = 0.00943887047f   + p*w;
    p = 1.00167406f      + p*w;
    p = 2.83297682f      + p*w;
  }
  return p*xx;
}

// ---------------- CSR construction (fused pairs via blockIdx.y) ----------
__global__ __launch_bounds__(256) void k_count(const int* __restrict__ src, const int* __restrict__ dst,
                                               int* __restrict__ degi, int* __restrict__ dego){
  int e = blockIdx.x*256 + threadIdx.x;
  if (e >= NEDGE) return;
  atomicAdd(&degi[dst[e]], 1);
  atomicAdd(&dego[src[e]], 1);
}

__global__ __launch_bounds__(256) void k_scan1(const int* __restrict__ degi, const int* __restrict__ dego,
                                               int* __restrict__ rpi, int* __restrict__ rpo,
                                               int* __restrict__ bsum){
  __shared__ int lds[256];
  const int* deg = blockIdx.y? dego : degi;
  int* rp = blockIdx.y? rpo : rpi;
  int* bs = bsum + blockIdx.y*256;
  int b = blockIdx.x, t = threadIdx.x;
  lds[t] = deg[b*256 + t];
  __syncthreads();
  for (int s=1;s<256;s<<=1){
    int add = (t>=s)? lds[t-s] : 0;
    __syncthreads();
    lds[t] += add;
    __syncthreads();
  }
  rp[b*256 + t + 1] = lds[t];
  if (t==0 && b==0) rp[0] = 0;
  if (t==255) bs[b] = lds[255];
}

__global__ __launch_bounds__(256) void k_scan2(int* __restrict__ bsum){
  __shared__ int lds[256];
  int* bs = bsum + blockIdx.x*256;
  int t = threadIdx.x;
  lds[t] = bs[t];
  __syncthreads();
  for (int s=1;s<256;s<<=1){
    int add = (t>=s)? lds[t-s] : 0;
    __syncthreads();
    lds[t] += add;
    __syncthreads();
  }
  bs[t] = (t==0)? 0 : lds[t-1];
}

__global__ __launch_bounds__(256) void k_scan3(int* __restrict__ rpi, int* __restrict__ rpo,
                                               const int* __restrict__ bsum){
  int* rp = blockIdx.y? rpo : rpi;
  const int* bs = bsum + blockIdx.y*256;
  int b = blockIdx.x, t = threadIdx.x;
  rp[b*256 + t + 1] += bs[b];
}

__global__ __launch_bounds__(256) void k_fill(const int* __restrict__ src, const int* __restrict__ dst,
                                              const int* __restrict__ rpi, const int* __restrict__ rpo,
                                              int* __restrict__ cntA, int* __restrict__ cntB,
                                              int* __restrict__ colI, int* __restrict__ colO){
  int e = blockIdx.x*256 + threadIdx.x;
  if (e >= NEDGE) return;
  if (blockIdx.y == 0){
    int d = dst[e];
    int p = atomicAdd(&cntA[d], 1);
    colI[rpi[d] + p] = e;
  } else {
    int d = src[e];
    int p = atomicAdd(&cntB[d], 1);
    colO[rpo[d] + p] = e;
  }
}

__global__ __launch_bounds__(256) void k_sortrow(const int* __restrict__ rpi, const int* __restrict__ rpo,
                                                 int* __restrict__ colI, int* __restrict__ colO,
                                                 const int* __restrict__ src, const int* __restrict__ dst,
                                                 const int* __restrict__ degi, float* __restrict__ dinv){
  const int* rp = blockIdx.y? rpo : rpi;
  int* colbuf   = blockIdx.y? colO : colI;
  const int* other = blockIdx.y? dst : src;
  int v = blockIdx.x*256 + threadIdx.x;
  if (v >= NN) return;
  int s0 = rp[v], s1 = rp[v+1];
  for (int i=s0+1;i<s1;i++){
    int key = colbuf[i]; int j = i-1;
    while (j>=s0 && colbuf[j]>key){ colbuf[j+1]=colbuf[j]; j--; }
    colbuf[j+1] = key;
  }
  for (int i=s0;i<s1;i++) colbuf[i] = other[colbuf[i]];
  if (blockIdx.y == 0) dinv[v] = 1.0f / sqrtf((float)(degi[v] + 1));
}

// ---------------- stage-2 GEMM helpers (standalone) ----------------
template<int CIN>
__global__ __launch_bounds__(256) void k_mm30(const float* __restrict__ x, const float* __restrict__ w,
                                              float* __restrict__ h, int nrow){
  __shared__ float ws[CIN*30];
  int t = threadIdx.x;
  for (int i=t;i<CIN*30;i+=256) ws[i] = w[i];
  __syncthreads();
  int id = blockIdx.x*256 + t;
  if (id >= nrow*30) return;
  int v = id/30, j = id - v*30;
  const float* xr = x + v*CIN;
  float acc = 0.f;
  #pragma unroll
  for (int k=0;k<CIN;k++) acc += xr[k]*ws[k*30+j];
  h[id] = acc;
}

__global__ __launch_bounds__(256) void k_mm30c(const float* __restrict__ x, const float* __restrict__ wfold,
                                               const float* __restrict__ cvec, float* __restrict__ h, int nrow){
  __shared__ float ws[900];
  __shared__ float cl[30];
  int t = threadIdx.x;
  for (int i=t;i<900;i+=256) ws[i] = wfold[i];
  if (t < 30) cl[t] = cvec[t];
  __syncthreads();
  int id = blockIdx.x*256 + t;
  if (id >= nrow*30) return;
  int v = id/30, j = id - v*30;
  const float* xr = x + v*30;
  float acc = cl[j];
  #pragma unroll
  for (int k=0;k<30;k++) acc += xr[k]*ws[k*30+j];
  h[id] = acc;
}

// BN finalize (standalone, stage-2)
template<int FOLD>
__global__ __launch_bounds__(256) void k_bnw(float* __restrict__ gS, float* __restrict__ gQ, float n,
    const float* __restrict__ g, const float* __restrict__ be,
    const float* __restrict__ wnext, float* __restrict__ sfc,
    float* __restrict__ wfold, float* __restrict__ cvec){
  __shared__ float s_l[30], c_l[30];
  int t = threadIdx.x;
  if (t < 30){
    float s=0.f, q=0.f;
    for (int u=0;u<64;u++){ s += gS[u*30+t]; q += gQ[u*30+t]; }
    float m = s/n;
    float var = q/n - m*m;
    float sc = g[t]*(1.0f/sqrtf(var+1e-5f));
    float c0 = be[t] - sc*m;
    s_l[t]=sc; c_l[t]=c0;
    sfc[t]=sc; sfc[32+t]=c0;
    for (int u=0;u<64;u++){ gS[u*30+t]=0.f; gQ[u*30+t]=0.f; }
  }
  __syncthreads();
  if (FOLD){
    for (int i=t;i<900;i+=256) wfold[i] = s_l[i/30]*wnext[i];
    if (t<30){
      float c=0.f;
      for (int k=0;k<30;k++) c += c_l[k]*wnext[k*30+t];
      cvec[t]=c;
    }
  }
}

// ---------------- belief propagation (col-vectorized, XCD-resident) -------
__device__ __forceinline__ void bp_decode2(int b, int& graph, int& run, int& jj){
  int xcd = b & 7, i = b >> 3;
  int gs = i >> 7, j = i & 127;
  if      (j <   4){ run=0; jj=j;    }
  else if (j <   8){ run=1; jj=j-4;  }
  else if (j <  16){ run=2; jj=j-8;  }
  else if (j <  32){ run=3; jj=j-16; }
  else if (j <  64){ run=4; jj=j-32; }
  else             { run=5; jj=j-64; }
  graph = gs*8 + xcd;
}

template<int TPR>
__device__ __forceinline__ void bfly_max4(float& m0, float& m1, float& m2, float& m3){
  if constexpr (TPR > 1){
    #pragma unroll
    for (int lm = TPR>>1; lm; lm >>= 1){
      float p0=__shfl_xor(m0,lm,64), p1=__shfl_xor(m1,lm,64);
      float p2=__shfl_xor(m2,lm,64), p3=__shfl_xor(m3,lm,64);
      m0=fmaxf(m0,p0); m1=fmaxf(m1,p1); m2=fmaxf(m2,p2); m3=fmaxf(m3,p3);
    }
  }
  { float t0=fmaxf(m0,m2), t1=fmaxf(m1,m3), t2=fmaxf(m2,m0), t3=fmaxf(m3,m1);
    m0=t0; m1=t1; m2=t2; m3=t3; }
  { float t0=fmaxf(m0,m1), t1=fmaxf(m1,m0), t2=fmaxf(m2,m3), t3=fmaxf(m3,m2);
    m0=t0; m1=t1; m2=t2; m3=t3; }
}

template<int TPR>
__device__ __forceinline__ void bfly_sum4(float& s0, float& s1, float& s2, float& s3){
  if constexpr (TPR > 1){
    #pragma unroll
    for (int lm = TPR>>1; lm; lm >>= 1){
      float p0=__shfl_xor(s0,lm,64), p1=__shfl_xor(s1,lm,64);
      float p2=__shfl_xor(s2,lm,64), p3=__shfl_xor(s3,lm,64);
      s0 += p0; s1 += p1; s2 += p2; s3 += p3;
    }
  }
  { float t0=s0+s2, t1=s1+s3, t2=s2+s0, t3=s3+s1;
    s0=t0; s1=t1; s2=t2; s3=t3; }
  { float t0=s0+s1, t1=s1+s0, t2=s2+s3, t3=s3+s2;
    s0=t0; s1=t1; s2=t2; s3=t3; }
}

template<int Q, int CO, int TPR, int L2T>
__device__ __forceinline__ void bp_first_elem2(int graph, int jj, float* __restrict__ psi_pk,
                                               float* __restrict__ lg, float eb,
                                               uint32_t k0, uint32_t k1){
  int idx = jj*256 + (int)threadIdx.x;
  if constexpr (Q == 2){
    int row = graph*1024 + idx;
    float z[2];
    #pragma unroll
    for (int r=0;r<2;r++){
      uint32_t b0,b1;
      tf2x32(k0,k1, 0u, (uint32_t)(row*2 + r), b0,b1);
      uint32_t bits = b0 ^ b1;
      float f = __uint_as_float((bits>>9) | 0x3F800000u) - 1.0f;
      const float lo = __uint_as_float(0xBF7FFFFFu);
      float u = fmaxf(lo, f*2.0f + lo);
      z[r] = __uint_as_float(0x3FB504F3u) * erfinv32(u);
    }
    float m0=fmaxf(z[0],z[1]), m1=fmaxf(z[1],z[0]);
    float e0=expf(z[0]-m0), e1=expf(z[1]-m1);
    float s0=e0+e1, s1=e1+e0;
    float p0=e0/s0, p1=e1/s1;
    ((float2*)(psi_pk + (size_t)NN*CO))[row] = make_float2(p0,p1);
    ((float2*)(lg     + (size_t)NN*CO))[row] = make_float2(log1pf(eb*p0), log1pf(eb*p1));
  } else {
    int rw = idx >> L2T, ct = idx & (TPR-1);
    int row = graph*1024 + rw;
    float z[4];
    #pragma unroll
    for (int r=0;r<4;r++){
      uint32_t b0,b1;
      tf2x32(k0,k1, 0u, (uint32_t)(row*Q + 4*ct + r), b0,b1);
      uint32_t bits = b0 ^ b1;
      float f = __uint_as_float((bits>>9) | 0x3F800000u) - 1.0f;
      const float lo = __uint_as_float(0xBF7FFFFFu);
      float u = fmaxf(lo, f*2.0f + lo);
      z[r] = __uint_as_float(0x3FB504F3u) * erfinv32(u);
    }
    float m0=z[0],m1=z[1],m2=z[2],m3=z[3];
    bfly_max4<TPR>(m0,m1,m2,m3);
    float e0=expf(z[0]-m0), e1=expf(z[1]-m1), e2=expf(z[2]-m2), e3=expf(z[3]-m3);
    float s0=e0,s1=e1,s2=e2,s3=e3;
    bfly_sum4<TPR>(s0,s1,s2,s3);
    float p0=e0/s0, p1=e1/s1, p2=e2/s2, p3=e3/s3;
    ((float4*)(psi_pk + (size_t)NN*CO))[(size_t)row*TPR + ct] = make_float4(p0,p1,p2,p3);
    ((float4*)(lg     + (size_t)NN*CO))[(size_t)row*TPR + ct] =
        make_float4(log1pf(eb*p0), log1pf(eb*p1), log1pf(eb*p2), log1pf(eb*p3));
  }
}

// bp_first + aux mm30<3> (blocks >= 8192)
__global__ __launch_bounds__(256) void k_bp_first(float* __restrict__ psi_pk, float* __restrict__ lg,
                                                  const float* __restrict__ betas,
                                                  const float* __restrict__ xin,
                                                  const float* __restrict__ w11,
                                                  float* __restrict__ hbuf){
  if (blockIdx.x >= 8192){
    __shared__ float ws[90];
    int t = threadIdx.x;
    for (int i=t;i<90;i+=256) ws[i] = w11[i];
    __syncthreads();
    int id = ((int)blockIdx.x - 8192)*256 + t;
    if (id >= NN*30) return;
    int v = id/30, j = id - v*30;
    const float* xr = xin + v*3;
    float acc = 0.f;
    #pragma unroll
    for (int k=0;k<3;k++) acc += xr[k]*ws[k*30+j];
    hbuf[id] = acc;
    return;
  }
  int graph, run, jj;
  bp_decode2(blockIdx.x, graph, run, jj);
  uint32_t k0, k1;
  tf2x32(0u, 42u, 0u, (uint32_t)run, k0, k1);
  float eb = expm1f(betas[run]);
  switch(run){
    case 0: bp_first_elem2< 2, 0, 1,0>(graph, jj, psi_pk, lg, eb, k0, k1); break;
    case 1: bp_first_elem2< 4, 2, 1,0>(graph, jj, psi_pk, lg, eb, k0, k1); break;
    case 2: bp_first_elem2< 8, 6, 2,1>(graph, jj, psi_pk, lg, eb, k0, k1); break;
    case 3: bp_first_elem2<16,14, 4,2>(graph, jj, psi_pk, lg, eb, k0, k1); break;
    case 4: bp_first_elem2<32,30, 8,3>(graph, jj, psi_pk, lg, eb, k0, k1); break;
    default:bp_first_elem2<64,62,16,4>(graph, jj, psi_pk, lg, eb, k0, k1); break;
  }
}

template<int Q, int CO, int TPR, int L2T>
__device__ __forceinline__ void bp_step_elem2(int graph, int run, int jj,
    const float* __restrict__ lcur, float* __restrict__ nxt, float* __restrict__ lnxt,
    const int* __restrict__ rp, const int* __restrict__ col,
    const float* __restrict__ field, float eb, int fin){
  int idx = jj*256 + (int)threadIdx.x;
  if constexpr (Q == 2){
    int row = graph*1024 + idx;
    const float2* B2 = (const float2*)(lcur + (size_t)NN*CO);
    float a0=0.f, a1=0.f;
    int a = rp[row], b2 = rp[row+1];
    for (; a+8<=b2; a+=8){
      int s0=col[a],s1=col[a+1],s2=col[a+2],s3=col[a+3];
      int s4=col[a+4],s5=col[a+5],s6=col[a+6],s7=col[a+7];
      float2 u0=B2[s0], u1=B2[s1], u2=B2[s2], u3=B2[s3];
      float2 u4=B2[s4], u5=B2[s5], u6=B2[s6], u7=B2[s7];
      a0+=u0.x; a1+=u0.y; a0+=u1.x; a1+=u1.y;
      a0+=u2.x; a1+=u2.y; a0+=u3.x; a1+=u3.y;
      a0+=u4.x; a1+=u4.y; a0+=u5.x; a1+=u5.y;
      a0+=u6.x; a1+=u6.y; a0+=u7.x; a1+=u7.y;
    }
    for (; a+4<=b2; a+=4){
      int s0=col[a],s1=col[a+1],s2=col[a+2],s3=col[a+3];
      float2 u0=B2[s0], u1=B2[s1], u2=B2[s2], u3=B2[s3];
      a0+=u0.x; a1+=u0.y; a0+=u1.x; a1+=u1.y;
      a0+=u2.x; a1+=u2.y; a0+=u3.x; a1+=u3.y;
    }
    for (; a<b2; ++a){ float2 u=B2[col[a]]; a0+=u.x; a1+=u.y; }
    float v0 = a0 - field[run*64 + 0];
    float v1 = a1 - field[run*64 + 1];
    float m0=fmaxf(v0,v1), m1=fmaxf(v1,v0);
    float e0=expf(v0-m0), e1=expf(v1-m1);
    float s0=e0+e1, s1=e1+e0;
    float p0=e0/s0, p1=e1/s1;
    if (fin){
      float* o = nxt + (size_t)row*126 + CO;
      o[0]=p0; o[1]=p1;
    } else {
      ((float2*)(nxt  + (size_t)NN*CO))[row] = make_float2(p0,p1);
      ((float2*)(lnxt + (size_t)NN*CO))[row] = make_float2(log1pf(eb*p0), log1pf(eb*p1));
    }
  } else {
    int rw = idx >> L2T, ct = idx & (TPR-1);
    int row = graph*1024 + rw;
    const float4* B4 = (const float4*)(lcur + (size_t)NN*CO);
    float a0=0.f,a1=0.f,a2=0.f,a3=0.f;
    int a = rp[row], b2 = rp[row+1];
    for (; a+8<=b2; a+=8){
      int s0=col[a],s1=col[a+1],s2=col[a+2],s3=col[a+3];
      int s4=col[a+4],s5=col[a+5],s6=col[a+6],s7=col[a+7];
      float4 u0=B4[(size_t)s0*TPR+ct], u1=B4[(size_t)s1*TPR+ct];
      float4 u2=B4[(size_t)s2*TPR+ct], u3=B4[(size_t)s3*TPR+ct];
      float4 u4=B4[(size_t)s4*TPR+ct], u5=B4[(size_t)s5*TPR+ct];
      float4 u6=B4[(size_t)s6*TPR+ct], u7=B4[(size_t)s7*TPR+ct];
      a0+=u0.x; a1+=u0.y; a2+=u0.z; a3+=u0.w;
      a0+=u1.x; a1+=u1.y; a2+=u1.z; a3+=u1.w;
      a0+=u2.x; a1+=u2.y; a2+=u2.z; a3+=u2.w;
      a0+=u3.x; a1+=u3.y; a2+=u3.z; a3+=u3.w;
      a0+=u4.x; a1+=u4.y; a2+=u4.z; a3+=u4.w;
      a0+=u5.x; a1+=u5.y; a2+=u5.z; a3+=u5.w;
      a0+=u6.x; a1+=u6.y; a2+=u6.z; a3+=u6.w;
      a0+=u7.x; a1+=u7.y; a2+=u7.z; a3+=u7.w;
    }
    for (; a+4<=b2; a+=4){
      int s0=col[a],s1=col[a+1],s2=col[a+2],s3=col[a+3];
      float4 u0=B4[(size_t)s0*TPR+ct], u1=B4[(size_t)s1*TPR+ct];
      float4 u2=B4[(size_t)s2*TPR+ct], u3=B4[(size_t)s3*TPR+ct];
      a0+=u0.x; a1+=u0.y; a2+=u0.z; a3+=u0.w;
      a0+=u1.x; a1+=u1.y; a2+=u1.z; a3+=u1.w;
      a0+=u2.x; a1+=u2.y; a2+=u2.z; a3+=u2.w;
      a0+=u3.x; a1+=u3.y; a2+=u3.z; a3+=u3.w;
    }
    for (; a<b2; ++a){
      float4 u = B4[(size_t)col[a]*TPR+ct];
      a0+=u.x; a1+=u.y; a2+=u.z; a3+=u.w;
    }
    const float4 fld = *(const float4*)(field + run*64 + 4*ct);
    float v0 = a0 - fld.x, v1 = a1 - fld.y, v2 = a2 - fld.z, v3 = a3 - fld.w;
    float m0=v0,m1=v1,m2=v2,m3=v3;
    bfly_max4<TPR>(m0,m1,m2,m3);
    float e0=expf(v0-m0), e1=expf(v1-m1), e2=expf(v2-m2), e3=expf(v3-m3);
    float s0=e0,s1=e1,s2=e2,s3=e3;
    bfly_sum4<TPR>(s0,s1,s2,s3);
    float p0=e0/s0, p1=e1/s1, p2=e2/s2, p3=e3/s3;
    if (fin){
      float* o = nxt + (size_t)row*126 + CO + 4*ct;
      o[0]=p0; o[1]=p1; o[2]=p2; o[3]=p3;
    } else {
      ((float4*)(nxt  + (size_t)NN*CO))[(size_t)row*TPR+ct] = make_float4(p0,p1,p2,p3);
      ((float4*)(lnxt + (size_t)NN*CO))[(size_t)row*TPR+ct] =
          make_float4(log1pf(eb*p0), log1pf(eb*p1), log1pf(eb*p2), log1pf(eb*p3));
    }
  }
}

// bp_step + aux blocks (>= 8192): 1=gcn_agg, 2=mm30c, 3=pool(stage-1)
__global__ __launch_bounds__(256) void k_bp_step(
    float* __restrict__ nxt, const float* __restrict__ lcur, float* __restrict__ lnxt,
    const int* __restrict__ rp, const int* __restrict__ col,
    const float* __restrict__ field, const float* __restrict__ betas, int fin,
    int auxType, const float* __restrict__ aA, const float* __restrict__ aB,
    const float* __restrict__ aC, float* __restrict__ aO,
    float* __restrict__ agS, float* __restrict__ agQ,
    const float* __restrict__ adinv, const float* __restrict__ asfc,
    float* __restrict__ aconv){
  if (blockIdx.x >= 8192){
    __shared__ float smem[960];
    int ab = (int)blockIdx.x - 8192;
    int t = threadIdx.x;
    if (auxType == 1){
      float* binS = smem; float* binQ = smem + 32;
      if (t < 30){ binS[t]=0.f; binQ[t]=0.f; }
      __syncthreads();
      int xcd = ab & 7, i = ab >> 3;
      int gs = i/60, j = i - gs*60;
      int graph = gs*8 + xcd;
      int idwg = j*256 + t;
      int rw = idwg/15, pr = idwg - rw*15;
      int v = graph*1024 + rw;
      float dv = adinv[v];
      float accx = 0.f, accy = 0.f;
      int a = rp[v], e = rp[v+1];
      for (; a+4<=e; a+=4){
        int s0=col[a], s1=col[a+1], s2=col[a+2], s3=col[a+3];
        float d0=adinv[s0], d1=adinv[s1], d2=adinv[s2], d3=adinv[s3];
        float2 h0=*(const float2*)(aA+s0*30+2*pr), h1=*(const float2*)(aA+s1*30+2*pr);
        float2 h2=*(const float2*)(aA+s2*30+2*pr), h3=*(const float2*)(aA+s3*30+2*pr);
        accx += h0.x*(d0*dv); accy += h0.y*(d0*dv);
        accx += h1.x*(d1*dv); accy += h1.y*(d1*dv);
        accx += h2.x*(d2*dv); accy += h2.y*(d2*dv);
        accx += h3.x*(d3*dv); accy += h3.y*(d3*dv);
      }
      for (; a<e; ++a){
        int s = col[a];
        float w = adinv[s]*dv;
        float2 hv = *(const float2*)(aA+s*30+2*pr);
        accx += hv.x*w; accy += hv.y*w;
      }
      float2 hs = *(const float2*)(aA + v*30 + 2*pr);
      float w2 = dv*dv;
      accx += hs.x*w2; accy += hs.y*w2;   // self loop last (JAX concat order)
      float2 o; o.x = accx + aB[2*pr]; o.y = accy + aB[2*pr+1];
      *(float2*)(aO + v*30 + 2*pr) = o;
      atomicAdd(&binS[2*pr],   o.x); atomicAdd(&binQ[2*pr],   o.x*o.x);
      atomicAdd(&binS[2*pr+1], o.y); atomicAdd(&binQ[2*pr+1], o.y*o.y);
      __syncthreads();
      if (t < 30){
        int slot = (ab & 63)*30 + t;
        atomicAdd(&agS[slot], binS[t]);
        atomicAdd(&agQ[slot], binQ[t]);
      }
    } else if (auxType == 2){
      float* ws = smem; float* cl = smem + 904;
      for (int i=t;i<900;i+=256) ws[i] = aB[i];
      if (t < 30) cl[t] = aC[t];
      __syncthreads();
      int id = ab*256 + t;
      if (id < NN*30){
        int v = id/30, j = id - v*30;
        const float* xr = aA + v*30;
        float acc = cl[j];
        #pragma unroll
        for (int k=0;k<30;k++) acc += xr[k]*ws[k*30+j];
        aO[id] = acc;
      }
    } else if (auxType == 3){
      int b2 = ab & 63, a = ab >> 6;
      const float* X = (a==0)? aA : ((a==1)? aB : aC);
      const float* sf = asfc + a*64;
      float acc[30];
      #pragma unroll
      for (int f=0;f<30;f++) acc[f] = -FLT_MAX;
      for (int r=t; r<1024; r+=256){
        const float* xr = X + (size_t)(b2*1024 + r)*30;
        #pragma unroll
        for (int f=0;f<30;f++) acc[f] = fmaxf(acc[f], sf[f]*xr[f] + sf[32+f]);
      }
      #pragma unroll
      for (int off=32; off; off>>=1){
        #pragma unroll
        for (int f=0;f<30;f++) acc[f] = fmaxf(acc[f], __shfl_xor(acc[f], off, 64));
      }
      int w = t>>6, lane = t&63;
      if (lane == 0){
        #pragma unroll
        for (int f=0;f<30;f++) smem[w*30+f] = acc[f];
      }
      __syncthreads();
      if (t < 30)
        aconv[b2*180 + a*30 + t] =
          fmaxf(fmaxf(smem[t], smem[30+t]), fmaxf(smem[60+t], smem[90+t]));
    }
    return;
  }
  int graph, run, jj;
  bp_decode2(blockIdx.x, graph, run, jj);
  float eb = expm1f(betas[run]);
  switch(run){
    case 0: bp_step_elem2< 2, 0, 1,0>(graph, run, jj, lcur, nxt, lnxt, rp, col, field, eb, fin); break;
    case 1: bp_step_elem2< 4, 2, 1,0>(graph, run, jj, lcur, nxt, lnxt, rp, col, field, eb, fin); break;
    case 2: bp_step_elem2< 8, 6, 2,1>(graph, run, jj, lcur, nxt, lnxt, rp, col, field, eb, fin); break;
    case 3: bp_step_elem2<16,14, 4,2>(graph, run, jj, lcur, nxt, lnxt, rp, col, field, eb, fin); break;
    case 4: bp_step_elem2<32,30, 8,3>(graph, run, jj, lcur, nxt, lnxt, rp, col, field, eb, fin); break;
    default:bp_step_elem2<64,62,16,4>(graph, run, jj, lcur, nxt, lnxt, rp, col, field, eb, fin); break;
  }
}

// column sums over PACKED psi; order bit-identical
__global__ __launch_bounds__(64) void k_colsum_part(const float* __restrict__ psi_pk, float* __restrict__ part){
  int b = blockIdx.x;
  int xcd = b & 7, i = b >> 3;
  int gs = i/24, rem = i - gs*24;
  int run = rem >> 2, cg = rem & 3;
  int graph = gs*8 + xcd;
  int chunk = graph*4 + cg;
  int q = cQS[run];
  int co = (run==0)?0:(run==1)?2:(run==2)?6:(run==3)?14:(run==4)?30:62;
  int c = threadIdx.x;
  if (q >= 4){
    int nq = q >> 2;
    if (c >= nq) return;
    const float4* p4 = (const float4*)(psi_pk + (size_t)NN*co + (size_t)chunk*256*q) + c;
    float s0=0.f,s1=0.f,s2=0.f,s3=0.f;
    #pragma unroll 8
    for (int r=0;r<256;r++){
      float4 u = p4[(size_t)r*nq];
      s0+=u.x; s1+=u.y; s2+=u.z; s3+=u.w;
    }
    float* o = part + (run*256 + chunk)*64 + 4*c;
    o[0]=s0; o[1]=s1; o[2]=s2; o[3]=s3;
  } else {
    if (c >= q) return;
    float s = 0.f;
    const float* p = psi_pk + (size_t)NN*co + (size_t)chunk*256*q + c;
    #pragma unroll 8
    for (int r=0;r<256;r++) s += p[r*q];
    part[(run*256 + chunk)*64 + c] = s;
  }
}

// field (block 0) + optional bnw aux (block 1). 2 blocks x 384 thr.
__global__ void k_field(const float* __restrict__ part, const float* __restrict__ betas,
                        float* __restrict__ field,
                        int auxFold, float* __restrict__ gS, float* __restrict__ gQ, float n,
                        const float* __restrict__ g, const float* __restrict__ be,
                        const float* __restrict__ wnext, float* __restrict__ sfc,
                        float* __restrict__ wfold, float* __restrict__ cvec){
  if (blockIdx.x == 1){
    if (auxFold < 0) return;
    __shared__ float s_l[30], c_l[30];
    int t = threadIdx.x;
    if (t < 30){
      float s=0.f, q=0.f;
      for (int u=0;u<64;u++){ s += gS[u*30+t]; q += gQ[u*30+t]; }
      float m = s/n;
      float var = q/n - m*m;
      float sc = g[t]*(1.0f/sqrtf(var+1e-5f));
      float c0 = be[t] - sc*m;
      s_l[t]=sc; c_l[t]=c0;
      sfc[t]=sc; sfc[32+t]=c0;
      for (int u=0;u<64;u++){ gS[u*30+t]=0.f; gQ[u*30+t]=0.f; }
    }
    __syncthreads();
    if (auxFold == 1){
      for (int i=t;i<900;i+=384) wfold[i] = s_l[i/30]*wnext[i];
      if (t<30){
        float c=0.f;
        for (int k=0;k<30;k++) c += c_l[k]*wnext[k*30+t];
        cvec[t]=c;
      }
    }
    return;
  }
  int id = threadIdx.x;
  int run = id >> 6, c = id & 63;
  if (c >= cQS[run]) return;
  float s = 0.f;
  for (int b=0;b<256;b++) s += part[(run*256 + b)*64 + c];
  float beta = betas[run];
  field[id] = s * (3.8f*beta/65536.0f);
}

// ---------------- diff-pool ----------------
__global__ __launch_bounds__(256) void k_catT(const float* __restrict__ cat, float* __restrict__ catT){
  __shared__ float tile[64*127];
  int b = blockIdx.x, t = threadIdx.x;
  const float* src = cat + (size_t)b*64*126;
  for (int i=t;i<8064;i+=256){
    int r = i/126, k = i - r*126;
    tile[r*127 + k] = src[i];
  }
  __syncthreads();
  for (int i=t;i<8064;i+=256){
    int k = i>>6, r = i&63;
    catT[(size_t)k*65536 + b*64 + r] = tile[r*127 + k];
  }
}

__global__ __launch_bounds__(256) void k_s1t(const float* __restrict__ catT, const float* __restrict__ pw,
                                             const float* __restrict__ pb, float* __restrict__ s1){
  __shared__ float wl[12600];
  __shared__ float pbl[100];
  __shared__ float redM[2][128];
  __shared__ float redS[2][128];
  int t = threadIdx.x;
  for (int i=t;i<12600;i+=256) wl[i] = pw[i];
  if (t < 100) pbl[t] = pb[t];
  int w = t>>6, lane = t&63;
  int rh = w&1, chh = w>>1;
  int ch = chh*50;
  int row = blockIdx.x*128 + rh*64 + lane;
  __syncthreads();
  float acc[50];
  #pragma unroll
  for (int j=0;j<50;j++) acc[j] = pbl[ch+j];
  for (int k=0;k<126;k++){
    float xv = catT[(size_t)k*65536 + row];
    const float* wr = &wl[k*100 + ch];
    #pragma unroll
    for (int j=0;j<50;j+=2){
      float2 wv = *(const float2*)&wr[j];
      acc[j]   += xv*wv.x;
      acc[j+1] += xv*wv.y;
    }
  }
  float m = acc[0];
  #pragma unroll
  for (int j=1;j<50;j++) m = fmaxf(m, acc[j]);
  redM[chh][rh*64 + lane] = m;
  __syncthreads();
  float mm = fmaxf(redM[0][rh*64 + lane], redM[1][rh*64 + lane]);
  float s = 0.f;
  #pragma unroll
  for (int j=0;j<50;j++){ acc[j] = expf(acc[j]-mm); s += acc[j]; }
  redS[chh][rh*64 + lane] = s;
  __syncthreads();
  float tot = redS[0][rh*64 + lane] + redS[1][rh*64 + lane];
  float* o = s1 + (size_t)row*100 + ch;
  #pragma unroll
  for (int j=0;j<50;j+=2){
    float2 ov; ov.x = acc[j]/tot; ov.y = acc[j+1]/tot;
    *(float2*)&o[j] = ov;
  }
}

__global__ __launch_bounds__(256) void k_T(const float* __restrict__ s1, const int* __restrict__ rp,
                                           const int* __restrict__ col, float* __restrict__ T){
  int b = blockIdx.x;
  int xcd = b & 7, i = b >> 3;
  int gs = i/100, j = i - gs*100;
  int graph = gs*8 + xcd;
  int idwg = j*256 + threadIdx.x;
  int rw = idwg/25, quad = idwg - rw*25;
  int v = graph*1024 + rw;
  float a0=0.f,a1=0.f,a2=0.f,a3=0.f;
  const float4* S4 = (const float4*)s1;
  int a = rp[v], e = rp[v+1];
  for (; a+8<=e; a+=8){
    int s0=col[a], s1_=col[a+1], s2=col[a+2], s3=col[a+3];
    int s4=col[a+4], s5=col[a+5], s6=col[a+6], s7=col[a+7];
    float4 u0=S4[(size_t)s0*25+quad], u1=S4[(size_t)s1_*25+quad];
    float4 u2=S4[(size_t)s2*25+quad], u3=S4[(size_t)s3*25+quad];
    float4 u4=S4[(size_t)s4*25+quad], u5=S4[(size_t)s5*25+quad];
    float4 u6=S4[(size_t)s6*25+quad], u7=S4[(size_t)s7*25+quad];
    a0+=u0.x; a1+=u0.y; a2+=u0.z; a3+=u0.w;
    a0+=u1.x; a1+=u1.y; a2+=u1.z; a3+=u1.w;
    a0+=u2.x; a1+=u2.y; a2+=u2.z; a3+=u2.w;
    a0+=u3.x; a1+=u3.y; a2+=u3.z; a3+=u3.w;
    a0+=u4.x; a1+=u4.y; a2+=u4.z; a3+=u4.w;
    a0+=u5.x; a1+=u5.y; a2+=u5.z; a3+=u5.w;
    a0+=u6.x; a1+=u6.y; a2+=u6.z; a3+=u6.w;
    a0+=u7.x; a1+=u7.y; a2+=u7.z; a3+=u7.w;
  }
  for (; a+4<=e; a+=4){
    int s0=col[a], s1_=col[a+1], s2=col[a+2], s3=col[a+3];
    float4 u0=S4[(size_t)s0*25+quad], u1=S4[(size_t)s1_*25+quad];
    float4 u2=S4[(size_t)s2*25+quad], u3=S4[(size_t)s3*25+quad];
    a0+=u0.x; a1+=u0.y; a2+=u0.z; a3+=u0.w;
    a0+=u1.x; a1+=u1.y; a2+=u1.z; a3+=u1.w;
    a0+=u2.x; a1+=u2.y; a2+=u2.z; a3+=u2.w;
    a0+=u3.x; a1+=u3.y; a2+=u3.z; a3+=u3.w;
  }
  for (; a<e; ++a){
    float4 u = S4[(size_t)col[a]*25+quad];
    a0+=u.x; a1+=u.y; a2+=u.z; a3+=u.w;
  }
  ((float4*)T)[(size_t)v*25 + quad] = make_float4(a0,a1,a2,a3);
}

// merged split-K: blocks 0..255 = p1adj, 256..511 = p1x (BN affine on fill)
__global__ __launch_bounds__(512) void k_p1ax(const float* __restrict__ s1, const float* __restrict__ T,
                                              const float* __restrict__ y3, const float* __restrict__ sfc,
                                              float* __restrict__ partA, float* __restrict__ partX){
  __shared__ float sS[6400];
  __shared__ float sT[6400];
  int t = threadIdx.x;
  if (blockIdx.x < 256){
    int blk = blockIdx.x;
    int b = blk >> 2, qtr = blk & 3;
    int tk = t/20, tl = t - tk*20;
    bool act = t < 500;
    int k0 = tk*4, l0 = tl*5;
    float acc[4][5];
    #pragma unroll
    for (int i=0;i<4;i++)
      #pragma unroll
      for (int j=0;j<5;j++) acc[i][j] = 0.f;
    const float* s1b = s1 + (size_t)b*102400;
    const float* Tb  = T  + (size_t)b*102400;
    for (int c=qtr*4; c<qtr*4+4; c++){
      for (int i=t;i<6400;i+=512){ sS[i] = s1b[c*6400+i]; sT[i] = Tb[c*6400+i]; }
      __syncthreads();
      if (act){
        #pragma unroll 2
        for (int n=0;n<64;n++){
          const float* sr = &sS[n*100 + k0];
          const float* tr = &sT[n*100 + l0];
          float s0=sr[0], s1v=sr[1], s2=sr[2], s3=sr[3];
          float t0=tr[0], t1=tr[1], t2=tr[2], t3=tr[3], t4=tr[4];
          acc[0][0]+=s0*t0; acc[0][1]+=s0*t1; acc[0][2]+=s0*t2; acc[0][3]+=s0*t3; acc[0][4]+=s0*t4;
          acc[1][0]+=s1v*t0; acc[1][1]+=s1v*t1; acc[1][2]+=s1v*t2; acc[1][3]+=s1v*t3; acc[1][4]+=s1v*t4;
          acc[2][0]+=s2*t0; acc[2][1]+=s2*t1; acc[2][2]+=s2*t2; acc[2][3]+=s2*t3; acc[2][4]+=s2*t4;
          acc[3][0]+=s3*t0; acc[3][1]+=s3*t1; acc[3][2]+=s3*t2; acc[3][3]+=s3*t3; acc[3][4]+=s3*t4;
        }
      }
      __syncthreads();
    }
    if (act){
      float* pp = partA + (size_t)qtr*640000 + (size_t)b*10000;
      #pragma unroll
      for (int i=0;i<4;i++){
        float* o = pp + (k0+i)*100 + l0;
        #pragma unroll
        for (int j=0;j<5;j++) o[j] = acc[i][j];
      }
    }
  } else {
    int blk = blockIdx.x - 256;
    int b = blk >> 2, qtr = blk & 3;
    float* sX = sT;
    int tk = t/10, tl = t - tk*10;
    bool act = t < 250;
    int k0 = tk*4, d0 = tl*3;
    float acc[4][3];
    #pragma unroll
    for (int i=0;i<4;i++)
      #pragma unroll
      for (int j=0;j<3;j++) acc[i][j] = 0.f;
    const float* s1b = s1 + (size_t)b*102400;
    const float* xb  = y3 + (size_t)b*30720;
    for (int c=qtr*4; c<qtr*4+4; c++){
      for (int i=t;i<6400;i+=512) sS[i] = s1b[c*6400+i];
      for (int i=t;i<1920;i+=512){
        int f = i % 30;
        sX[i] = sfc[f]*xb[c*1920+i] + sfc[32+f];
      }
      __syncthreads();
      if (act){
        #pragma unroll 2
        for (int n=0;n<64;n++){
          const float* sr = &sS[n*100 + k0];
          const float* xr = &sX[n*30 + d0];
          float s0=sr[0], s1v=sr[1], s2=sr[2], s3=sr[3];
          float x0=xr[0], x1=xr[1], x2=xr[2];
          acc[0][0]+=s0*x0; acc[0][1]+=s0*x1; acc[0][2]+=s0*x2;
          acc[1][0]+=s1v*x0; acc[1][1]+=s1v*x1; acc[1][2]+=s1v*x2;
          acc[2][0]+=s2*x0; acc[2][1]+=s2*x1; acc[2][2]+=s2*x2;
          acc[3][0]+=s3*x0; acc[3][1]+=s3*x1; acc[3][2]+=s3*x2;
        }
      }
      __syncthreads();
    }
    if (act){
      float* pp = partX + (size_t)qtr*192000 + (size_t)b*3000;
      #pragma unroll
      for (int i=0;i<4;i++){
        float* o = pp + (k0+i)*30 + d0;
        #pragma unroll
        for (int j=0;j<3;j++) o[j] = acc[i][j];
      }
    }
  }
}

// blocks 0..63: reduce padj parts + normalize -> An; 64..813: px reduce
__global__ __launch_bounds__(256) void k_anpx(const float* __restrict__ pA, const float* __restrict__ pX,
                                              float* __restrict__ An, float* __restrict__ px){
  if (blockIdx.x < 64){
    __shared__ float pj[10000];
    __shared__ float dv[100];
    int b = blockIdx.x, t = threadIdx.x;
    size_t base = (size_t)b*10000;
    for (int i=t;i<10000;i+=256)
      pj[i] = pA[base+i] + pA[640000+base+i] + pA[1280000+base+i] + pA[1920000+base+i];
    __syncthreads();
    if (t < 100){
      const float* r = pj + t*100;
      float s = 0.f;
      for (int l=0;l<100;l++){
        float v = r[l];
        if (l==t) v += 1.0f;
        s += v;
      }
      dv[t] = 1.0f/sqrtf(s);
    }
    __syncthreads();
    for (int i=t;i<10000;i+=256){
      int k = i/100, l = i - k*100;
      float a = pj[i] + ((k==l)? 1.0f : 0.0f);
      An[base + i] = (dv[k]*a)*dv[l];
    }
  } else {
    int id = ((int)blockIdx.x - 64)*256 + threadIdx.x;
    if (id < 192000)
      px[id] = pX[id] + pX[192000+id] + pX[384000+id] + pX[576000+id];
  }
}

// ---------------- stage-2 dense GCN ----------------
__global__ __launch_bounds__(256) void k_y2(const float* __restrict__ An, const float* __restrict__ h,
    const float* __restrict__ bias, float* __restrict__ y,
    float* __restrict__ gS, float* __restrict__ gQ){
  __shared__ float binS[30], binQ[30];
  int t = threadIdx.x;
  if (t < 30){ binS[t]=0.f; binQ[t]=0.f; }
  __syncthreads();
  int id = blockIdx.x*256 + t;
  if (id < NBG*100*30){
    int d = id % 30;
    int bk = id / 30;
    int b = bk / 100;
    const float* Ar = An + bk*100;
    const float* hb = h + b*100*30;
    float acc = 0.f;
    for (int l=0;l<100;l++) acc += Ar[l]*hb[l*30+d];
    float val = acc + bias[d];
    y[id] = val;
    atomicAdd(&binS[d], val);
    atomicAdd(&binQ[d], val*val);
  }
  __syncthreads();
  if (t < 30){
    int slot = (blockIdx.x & 63)*30 + t;
    atomicAdd(&gS[slot], binS[t]);
    atomicAdd(&gQ[slot], binQ[t]);
  }
}

// stage-2 pool (big-LDS variant, separate launch)
__global__ __launch_bounds__(256) void k_pool2(const float* __restrict__ A,
    const float* __restrict__ Bv, const float* __restrict__ Cv,
    const float* __restrict__ sfcBase,
    int rows, float* __restrict__ conv, int coff){
  __shared__ float lds[256*31];
  int b = blockIdx.x, a = blockIdx.y, t = threadIdx.x;
  const float* X = (a==0)? A : ((a==1)? Bv : Cv);
  const float* sf = sfcBase + a*64;
  float acc[30];
  #pragma unroll
  for (int f=0;f<30;f++) acc[f] = -FLT_MAX;
  for (int r=t; r<rows; r+=256){
    const float* xr = X + (size_t)(b*rows + r)*30;
    #pragma unroll
    for (int f=0;f<30;f++) acc[f] = fmaxf(acc[f], sf[f]*xr[f] + sf[32+f]);
  }
  #pragma unroll
  for (int f=0;f<30;f++) lds[t*31+f] = acc[f];
  __syncthreads();
  for (int s=128;s>0;s>>=1){
    if (t<s){
      #pragma unroll
      for (int f=0;f<30;f++) lds[t*31+f] = fmaxf(lds[t*31+f], lds[(t+s)*31+f]);
    }
    __syncthreads();
  }
  if (t<30) conv[b*180 + coff + a*30 + t] = lds[t];
}

__global__ __launch_bounds__(64) void k_fc(const float* __restrict__ conv,
    const float* __restrict__ w1, const float* __restrict__ b1,
    const float* __restrict__ w2, const float* __restrict__ b2, float* __restrict__ out){
  __shared__ float row[180];
  __shared__ float hid[50];
  int b = blockIdx.x, t = threadIdx.x;
  for (int i=t;i<180;i+=64) row[i] = conv[b*180+i];
  __syncthreads();
  if (t < 50){
    float a = b1[t];
    for (int i=0;i<180;i++) a += row[i]*w1[i*50+t];
    hid[t] = fmaxf(a, 0.f);
  }
  __syncthreads();
  if (t < 6){
    float a = b2[t];
    for (int i=0;i<50;i++) a += hid[i]*w2[i*6+t];
    out[b*6+t] = a;
  }
  if (b==0 && t==63) out[NBG*6] = 0.0f;
}

// ---------------------------------------------------------------------------
extern "C" void kernel_launch(void* const* d_in, const int* in_sizes, int n_in,
                              void* d_out, int out_size, void* d_ws, size_t ws_size,
                              hipStream_t stream)
{
  (void)in_sizes; (void)n_in; (void)out_size; (void)ws_size;
  const float* x   = (const float*)d_in[0];
  const int*   src = (const int*)d_in[1];
  const int*   dst = src + NEDGE;
  const float* w11=(const float*)d_in[3],  *b11=(const float*)d_in[4],  *g11=(const float*)d_in[5],  *be11=(const float*)d_in[6];
  const float* w12=(const float*)d_in[7],  *b12=(const float*)d_in[8],  *g12=(const float*)d_in[9],  *be12=(const float*)d_in[10];
  const float* w13=(const float*)d_in[11], *b13=(const float*)d_in[12], *g13=(const float*)d_in[13], *be13=(const float*)d_in[14];
  const float* w21=(const float*)d_in[15], *b21=(const float*)d_in[16], *g21=(const float*)d_in[17], *be21=(const float*)d_in[18];
  const float* w22=(const float*)d_in[19], *b22=(const float*)d_in[20], *g22=(const float*)d_in[21], *be22=(const float*)d_in[22];
  const float* w23=(const float*)d_in[23], *b23=(const float*)d_in[24], *g23=(const float*)d_in[25], *be23=(const float*)d_in[26];
  const float* betas=(const float*)d_in[27];
  const float* poolw=(const float*)d_in[28], *poolb=(const float*)d_in[29];
  const float* fc1w=(const float*)d_in[30], *fc1b=(const float*)d_in[31];
  const float* fc2w=(const float*)d_in[32], *fc2b=(const float*)d_in[33];
  float* out = (float*)d_out;

  uint8_t* basep = (uint8_t*)d_ws;
  size_t off = 0;
  auto take = [&](size_t bytes)->void*{
    void* p = basep + off;
    off = (off + bytes + 255) & ~(size_t)255;
    return p;
  };
  int* degi    = (int*)take((size_t)NN*4);
  int* dego    = (int*)take((size_t)NN*4);
  int* cntA    = (int*)take((size_t)NN*4);
  int* cntB    = (int*)take((size_t)NN*4);
  float* gS    = (float*)take(64*30*4);     // BN stat slots (zeroed by memset)
  float* gQ    = (float*)take(64*30*4);
  int* rp_in   = (int*)take((size_t)(NN+1)*4);
  int* rp_out  = (int*)take((size_t)(NN+1)*4);
  int* bsum    = (int*)take(512*4);
  int* col_in  = (int*)take((size_t)NEDGE*4);
  int* col_out = (int*)take((size_t)NEDGE*4);
  float* dinv  = (float*)take((size_t)NN*4);
  float* hbuf  = (float*)take((size_t)NN*30*4);
  float* X1    = (float*)take((size_t)NN*30*4);   // pre-BN y1
  float* X2    = (float*)take((size_t)NN*30*4);   // pre-BN y2
  float* X3    = (float*)take((size_t)NN*30*4);   // pre-BN y3
  float* bufA  = (float*)take((size_t)NN*126*4);
  float* bufB  = (float*)take((size_t)NN*126*4);
  float* logA  = (float*)take((size_t)NN*126*4);
  float* logB  = (float*)take((size_t)NN*126*4);
  float* partCS= (float*)take((size_t)6*256*64*4);
  float* fieldv= (float*)take(384*4);
  float* sfcAll= (float*)take(6*64*4);
  float* wfold = (float*)take(960*4);
  float* cvec  = (float*)take(32*4);
  float* px    = (float*)take(192000*4);
  float* An    = (float*)take(640000*4);
  float* h2    = (float*)take(192000*4);
  float* X21   = (float*)take(192000*4);  // pre-BN
  float* X22   = (float*)take(192000*4);
  float* X23   = (float*)take(192000*4);
  float* conv  = (float*)take(64*180*4);

  // post-BP scratch reuse: catT -> logA; split-K partials -> logB
  float* catT     = logA;
  float* pAdjPart = logB;               // 4*640000 floats
  float* pPxPart  = logB + 2560000;     // 4*192000 floats

  // ---- CSR + stat zero (degi..gQ contiguous -> single memset) ----
  hipMemsetAsync(degi, 0, (size_t)4*NN*4 + 2*64*30*4, stream);
  k_count<<<2048,256,0,stream>>>(src,dst,degi,dego);
  k_scan1<<<dim3(256,2),256,0,stream>>>(degi, dego, rp_in, rp_out, bsum);
  k_scan2<<<2,256,0,stream>>>(bsum);
  k_scan3<<<dim3(256,2),256,0,stream>>>(rp_in, rp_out, bsum);
  k_fill<<<dim3(2048,2),256,0,stream>>>(src, dst, rp_in, rp_out, cntA, cntB, col_in, col_out);
  k_sortrow<<<dim3(256,2),256,0,stream>>>(rp_in, rp_out, col_in, col_out, src, dst, degi, dinv);

  // ---- BP with stage-1 hidden as aux blocks ----
  k_bp_first<<<15872,256,0,stream>>>(bufA, logA, betas, x, w11, hbuf);  // + mm30<3>

  float* cur = bufA;  float* nxt = bufB;
  float* lcur = logA; float* lnxt = logB;
  for (int it=0; it<10; ++it){
    k_colsum_part<<<1536,64,0,stream>>>(cur, partCS);
    // field + optional bnw aux (iters 1,3,5)
    int fold = (it==1||it==3)? 1 : ((it==5)? 0 : -1);
    const float* gg = (it==1)? g11 : ((it==3)? g12 : g13);
    const float* bb = (it==1)? be11: ((it==3)? be12: be13);
    const float* wn = (it==1)? w12 : ((it==3)? w13 : nullptr);
    float* sfc = (it==1)? sfcAll : ((it==3)? sfcAll+64 : sfcAll+128);
    k_field<<<2,384,0,stream>>>(partCS, betas, fieldv, fold, gS, gQ, 65536.f,
                                gg, bb, wn, sfc, wfold, cvec);
    int fin = (it==9);
    int auxType = 0, auxN = 0;
    const float *aA=nullptr, *aB=nullptr, *aC=nullptr; float *aO=nullptr;
    if      (it==0){ auxType=1; auxN=3840; aA=hbuf; aB=b11; aO=X1; }
    else if (it==1){ auxType=2; auxN=7680; aA=X1; aB=wfold; aC=cvec; aO=hbuf; }
    else if (it==2){ auxType=1; auxN=3840; aA=hbuf; aB=b12; aO=X2; }
    else if (it==3){ auxType=2; auxN=7680; aA=X2; aB=wfold; aC=cvec; aO=hbuf; }
    else if (it==4){ auxType=1; auxN=3840; aA=hbuf; aB=b13; aO=X3; }
    else if (it==5){ auxType=3; auxN=192;  aA=X1; aB=X2; aC=X3; }
    k_bp_step<<<8192+auxN,256,0,stream>>>(nxt, lcur, lnxt, rp_in, col_in, fieldv, betas, fin,
        auxType, aA, aB, aC, aO, gS, gQ, dinv, sfcAll, conv);
    float* tp = cur;  cur = nxt;   nxt = tp;
    float* tl = lcur; lcur = lnxt; lnxt = tl;
  }
  // final concatenated psi [NN][126] now in bufA

  // ---- diff-pool ----
  k_catT<<<1024,256,0,stream>>>(bufA, catT);
  k_s1t<<<512,256,0,stream>>>(catT, poolw, poolb, bufB);
  k_T<<<6400,256,0,stream>>>(bufB, rp_out, col_out, bufA);
  k_p1ax<<<512,512,0,stream>>>(bufB, bufA, X3, sfcAll+128, pAdjPart, pPxPart);
  k_anpx<<<814,256,0,stream>>>(pAdjPart, pPxPart, An, px);

  // ---- stage 2: dense GCN x3 with folded BN ----
  k_mm30<30><<<750,256,0,stream>>>(px, w21, h2, NBG*100);
  k_y2<<<750,256,0,stream>>>(An, h2, b21, X21, gS, gQ);
  k_bnw<1><<<1,256,0,stream>>>(gS, gQ, 6400.f, g21, be21, w22, sfcAll+3*64, wfold, cvec);
  k_mm30c<<<750,256,0,stream>>>(X21, wfold, cvec, h2, NBG*100);
  k_y2<<<750,256,0,stream>>>(An, h2, b22, X22, gS, gQ);
  k_bnw<1><<<1,256,0,stream>>>(gS, gQ, 6400.f, g22, be22, w23, sfcAll+4*64, wfold, cvec);
  k_mm30c<<<750,256,0,stream>>>(X22, wfold, cvec, h2, NBG*100);
  k_y2<<<750,256,0,stream>>>(An, h2, b23, X23, gS, gQ);
  k_bnw<0><<<1,256,0,stream>>>(gS, gQ, 6400.f, g23, be23, nullptr, sfcAll+5*64, nullptr, nullptr);
  k_pool2<<<dim3(NBG,3),256,0,stream>>>(X21, X22, X23, sfcAll+3*64, 100, conv, 90);

  // ---- FC head ----
  k_fc<<<64,64,0,stream>>>(conv, fc1w, fc1b, fc2w, fc2b, out);
}

// Round 16
// 1181.930 us; speedup vs baseline: 1.6580x; 1.0425x over previous
//
#include <hip/hip_runtime.h>
#include <stdint.h>
#include <float.h>

// ---------------------------------------------------------------------------
// Net_57604101374728: GCN(x3)+BN -> maxpool | 6x belief-prop -> diffpool ->
// dense GCN(x3)+BN -> maxpool -> FC. Full fp32 port of the JAX reference.
//
// R16: stage-1 aux work moved from bp_step (50%-busy) to colsum (95%-idle
// 64-thr launch): colsum repacked 384x256 (same per-chunk sequential sums ->
// field bit-exact) + aux blocks appended. bp_step now pure (~50us). Final
// bp_step writes psi directly in catT [126][NN] layout -> k_catT eliminated.
// BP arithmetic identical to R15.
// ---------------------------------------------------------------------------

constexpr int NN    = 65536;    // total nodes
constexpr int NEDGE = 524288;   // edges
constexpr int NBG   = 64;       // graphs

__constant__ int cQS[6]   = {2,4,8,16,32,64};

// ---------------- threefry2x32 (20 rounds) ----------------
__device__ __forceinline__ void tf2x32(uint32_t k0, uint32_t k1, uint32_t x0, uint32_t x1,
                                       uint32_t& o0, uint32_t& o1){
  uint32_t ks[3] = {k0, k1, k0 ^ k1 ^ 0x1BD11BDAu};
  x0 += ks[0]; x1 += ks[1];
  const int RA[4] = {13,15,26,6}, RB[4] = {17,29,16,24};
  #pragma unroll
  for (int i=0;i<5;i++){
    const int* r = (i&1)? RB : RA;
    #pragma unroll
    for (int j=0;j<4;j++){
      x0 += x1;
      x1 = (x1 << r[j]) | (x1 >> (32 - r[j]));
      x1 ^= x0;
    }
    x0 += ks[(i+1)%3];
    x1 += ks[(i+2)%3] + (uint32_t)(i+1);
  }
  o0 = x0; o1 = x1;
}

// ---------------- XLA ErfInv32 (Giles), contraction off ----------------
__device__ __forceinline__ float erfinv32(float xx){
  #pragma clang fp contract(off)
  float w = -log1pf(-xx*xx);
  float p;
  if (w < 5.0f){
    w = w - 2.5f;
    p = 2.81022636e-08f;
    p = 3.43273939e-07f  + p*w;
    p = -3.5233877e-06f  + p*w;
    p = -4.39150654e-06f + p*w;
    p = 0.00021858087f   + p*w;
    p = -0.00125372503f  + p*w;
    p = -0.00417768164f  + p*w;
    p = 0.246640727f     + p*w;
    p = 1.50140941f      + p*w;
  } else {
    w = sqrtf(w) - 3.0f;
    p = -0.000200214257f;
    p = 0.000100950558f  + p*w;
    p = 0.00134934322f   + p*w;
    p = -0.00367342844f  + p*w;
    p = 0.00573950773f   + p*w;
    p = -0.0076224613f   + p*w;
    p = 0.00943887047f   + p*w;
    p = 1.00167406f      + p*w;
    p = 2.83297682f      + p*w;
  }
  return p*xx;
}

// ---------------- CSR construction (fused pairs via blockIdx.y) ----------
__global__ __launch_bounds__(256) void k_count(const int* __restrict__ src, const int* __restrict__ dst,
                                               int* __restrict__ degi, int* __restrict__ dego){
  int e = blockIdx.x*256 + threadIdx.x;
  if (e >= NEDGE) return;
  atomicAdd(&degi[dst[e]], 1);
  atomicAdd(&dego[src[e]], 1);
}

__global__ __launch_bounds__(256) void k_scan1(const int* __restrict__ degi, const int* __restrict__ dego,
                                               int* __restrict__ rpi, int* __restrict__ rpo,
                                               int* __restrict__ bsum){
  __shared__ int lds[256];
  const int* deg = blockIdx.y? dego : degi;
  int* rp = blockIdx.y? rpo : rpi;
  int* bs = bsum + blockIdx.y*256;
  int b = blockIdx.x, t = threadIdx.x;
  lds[t] = deg[b*256 + t];
  __syncthreads();
  for (int s=1;s<256;s<<=1){
    int add = (t>=s)? lds[t-s] : 0;
    __syncthreads();
    lds[t] += add;
    __syncthreads();
  }
  rp[b*256 + t + 1] = lds[t];
  if (t==0 && b==0) rp[0] = 0;
  if (t==255) bs[b] = lds[255];
}

__global__ __launch_bounds__(256) void k_scan2(int* __restrict__ bsum){
  __shared__ int lds[256];
  int* bs = bsum + blockIdx.x*256;
  int t = threadIdx.x;
  lds[t] = bs[t];
  __syncthreads();
  for (int s=1;s<256;s<<=1){
    int add = (t>=s)? lds[t-s] : 0;
    __syncthreads();
    lds[t] += add;
    __syncthreads();
  }
  bs[t] = (t==0)? 0 : lds[t-1];
}

__global__ __launch_bounds__(256) void k_scan3(int* __restrict__ rpi, int* __restrict__ rpo,
                                               const int* __restrict__ bsum){
  int* rp = blockIdx.y? rpo : rpi;
  const int* bs = bsum + blockIdx.y*256;
  int b = blockIdx.x, t = threadIdx.x;
  rp[b*256 + t + 1] += bs[b];
}

__global__ __launch_bounds__(256) void k_fill(const int* __restrict__ src, const int* __restrict__ dst,
                                              const int* __restrict__ rpi, const int* __restrict__ rpo,
                                              int* __restrict__ cntA, int* __restrict__ cntB,
                                              int* __restrict__ colI, int* __restrict__ colO){
  int e = blockIdx.x*256 + threadIdx.x;
  if (e >= NEDGE) return;
  if (blockIdx.y == 0){
    int d = dst[e];
    int p = atomicAdd(&cntA[d], 1);
    colI[rpi[d] + p] = e;
  } else {
    int d = src[e];
    int p = atomicAdd(&cntB[d], 1);
    colO[rpo[d] + p] = e;
  }
}

__global__ __launch_bounds__(256) void k_sortrow(const int* __restrict__ rpi, const int* __restrict__ rpo,
                                                 int* __restrict__ colI, int* __restrict__ colO,
                                                 const int* __restrict__ src, const int* __restrict__ dst,
                                                 const int* __restrict__ degi, float* __restrict__ dinv){
  const int* rp = blockIdx.y? rpo : rpi;
  int* colbuf   = blockIdx.y? colO : colI;
  const int* other = blockIdx.y? dst : src;
  int v = blockIdx.x*256 + threadIdx.x;
  if (v >= NN) return;
  int s0 = rp[v], s1 = rp[v+1];
  for (int i=s0+1;i<s1;i++){
    int key = colbuf[i]; int j = i-1;
    while (j>=s0 && colbuf[j]>key){ colbuf[j+1]=colbuf[j]; j--; }
    colbuf[j+1] = key;
  }
  for (int i=s0;i<s1;i++) colbuf[i] = other[colbuf[i]];
  if (blockIdx.y == 0) dinv[v] = 1.0f / sqrtf((float)(degi[v] + 1));
}

// ---------------- stage-2 GEMM helpers (standalone) ----------------
template<int CIN>
__global__ __launch_bounds__(256) void k_mm30(const float* __restrict__ x, const float* __restrict__ w,
                                              float* __restrict__ h, int nrow){
  __shared__ float ws[CIN*30];
  int t = threadIdx.x;
  for (int i=t;i<CIN*30;i+=256) ws[i] = w[i];
  __syncthreads();
  int id = blockIdx.x*256 + t;
  if (id >= nrow*30) return;
  int v = id/30, j = id - v*30;
  const float* xr = x + v*CIN;
  float acc = 0.f;
  #pragma unroll
  for (int k=0;k<CIN;k++) acc += xr[k]*ws[k*30+j];
  h[id] = acc;
}

__global__ __launch_bounds__(256) void k_mm30c(const float* __restrict__ x, const float* __restrict__ wfold,
                                               const float* __restrict__ cvec, float* __restrict__ h, int nrow){
  __shared__ float ws[900];
  __shared__ float cl[30];
  int t = threadIdx.x;
  for (int i=t;i<900;i+=256) ws[i] = wfold[i];
  if (t < 30) cl[t] = cvec[t];
  __syncthreads();
  int id = blockIdx.x*256 + t;
  if (id >= nrow*30) return;
  int v = id/30, j = id - v*30;
  const float* xr = x + v*30;
  float acc = cl[j];
  #pragma unroll
  for (int k=0;k<30;k++) acc += xr[k]*ws[k*30+j];
  h[id] = acc;
}

// BN finalize (standalone, stage-2)
template<int FOLD>
__global__ __launch_bounds__(256) void k_bnw(float* __restrict__ gS, float* __restrict__ gQ, float n,
    const float* __restrict__ g, const float* __restrict__ be,
    const float* __restrict__ wnext, float* __restrict__ sfc,
    float* __restrict__ wfold, float* __restrict__ cvec){
  __shared__ float s_l[30], c_l[30];
  int t = threadIdx.x;
  if (t < 30){
    float s=0.f, q=0.f;
    for (int u=0;u<64;u++){ s += gS[u*30+t]; q += gQ[u*30+t]; }
    float m = s/n;
    float var = q/n - m*m;
    float sc = g[t]*(1.0f/sqrtf(var+1e-5f));
    float c0 = be[t] - sc*m;
    s_l[t]=sc; c_l[t]=c0;
    sfc[t]=sc; sfc[32+t]=c0;
    for (int u=0;u<64;u++){ gS[u*30+t]=0.f; gQ[u*30+t]=0.f; }
  }
  __syncthreads();
  if (FOLD){
    for (int i=t;i<900;i+=256) wfold[i] = s_l[i/30]*wnext[i];
    if (t<30){
      float c=0.f;
      for (int k=0;k<30;k++) c += c_l[k]*wnext[k*30+t];
      cvec[t]=c;
    }
  }
}

// ---------------- belief propagation (col-vectorized, XCD-resident) -------
__device__ __forceinline__ void bp_decode2(int b, int& graph, int& run, int& jj){
  int xcd = b & 7, i = b >> 3;
  int gs = i >> 7, j = i & 127;
  if      (j <   4){ run=0; jj=j;    }
  else if (j <   8){ run=1; jj=j-4;  }
  else if (j <  16){ run=2; jj=j-8;  }
  else if (j <  32){ run=3; jj=j-16; }
  else if (j <  64){ run=4; jj=j-32; }
  else             { run=5; jj=j-64; }
  graph = gs*8 + xcd;
}

template<int TPR>
__device__ __forceinline__ void bfly_max4(float& m0, float& m1, float& m2, float& m3){
  if constexpr (TPR > 1){
    #pragma unroll
    for (int lm = TPR>>1; lm; lm >>= 1){
      float p0=__shfl_xor(m0,lm,64), p1=__shfl_xor(m1,lm,64);
      float p2=__shfl_xor(m2,lm,64), p3=__shfl_xor(m3,lm,64);
      m0=fmaxf(m0,p0); m1=fmaxf(m1,p1); m2=fmaxf(m2,p2); m3=fmaxf(m3,p3);
    }
  }
  { float t0=fmaxf(m0,m2), t1=fmaxf(m1,m3), t2=fmaxf(m2,m0), t3=fmaxf(m3,m1);
    m0=t0; m1=t1; m2=t2; m3=t3; }
  { float t0=fmaxf(m0,m1), t1=fmaxf(m1,m0), t2=fmaxf(m2,m3), t3=fmaxf(m3,m2);
    m0=t0; m1=t1; m2=t2; m3=t3; }
}

template<int TPR>
__device__ __forceinline__ void bfly_sum4(float& s0, float& s1, float& s2, float& s3){
  if constexpr (TPR > 1){
    #pragma unroll
    for (int lm = TPR>>1; lm; lm >>= 1){
      float p0=__shfl_xor(s0,lm,64), p1=__shfl_xor(s1,lm,64);
      float p2=__shfl_xor(s2,lm,64), p3=__shfl_xor(s3,lm,64);
      s0 += p0; s1 += p1; s2 += p2; s3 += p3;
    }
  }
  { float t0=s0+s2, t1=s1+s3, t2=s2+s0, t3=s3+s1;
    s0=t0; s1=t1; s2=t2; s3=t3; }
  { float t0=s0+s1, t1=s1+s0, t2=s2+s3, t3=s3+s2;
    s0=t0; s1=t1; s2=t2; s3=t3; }
}

template<int Q, int CO, int TPR, int L2T>
__device__ __forceinline__ void bp_first_elem2(int graph, int jj, float* __restrict__ psi_pk,
                                               float* __restrict__ lg, float eb,
                                               uint32_t k0, uint32_t k1){
  int idx = jj*256 + (int)threadIdx.x;
  if constexpr (Q == 2){
    int row = graph*1024 + idx;
    float z[2];
    #pragma unroll
    for (int r=0;r<2;r++){
      uint32_t b0,b1;
      tf2x32(k0,k1, 0u, (uint32_t)(row*2 + r), b0,b1);
      uint32_t bits = b0 ^ b1;
      float f = __uint_as_float((bits>>9) | 0x3F800000u) - 1.0f;
      const float lo = __uint_as_float(0xBF7FFFFFu);
      float u = fmaxf(lo, f*2.0f + lo);
      z[r] = __uint_as_float(0x3FB504F3u) * erfinv32(u);
    }
    float m0=fmaxf(z[0],z[1]), m1=fmaxf(z[1],z[0]);
    float e0=expf(z[0]-m0), e1=expf(z[1]-m1);
    float s0=e0+e1, s1=e1+e0;
    float p0=e0/s0, p1=e1/s1;
    ((float2*)(psi_pk + (size_t)NN*CO))[row] = make_float2(p0,p1);
    ((float2*)(lg     + (size_t)NN*CO))[row] = make_float2(log1pf(eb*p0), log1pf(eb*p1));
  } else {
    int rw = idx >> L2T, ct = idx & (TPR-1);
    int row = graph*1024 + rw;
    float z[4];
    #pragma unroll
    for (int r=0;r<4;r++){
      uint32_t b0,b1;
      tf2x32(k0,k1, 0u, (uint32_t)(row*Q + 4*ct + r), b0,b1);
      uint32_t bits = b0 ^ b1;
      float f = __uint_as_float((bits>>9) | 0x3F800000u) - 1.0f;
      const float lo = __uint_as_float(0xBF7FFFFFu);
      float u = fmaxf(lo, f*2.0f + lo);
      z[r] = __uint_as_float(0x3FB504F3u) * erfinv32(u);
    }
    float m0=z[0],m1=z[1],m2=z[2],m3=z[3];
    bfly_max4<TPR>(m0,m1,m2,m3);
    float e0=expf(z[0]-m0), e1=expf(z[1]-m1), e2=expf(z[2]-m2), e3=expf(z[3]-m3);
    float s0=e0,s1=e1,s2=e2,s3=e3;
    bfly_sum4<TPR>(s0,s1,s2,s3);
    float p0=e0/s0, p1=e1/s1, p2=e2/s2, p3=e3/s3;
    ((float4*)(psi_pk + (size_t)NN*CO))[(size_t)row*TPR + ct] = make_float4(p0,p1,p2,p3);
    ((float4*)(lg     + (size_t)NN*CO))[(size_t)row*TPR + ct] =
        make_float4(log1pf(eb*p0), log1pf(eb*p1), log1pf(eb*p2), log1pf(eb*p3));
  }
}

// bp_first + aux mm30<3> (blocks >= 8192)
__global__ __launch_bounds__(256) void k_bp_first(float* __restrict__ psi_pk, float* __restrict__ lg,
                                                  const float* __restrict__ betas,
                                                  const float* __restrict__ xin,
                                                  const float* __restrict__ w11,
                                                  float* __restrict__ hbuf){
  if (blockIdx.x >= 8192){
    __shared__ float ws[90];
    int t = threadIdx.x;
    for (int i=t;i<90;i+=256) ws[i] = w11[i];
    __syncthreads();
    int id = ((int)blockIdx.x - 8192)*256 + t;
    if (id >= NN*30) return;
    int v = id/30, j = id - v*30;
    const float* xr = xin + v*3;
    float acc = 0.f;
    #pragma unroll
    for (int k=0;k<3;k++) acc += xr[k]*ws[k*30+j];
    hbuf[id] = acc;
    return;
  }
  int graph, run, jj;
  bp_decode2(blockIdx.x, graph, run, jj);
  uint32_t k0, k1;
  tf2x32(0u, 42u, 0u, (uint32_t)run, k0, k1);
  float eb = expm1f(betas[run]);
  switch(run){
    case 0: bp_first_elem2< 2, 0, 1,0>(graph, jj, psi_pk, lg, eb, k0, k1); break;
    case 1: bp_first_elem2< 4, 2, 1,0>(graph, jj, psi_pk, lg, eb, k0, k1); break;
    case 2: bp_first_elem2< 8, 6, 2,1>(graph, jj, psi_pk, lg, eb, k0, k1); break;
    case 3: bp_first_elem2<16,14, 4,2>(graph, jj, psi_pk, lg, eb, k0, k1); break;
    case 4: bp_first_elem2<32,30, 8,3>(graph, jj, psi_pk, lg, eb, k0, k1); break;
    default:bp_first_elem2<64,62,16,4>(graph, jj, psi_pk, lg, eb, k0, k1); break;
  }
}

// fin==1: write psi TRANSPOSED (catT [126][NN] layout) into nxt
template<int Q, int CO, int TPR, int L2T>
__device__ __forceinline__ void bp_step_elem2(int graph, int run, int jj,
    const float* __restrict__ lcur, float* __restrict__ nxt, float* __restrict__ lnxt,
    const int* __restrict__ rp, const int* __restrict__ col,
    const float* __restrict__ field, float eb, int fin){
  int idx = jj*256 + (int)threadIdx.x;
  if constexpr (Q == 2){
    int row = graph*1024 + idx;
    const float2* B2 = (const float2*)(lcur + (size_t)NN*CO);
    float a0=0.f, a1=0.f;
    int a = rp[row], b2 = rp[row+1];
    for (; a+8<=b2; a+=8){
      int s0=col[a],s1=col[a+1],s2=col[a+2],s3=col[a+3];
      int s4=col[a+4],s5=col[a+5],s6=col[a+6],s7=col[a+7];
      float2 u0=B2[s0], u1=B2[s1], u2=B2[s2], u3=B2[s3];
      float2 u4=B2[s4], u5=B2[s5], u6=B2[s6], u7=B2[s7];
      a0+=u0.x; a1+=u0.y; a0+=u1.x; a1+=u1.y;
      a0+=u2.x; a1+=u2.y; a0+=u3.x; a1+=u3.y;
      a0+=u4.x; a1+=u4.y; a0+=u5.x; a1+=u5.y;
      a0+=u6.x; a1+=u6.y; a0+=u7.x; a1+=u7.y;
    }
    for (; a+4<=b2; a+=4){
      int s0=col[a],s1=col[a+1],s2=col[a+2],s3=col[a+3];
      float2 u0=B2[s0], u1=B2[s1], u2=B2[s2], u3=B2[s3];
      a0+=u0.x; a1+=u0.y; a0+=u1.x; a1+=u1.y;
      a0+=u2.x; a1+=u2.y; a0+=u3.x; a1+=u3.y;
    }
    for (; a<b2; ++a){ float2 u=B2[col[a]]; a0+=u.x; a1+=u.y; }
    float v0 = a0 - field[run*64 + 0];
    float v1 = a1 - field[run*64 + 1];
    float m0=fmaxf(v0,v1), m1=fmaxf(v1,v0);
    float e0=expf(v0-m0), e1=expf(v1-m1);
    float s0=e0+e1, s1=e1+e0;
    float p0=e0/s0, p1=e1/s1;
    if (fin){
      nxt[(size_t)(CO+0)*NN + row] = p0;
      nxt[(size_t)(CO+1)*NN + row] = p1;
    } else {
      ((float2*)(nxt  + (size_t)NN*CO))[row] = make_float2(p0,p1);
      ((float2*)(lnxt + (size_t)NN*CO))[row] = make_float2(log1pf(eb*p0), log1pf(eb*p1));
    }
  } else {
    int rw = idx >> L2T, ct = idx & (TPR-1);
    int row = graph*1024 + rw;
    const float4* B4 = (const float4*)(lcur + (size_t)NN*CO);
    float a0=0.f,a1=0.f,a2=0.f,a3=0.f;
    int a = rp[row], b2 = rp[row+1];
    for (; a+8<=b2; a+=8){
      int s0=col[a],s1=col[a+1],s2=col[a+2],s3=col[a+3];
      int s4=col[a+4],s5=col[a+5],s6=col[a+6],s7=col[a+7];
      float4 u0=B4[(size_t)s0*TPR+ct], u1=B4[(size_t)s1*TPR+ct];
      float4 u2=B4[(size_t)s2*TPR+ct], u3=B4[(size_t)s3*TPR+ct];
      float4 u4=B4[(size_t)s4*TPR+ct], u5=B4[(size_t)s5*TPR+ct];
      float4 u6=B4[(size_t)s6*TPR+ct], u7=B4[(size_t)s7*TPR+ct];
      a0+=u0.x; a1+=u0.y; a2+=u0.z; a3+=u0.w;
      a0+=u1.x; a1+=u1.y; a2+=u1.z; a3+=u1.w;
      a0+=u2.x; a1+=u2.y; a2+=u2.z; a3+=u2.w;
      a0+=u3.x; a1+=u3.y; a2+=u3.z; a3+=u3.w;
      a0+=u4.x; a1+=u4.y; a2+=u4.z; a3+=u4.w;
      a0+=u5.x; a1+=u5.y; a2+=u5.z; a3+=u5.w;
      a0+=u6.x; a1+=u6.y; a2+=u6.z; a3+=u6.w;
      a0+=u7.x; a1+=u7.y; a2+=u7.z; a3+=u7.w;
    }
    for (; a+4<=b2; a+=4){
      int s0=col[a],s1=col[a+1],s2=col[a+2],s3=col[a+3];
      float4 u0=B4[(size_t)s0*TPR+ct], u1=B4[(size_t)s1*TPR+ct];
      float4 u2=B4[(size_t)s2*TPR+ct], u3=B4[(size_t)s3*TPR+ct];
      a0+=u0.x; a1+=u0.y; a2+=u0.z; a3+=u0.w;
      a0+=u1.x; a1+=u1.y; a2+=u1.z; a3+=u1.w;
      a0+=u2.x; a1+=u2.y; a2+=u2.z; a3+=u2.w;
      a0+=u3.x; a1+=u3.y; a2+=u3.z; a3+=u3.w;
    }
    for (; a<b2; ++a){
      float4 u = B4[(size_t)col[a]*TPR+ct];
      a0+=u.x; a1+=u.y; a2+=u.z; a3+=u.w;
    }
    const float4 fld = *(const float4*)(field + run*64 + 4*ct);
    float v0 = a0 - fld.x, v1 = a1 - fld.y, v2 = a2 - fld.z, v3 = a3 - fld.w;
    float m0=v0,m1=v1,m2=v2,m3=v3;
    bfly_max4<TPR>(m0,m1,m2,m3);
    float e0=expf(v0-m0), e1=expf(v1-m1), e2=expf(v2-m2), e3=expf(v3-m3);
    float s0=e0,s1=e1,s2=e2,s3=e3;
    bfly_sum4<TPR>(s0,s1,s2,s3);
    float p0=e0/s0, p1=e1/s1, p2=e2/s2, p3=e3/s3;
    if (fin){
      int kb = CO + 4*ct;
      nxt[(size_t)(kb+0)*NN + row] = p0;
      nxt[(size_t)(kb+1)*NN + row] = p1;
      nxt[(size_t)(kb+2)*NN + row] = p2;
      nxt[(size_t)(kb+3)*NN + row] = p3;
    } else {
      ((float4*)(nxt  + (size_t)NN*CO))[(size_t)row*TPR+ct] = make_float4(p0,p1,p2,p3);
      ((float4*)(lnxt + (size_t)NN*CO))[(size_t)row*TPR+ct] =
          make_float4(log1pf(eb*p0), log1pf(eb*p1), log1pf(eb*p2), log1pf(eb*p3));
    }
  }
}

// pure bp_step (no aux)
__global__ __launch_bounds__(256) void k_bp_step(
    float* __restrict__ nxt, const float* __restrict__ lcur, float* __restrict__ lnxt,
    const int* __restrict__ rp, const int* __restrict__ col,
    const float* __restrict__ field, const float* __restrict__ betas, int fin){
  int graph, run, jj;
  bp_decode2(blockIdx.x, graph, run, jj);
  float eb = expm1f(betas[run]);
  switch(run){
    case 0: bp_step_elem2< 2, 0, 1,0>(graph, run, jj, lcur, nxt, lnxt, rp, col, field, eb, fin); break;
    case 1: bp_step_elem2< 4, 2, 1,0>(graph, run, jj, lcur, nxt, lnxt, rp, col, field, eb, fin); break;
    case 2: bp_step_elem2< 8, 6, 2,1>(graph, run, jj, lcur, nxt, lnxt, rp, col, field, eb, fin); break;
    case 3: bp_step_elem2<16,14, 4,2>(graph, run, jj, lcur, nxt, lnxt, rp, col, field, eb, fin); break;
    case 4: bp_step_elem2<32,30, 8,3>(graph, run, jj, lcur, nxt, lnxt, rp, col, field, eb, fin); break;
    default:bp_step_elem2<64,62,16,4>(graph, run, jj, lcur, nxt, lnxt, rp, col, field, eb, fin); break;
  }
}

// colsum (blocks 0..383, 4 chunks/block, per-chunk sums bit-identical)
// + aux blocks >= 384: 1=gcn_agg, 2=mm30c, 3=pool(stage-1)
__global__ __launch_bounds__(256) void k_colsum(const float* __restrict__ psi_pk,
    float* __restrict__ part, const int* __restrict__ rp, const int* __restrict__ col,
    int auxType, const float* __restrict__ aA, const float* __restrict__ aB,
    const float* __restrict__ aC, float* __restrict__ aO,
    float* __restrict__ agS, float* __restrict__ agQ,
    const float* __restrict__ adinv, const float* __restrict__ asfc,
    float* __restrict__ aconv){
  __shared__ float smem[960];
  int t = threadIdx.x;
  if (blockIdx.x < 384){
    int grp = t >> 6, c = t & 63;
    int b = blockIdx.x*4 + grp;            // virtual chunk-block id (== R15 b)
    int xcd = b & 7, i = b >> 3;
    int gs = i/24, rem = i - gs*24;
    int run = rem >> 2, cg = rem & 3;
    int graph = gs*8 + xcd;
    int chunk = graph*4 + cg;
    int q = cQS[run];
    int co = (run==0)?0:(run==1)?2:(run==2)?6:(run==3)?14:(run==4)?30:62;
    if (q >= 4){
      int nq = q >> 2;
      if (c >= nq) return;
      const float4* p4 = (const float4*)(psi_pk + (size_t)NN*co + (size_t)chunk*256*q) + c;
      float s0=0.f,s1=0.f,s2=0.f,s3=0.f;
      #pragma unroll 8
      for (int r=0;r<256;r++){
        float4 u = p4[(size_t)r*nq];
        s0+=u.x; s1+=u.y; s2+=u.z; s3+=u.w;
      }
      float* o = part + (run*256 + chunk)*64 + 4*c;
      o[0]=s0; o[1]=s1; o[2]=s2; o[3]=s3;
    } else {
      if (c >= q) return;
      float s = 0.f;
      const float* p = psi_pk + (size_t)NN*co + (size_t)chunk*256*q + c;
      #pragma unroll 8
      for (int r=0;r<256;r++) s += p[r*q];
      part[(run*256 + chunk)*64 + c] = s;
    }
    return;
  }
  int ab = (int)blockIdx.x - 384;
  if (auxType == 1){
    float* binS = smem; float* binQ = smem + 32;
    if (t < 30){ binS[t]=0.f; binQ[t]=0.f; }
    __syncthreads();
    int xcd = ab & 7, i = ab >> 3;
    int gs = i/60, j = i - gs*60;
    int graph = gs*8 + xcd;
    int idwg = j*256 + t;
    int rw = idwg/15, pr = idwg - rw*15;
    int v = graph*1024 + rw;
    float dv = adinv[v];
    float accx = 0.f, accy = 0.f;
    int a = rp[v], e = rp[v+1];
    for (; a+4<=e; a+=4){
      int s0=col[a], s1=col[a+1], s2=col[a+2], s3=col[a+3];
      float d0=adinv[s0], d1=adinv[s1], d2=adinv[s2], d3=adinv[s3];
      float2 h0=*(const float2*)(aA+s0*30+2*pr), h1=*(const float2*)(aA+s1*30+2*pr);
      float2 h2=*(const float2*)(aA+s2*30+2*pr), h3=*(const float2*)(aA+s3*30+2*pr);
      accx += h0.x*(d0*dv); accy += h0.y*(d0*dv);
      accx += h1.x*(d1*dv); accy += h1.y*(d1*dv);
      accx += h2.x*(d2*dv); accy += h2.y*(d2*dv);
      accx += h3.x*(d3*dv); accy += h3.y*(d3*dv);
    }
    for (; a<e; ++a){
      int s = col[a];
      float w = adinv[s]*dv;
      float2 hv = *(const float2*)(aA+s*30+2*pr);
      accx += hv.x*w; accy += hv.y*w;
    }
    float2 hs = *(const float2*)(aA + v*30 + 2*pr);
    float w2 = dv*dv;
    accx += hs.x*w2; accy += hs.y*w2;   // self loop last (JAX concat order)
    float2 o; o.x = accx + aB[2*pr]; o.y = accy + aB[2*pr+1];
    *(float2*)(aO + v*30 + 2*pr) = o;
    atomicAdd(&binS[2*pr],   o.x); atomicAdd(&binQ[2*pr],   o.x*o.x);
    atomicAdd(&binS[2*pr+1], o.y); atomicAdd(&binQ[2*pr+1], o.y*o.y);
    __syncthreads();
    if (t < 30){
      int slot = (ab & 63)*30 + t;
      atomicAdd(&agS[slot], binS[t]);
      atomicAdd(&agQ[slot], binQ[t]);
    }
  } else if (auxType == 2){
    float* ws = smem; float* cl = smem + 904;
    for (int i=t;i<900;i+=256) ws[i] = aB[i];
    if (t < 30) cl[t] = aC[t];
    __syncthreads();
    int id = ab*256 + t;
    if (id < NN*30){
      int v = id/30, j = id - v*30;
      const float* xr = aA + v*30;
      float acc = cl[j];
      #pragma unroll
      for (int k=0;k<30;k++) acc += xr[k]*ws[k*30+j];
      aO[id] = acc;
    }
  } else if (auxType == 3){
    int b2 = ab & 63, a = ab >> 6;
    const float* X = (a==0)? aA : ((a==1)? aB : aC);
    const float* sf = asfc + a*64;
    float acc[30];
    #pragma unroll
    for (int f=0;f<30;f++) acc[f] = -FLT_MAX;
    for (int r=t; r<1024; r+=256){
      const float* xr = X + (size_t)(b2*1024 + r)*30;
      #pragma unroll
      for (int f=0;f<30;f++) acc[f] = fmaxf(acc[f], sf[f]*xr[f] + sf[32+f]);
    }
    #pragma unroll
    for (int off=32; off; off>>=1){
      #pragma unroll
      for (int f=0;f<30;f++) acc[f] = fmaxf(acc[f], __shfl_xor(acc[f], off, 64));
    }
    int w = t>>6, lane = t&63;
    if (lane == 0){
      #pragma unroll
      for (int f=0;f<30;f++) smem[w*30+f] = acc[f];
    }
    __syncthreads();
    if (t < 30)
      aconv[b2*180 + a*30 + t] =
        fmaxf(fmaxf(smem[t], smem[30+t]), fmaxf(smem[60+t], smem[90+t]));
  }
}

// field (block 0) + optional bnw aux (block 1). 2 blocks x 384 thr.
__global__ void k_field(const float* __restrict__ part, const float* __restrict__ betas,
                        float* __restrict__ field,
                        int auxFold, float* __restrict__ gS, float* __restrict__ gQ, float n,
                        const float* __restrict__ g, const float* __restrict__ be,
                        const float* __restrict__ wnext, float* __restrict__ sfc,
                        float* __restrict__ wfold, float* __restrict__ cvec){
  if (blockIdx.x == 1){
    if (auxFold < 0) return;
    __shared__ float s_l[30], c_l[30];
    int t = threadIdx.x;
    if (t < 30){
      float s=0.f, q=0.f;
      for (int u=0;u<64;u++){ s += gS[u*30+t]; q += gQ[u*30+t]; }
      float m = s/n;
      float var = q/n - m*m;
      float sc = g[t]*(1.0f/sqrtf(var+1e-5f));
      float c0 = be[t] - sc*m;
      s_l[t]=sc; c_l[t]=c0;
      sfc[t]=sc; sfc[32+t]=c0;
      for (int u=0;u<64;u++){ gS[u*30+t]=0.f; gQ[u*30+t]=0.f; }
    }
    __syncthreads();
    if (auxFold == 1){
      for (int i=t;i<900;i+=384) wfold[i] = s_l[i/30]*wnext[i];
      if (t<30){
        float c=0.f;
        for (int k=0;k<30;k++) c += c_l[k]*wnext[k*30+t];
        cvec[t]=c;
      }
    }
    return;
  }
  int id = threadIdx.x;
  int run = id >> 6, c = id & 63;
  if (c >= cQS[run]) return;
  float s = 0.f;
  for (int b=0;b<256;b++) s += part[(run*256 + b)*64 + c];
  float beta = betas[run];
  field[id] = s * (3.8f*beta/65536.0f);
}

// ---------------- diff-pool ----------------
__global__ __launch_bounds__(256) void k_s1t(const float* __restrict__ catT, const float* __restrict__ pw,
                                             const float* __restrict__ pb, float* __restrict__ s1){
  __shared__ float wl[12600];
  __shared__ float pbl[100];
  __shared__ float redM[2][128];
  __shared__ float redS[2][128];
  int t = threadIdx.x;
  for (int i=t;i<12600;i+=256) wl[i] = pw[i];
  if (t < 100) pbl[t] = pb[t];
  int w = t>>6, lane = t&63;
  int rh = w&1, chh = w>>1;
  int ch = chh*50;
  int row = blockIdx.x*128 + rh*64 + lane;
  __syncthreads();
  float acc[50];
  #pragma unroll
  for (int j=0;j<50;j++) acc[j] = pbl[ch+j];
  for (int k=0;k<126;k++){
    float xv = catT[(size_t)k*65536 + row];
    const float* wr = &wl[k*100 + ch];
    #pragma unroll
    for (int j=0;j<50;j+=2){
      float2 wv = *(const float2*)&wr[j];
      acc[j]   += xv*wv.x;
      acc[j+1] += xv*wv.y;
    }
  }
  float m = acc[0];
  #pragma unroll
  for (int j=1;j<50;j++) m = fmaxf(m, acc[j]);
  redM[chh][rh*64 + lane] = m;
  __syncthreads();
  float mm = fmaxf(redM[0][rh*64 + lane], redM[1][rh*64 + lane]);
  float s = 0.f;
  #pragma unroll
  for (int j=0;j<50;j++){ acc[j] = expf(acc[j]-mm); s += acc[j]; }
  redS[chh][rh*64 + lane] = s;
  __syncthreads();
  float tot = redS[0][rh*64 + lane] + redS[1][rh*64 + lane];
  float* o = s1 + (size_t)row*100 + ch;
  #pragma unroll
  for (int j=0;j<50;j+=2){
    float2 ov; ov.x = acc[j]/tot; ov.y = acc[j+1]/tot;
    *(float2*)&o[j] = ov;
  }
}

__global__ __launch_bounds__(256) void k_T(const float* __restrict__ s1, const int* __restrict__ rp,
                                           const int* __restrict__ col, float* __restrict__ T){
  int b = blockIdx.x;
  int xcd = b & 7, i = b >> 3;
  int gs = i/100, j = i - gs*100;
  int graph = gs*8 + xcd;
  int idwg = j*256 + threadIdx.x;
  int rw = idwg/25, quad = idwg - rw*25;
  int v = graph*1024 + rw;
  float a0=0.f,a1=0.f,a2=0.f,a3=0.f;
  const float4* S4 = (const float4*)s1;
  int a = rp[v], e = rp[v+1];
  for (; a+8<=e; a+=8){
    int s0=col[a], s1_=col[a+1], s2=col[a+2], s3=col[a+3];
    int s4=col[a+4], s5=col[a+5], s6=col[a+6], s7=col[a+7];
    float4 u0=S4[(size_t)s0*25+quad], u1=S4[(size_t)s1_*25+quad];
    float4 u2=S4[(size_t)s2*25+quad], u3=S4[(size_t)s3*25+quad];
    float4 u4=S4[(size_t)s4*25+quad], u5=S4[(size_t)s5*25+quad];
    float4 u6=S4[(size_t)s6*25+quad], u7=S4[(size_t)s7*25+quad];
    a0+=u0.x; a1+=u0.y; a2+=u0.z; a3+=u0.w;
    a0+=u1.x; a1+=u1.y; a2+=u1.z; a3+=u1.w;
    a0+=u2.x; a1+=u2.y; a2+=u2.z; a3+=u2.w;
    a0+=u3.x; a1+=u3.y; a2+=u3.z; a3+=u3.w;
    a0+=u4.x; a1+=u4.y; a2+=u4.z; a3+=u4.w;
    a0+=u5.x; a1+=u5.y; a2+=u5.z; a3+=u5.w;
    a0+=u6.x; a1+=u6.y; a2+=u6.z; a3+=u6.w;
    a0+=u7.x; a1+=u7.y; a2+=u7.z; a3+=u7.w;
  }
  for (; a+4<=e; a+=4){
    int s0=col[a], s1_=col[a+1], s2=col[a+2], s3=col[a+3];
    float4 u0=S4[(size_t)s0*25+quad], u1=S4[(size_t)s1_*25+quad];
    float4 u2=S4[(size_t)s2*25+quad], u3=S4[(size_t)s3*25+quad];
    a0+=u0.x; a1+=u0.y; a2+=u0.z; a3+=u0.w;
    a0+=u1.x; a1+=u1.y; a2+=u1.z; a3+=u1.w;
    a0+=u2.x; a1+=u2.y; a2+=u2.z; a3+=u2.w;
    a0+=u3.x; a1+=u3.y; a2+=u3.z; a3+=u3.w;
  }
  for (; a<e; ++a){
    float4 u = S4[(size_t)col[a]*25+quad];
    a0+=u.x; a1+=u.y; a2+=u.z; a3+=u.w;
  }
  ((float4*)T)[(size_t)v*25 + quad] = make_float4(a0,a1,a2,a3);
}

// merged split-K: blocks 0..255 = p1adj, 256..511 = p1x (BN affine on fill)
__global__ __launch_bounds__(512) void k_p1ax(const float* __restrict__ s1, const float* __restrict__ T,
                                              const float* __restrict__ y3, const float* __restrict__ sfc,
                                              float* __restrict__ partA, float* __restrict__ partX){
  __shared__ float sS[6400];
  __shared__ float sT[6400];
  int t = threadIdx.x;
  if (blockIdx.x < 256){
    int blk = blockIdx.x;
    int b = blk >> 2, qtr = blk & 3;
    int tk = t/20, tl = t - tk*20;
    bool act = t < 500;
    int k0 = tk*4, l0 = tl*5;
    float acc[4][5];
    #pragma unroll
    for (int i=0;i<4;i++)
      #pragma unroll
      for (int j=0;j<5;j++) acc[i][j] = 0.f;
    const float* s1b = s1 + (size_t)b*102400;
    const float* Tb  = T  + (size_t)b*102400;
    for (int c=qtr*4; c<qtr*4+4; c++){
      for (int i=t;i<6400;i+=512){ sS[i] = s1b[c*6400+i]; sT[i] = Tb[c*6400+i]; }
      __syncthreads();
      if (act){
        #pragma unroll 2
        for (int n=0;n<64;n++){
          const float* sr = &sS[n*100 + k0];
          const float* tr = &sT[n*100 + l0];
          float s0=sr[0], s1v=sr[1], s2=sr[2], s3=sr[3];
          float t0=tr[0], t1=tr[1], t2=tr[2], t3=tr[3], t4=tr[4];
          acc[0][0]+=s0*t0; acc[0][1]+=s0*t1; acc[0][2]+=s0*t2; acc[0][3]+=s0*t3; acc[0][4]+=s0*t4;
          acc[1][0]+=s1v*t0; acc[1][1]+=s1v*t1; acc[1][2]+=s1v*t2; acc[1][3]+=s1v*t3; acc[1][4]+=s1v*t4;
          acc[2][0]+=s2*t0; acc[2][1]+=s2*t1; acc[2][2]+=s2*t2; acc[2][3]+=s2*t3; acc[2][4]+=s2*t4;
          acc[3][0]+=s3*t0; acc[3][1]+=s3*t1; acc[3][2]+=s3*t2; acc[3][3]+=s3*t3; acc[3][4]+=s3*t4;
        }
      }
      __syncthreads();
    }
    if (act){
      float* pp = partA + (size_t)qtr*640000 + (size_t)b*10000;
      #pragma unroll
      for (int i=0;i<4;i++){
        float* o = pp + (k0+i)*100 + l0;
        #pragma unroll
        for (int j=0;j<5;j++) o[j] = acc[i][j];
      }
    }
  } else {
    int blk = blockIdx.x - 256;
    int b = blk >> 2, qtr = blk & 3;
    float* sX = sT;
    int tk = t/10, tl = t - tk*10;
    bool act = t < 250;
    int k0 = tk*4, d0 = tl*3;
    float acc[4][3];
    #pragma unroll
    for (int i=0;i<4;i++)
      #pragma unroll
      for (int j=0;j<3;j++) acc[i][j] = 0.f;
    const float* s1b = s1 + (size_t)b*102400;
    const float* xb  = y3 + (size_t)b*30720;
    for (int c=qtr*4; c<qtr*4+4; c++){
      for (int i=t;i<6400;i+=512) sS[i] = s1b[c*6400+i];
      for (int i=t;i<1920;i+=512){
        int f = i % 30;
        sX[i] = sfc[f]*xb[c*1920+i] + sfc[32+f];
      }
      __syncthreads();
      if (act){
        #pragma unroll 2
        for (int n=0;n<64;n++){
          const float* sr = &sS[n*100 + k0];
          const float* xr = &sX[n*30 + d0];
          float s0=sr[0], s1v=sr[1], s2=sr[2], s3=sr[3];
          float x0=xr[0], x1=xr[1], x2=xr[2];
          acc[0][0]+=s0*x0; acc[0][1]+=s0*x1; acc[0][2]+=s0*x2;
          acc[1][0]+=s1v*x0; acc[1][1]+=s1v*x1; acc[1][2]+=s1v*x2;
          acc[2][0]+=s2*x0; acc[2][1]+=s2*x1; acc[2][2]+=s2*x2;
          acc[3][0]+=s3*x0; acc[3][1]+=s3*x1; acc[3][2]+=s3*x2;
        }
      }
      __syncthreads();
    }
    if (act){
      float* pp = partX + (size_t)qtr*192000 + (size_t)b*3000;
      #pragma unroll
      for (int i=0;i<4;i++){
        float* o = pp + (k0+i)*30 + d0;
        #pragma unroll
        for (int j=0;j<3;j++) o[j] = acc[i][j];
      }
    }
  }
}

// blocks 0..63: reduce padj parts + normalize -> An; 64..813: px reduce
__global__ __launch_bounds__(256) void k_anpx(const float* __restrict__ pA, const float* __restrict__ pX,
                                              float* __restrict__ An, float* __restrict__ px){
  if (blockIdx.x < 64){
    __shared__ float pj[10000];
    __shared__ float dv[100];
    int b = blockIdx.x, t = threadIdx.x;
    size_t base = (size_t)b*10000;
    for (int i=t;i<10000;i+=256)
      pj[i] = pA[base+i] + pA[640000+base+i] + pA[1280000+base+i] + pA[1920000+base+i];
    __syncthreads();
    if (t < 100){
      const float* r = pj + t*100;
      float s = 0.f;
      for (int l=0;l<100;l++){
        float v = r[l];
        if (l==t) v += 1.0f;
        s += v;
      }
      dv[t] = 1.0f/sqrtf(s);
    }
    __syncthreads();
    for (int i=t;i<10000;i+=256){
      int k = i/100, l = i - k*100;
      float a = pj[i] + ((k==l)? 1.0f : 0.0f);
      An[base + i] = (dv[k]*a)*dv[l];
    }
  } else {
    int id = ((int)blockIdx.x - 64)*256 + threadIdx.x;
    if (id < 192000)
      px[id] = pX[id] + pX[192000+id] + pX[384000+id] + pX[576000+id];
  }
}

// ---------------- stage-2 dense GCN ----------------
__global__ __launch_bounds__(256) void k_y2(const float* __restrict__ An, const float* __restrict__ h,
    const float* __restrict__ bias, float* __restrict__ y,
    float* __restrict__ gS, float* __restrict__ gQ){
  __shared__ float binS[30], binQ[30];
  int t = threadIdx.x;
  if (t < 30){ binS[t]=0.f; binQ[t]=0.f; }
  __syncthreads();
  int id = blockIdx.x*256 + t;
  if (id < NBG*100*30){
    int d = id % 30;
    int bk = id / 30;
    int b = bk / 100;
    const float* Ar = An + bk*100;
    const float* hb = h + b*100*30;
    float acc = 0.f;
    for (int l=0;l<100;l++) acc += Ar[l]*hb[l*30+d];
    float val = acc + bias[d];
    y[id] = val;
    atomicAdd(&binS[d], val);
    atomicAdd(&binQ[d], val*val);
  }
  __syncthreads();
  if (t < 30){
    int slot = (blockIdx.x & 63)*30 + t;
    atomicAdd(&gS[slot], binS[t]);
    atomicAdd(&gQ[slot], binQ[t]);
  }
}

// stage-2 pool (big-LDS variant, separate launch)
__global__ __launch_bounds__(256) void k_pool2(const float* __restrict__ A,
    const float* __restrict__ Bv, const float* __restrict__ Cv,
    const float* __restrict__ sfcBase,
    int rows, float* __restrict__ conv, int coff){
  __shared__ float lds[256*31];
  int b = blockIdx.x, a = blockIdx.y, t = threadIdx.x;
  const float* X = (a==0)? A : ((a==1)? Bv : Cv);
  const float* sf = sfcBase + a*64;
  float acc[30];
  #pragma unroll
  for (int f=0;f<30;f++) acc[f] = -FLT_MAX;
  for (int r=t; r<rows; r+=256){
    const float* xr = X + (size_t)(b*rows + r)*30;
    #pragma unroll
    for (int f=0;f<30;f++) acc[f] = fmaxf(acc[f], sf[f]*xr[f] + sf[32+f]);
  }
  #pragma unroll
  for (int f=0;f<30;f++) lds[t*31+f] = acc[f];
  __syncthreads();
  for (int s=128;s>0;s>>=1){
    if (t<s){
      #pragma unroll
      for (int f=0;f<30;f++) lds[t*31+f] = fmaxf(lds[t*31+f], lds[(t+s)*31+f]);
    }
    __syncthreads();
  }
  if (t<30) conv[b*180 + coff + a*30 + t] = lds[t];
}

__global__ __launch_bounds__(64) void k_fc(const float* __restrict__ conv,
    const float* __restrict__ w1, const float* __restrict__ b1,
    const float* __restrict__ w2, const float* __restrict__ b2, float* __restrict__ out){
  __shared__ float row[180];
  __shared__ float hid[50];
  int b = blockIdx.x, t = threadIdx.x;
  for (int i=t;i<180;i+=64) row[i] = conv[b*180+i];
  __syncthreads();
  if (t < 50){
    float a = b1[t];
    for (int i=0;i<180;i++) a += row[i]*w1[i*50+t];
    hid[t] = fmaxf(a, 0.f);
  }
  __syncthreads();
  if (t < 6){
    float a = b2[t];
    for (int i=0;i<50;i++) a += hid[i]*w2[i*6+t];
    out[b*6+t] = a;
  }
  if (b==0 && t==63) out[NBG*6] = 0.0f;
}

// ---------------------------------------------------------------------------
extern "C" void kernel_launch(void* const* d_in, const int* in_sizes, int n_in,
                              void* d_out, int out_size, void* d_ws, size_t ws_size,
                              hipStream_t stream)
{
  (void)in_sizes; (void)n_in; (void)out_size; (void)ws_size;
  const float* x   = (const float*)d_in[0];
  const int*   src = (const int*)d_in[1];
  const int*   dst = src + NEDGE;
  const float* w11=(const float*)d_in[3],  *b11=(const float*)d_in[4],  *g11=(const float*)d_in[5],  *be11=(const float*)d_in[6];
  const float* w12=(const float*)d_in[7],  *b12=(const float*)d_in[8],  *g12=(const float*)d_in[9],  *be12=(const float*)d_in[10];
  const float* w13=(const float*)d_in[11], *b13=(const float*)d_in[12], *g13=(const float*)d_in[13], *be13=(const float*)d_in[14];
  const float* w21=(const float*)d_in[15], *b21=(const float*)d_in[16], *g21=(const float*)d_in[17], *be21=(const float*)d_in[18];
  const float* w22=(const float*)d_in[19], *b22=(const float*)d_in[20], *g22=(const float*)d_in[21], *be22=(const float*)d_in[22];
  const float* w23=(const float*)d_in[23], *b23=(const float*)d_in[24], *g23=(const float*)d_in[25], *be23=(const float*)d_in[26];
  const float* betas=(const float*)d_in[27];
  const float* poolw=(const float*)d_in[28], *poolb=(const float*)d_in[29];
  const float* fc1w=(const float*)d_in[30], *fc1b=(const float*)d_in[31];
  const float* fc2w=(const float*)d_in[32], *fc2b=(const float*)d_in[33];
  float* out = (float*)d_out;

  uint8_t* basep = (uint8_t*)d_ws;
  size_t off = 0;
  auto take = [&](size_t bytes)->void*{
    void* p = basep + off;
    off = (off + bytes + 255) & ~(size_t)255;
    return p;
  };
  int* degi    = (int*)take((size_t)NN*4);
  int* dego    = (int*)take((size_t)NN*4);
  int* cntA    = (int*)take((size_t)NN*4);
  int* cntB    = (int*)take((size_t)NN*4);
  float* gS    = (float*)take(64*30*4);     // BN stat slots (zeroed by memset)
  float* gQ    = (float*)take(64*30*4);
  int* rp_in   = (int*)take((size_t)(NN+1)*4);
  int* rp_out  = (int*)take((size_t)(NN+1)*4);
  int* bsum    = (int*)take(512*4);
  int* col_in  = (int*)take((size_t)NEDGE*4);
  int* col_out = (int*)take((size_t)NEDGE*4);
  float* dinv  = (float*)take((size_t)NN*4);
  float* hbuf  = (float*)take((size_t)NN*30*4);
  float* X1    = (float*)take((size_t)NN*30*4);   // pre-BN y1
  float* X2    = (float*)take((size_t)NN*30*4);   // pre-BN y2
  float* X3    = (float*)take((size_t)NN*30*4);   // pre-BN y3
  float* bufA  = (float*)take((size_t)NN*126*4);
  float* bufB  = (float*)take((size_t)NN*126*4);
  float* logA  = (float*)take((size_t)NN*126*4);
  float* logB  = (float*)take((size_t)NN*126*4);
  float* partCS= (float*)take((size_t)6*256*64*4);
  float* fieldv= (float*)take(384*4);
  float* sfcAll= (float*)take(6*64*4);
  float* wfold = (float*)take(960*4);
  float* cvec  = (float*)take(32*4);
  float* px    = (float*)take(192000*4);
  float* An    = (float*)take(640000*4);
  float* h2    = (float*)take(192000*4);
  float* X21   = (float*)take(192000*4);  // pre-BN
  float* X22   = (float*)take(192000*4);
  float* X23   = (float*)take(192000*4);
  float* conv  = (float*)take(64*180*4);

  // post-BP scratch reuse: catT -> logA (L of it7, dead at it9; fin writes
  // no L and lcur=logB at it9); split-K partials -> logB (dead after it9).
  float* catT     = logA;
  float* pAdjPart = logB;               // 4*640000 floats
  float* pPxPart  = logB + 2560000;     // 4*192000 floats

  // ---- CSR + stat zero (degi..gQ contiguous -> single memset) ----
  hipMemsetAsync(degi, 0, (size_t)4*NN*4 + 2*64*30*4, stream);
  k_count<<<2048,256,0,stream>>>(src,dst,degi,dego);
  k_scan1<<<dim3(256,2),256,0,stream>>>(degi, dego, rp_in, rp_out, bsum);
  k_scan2<<<2,256,0,stream>>>(bsum);
  k_scan3<<<dim3(256,2),256,0,stream>>>(rp_in, rp_out, bsum);
  k_fill<<<dim3(2048,2),256,0,stream>>>(src, dst, rp_in, rp_out, cntA, cntB, col_in, col_out);
  k_sortrow<<<dim3(256,2),256,0,stream>>>(rp_in, rp_out, col_in, col_out, src, dst, degi, dinv);

  // ---- BP; stage-1 rides colsum launches (aux), bp_first carries mm30<3> --
  k_bp_first<<<15872,256,0,stream>>>(bufA, logA, betas, x, w11, hbuf);

  float* cur = bufA;  float* nxt = bufB;
  float* lcur = logA; float* lnxt = logB;
  for (int it=0; it<10; ++it){
    // colsum + stage-1 aux
    int auxType = 0, auxN = 0;
    const float *aA=nullptr, *aB=nullptr, *aC=nullptr; float *aO=nullptr;
    if      (it==0){ auxType=1; auxN=3840; aA=hbuf; aB=b11; aO=X1; }
    else if (it==1){ auxType=2; auxN=7680; aA=X1; aB=wfold; aC=cvec; aO=hbuf; }
    else if (it==2){ auxType=1; auxN=3840; aA=hbuf; aB=b12; aO=X2; }
    else if (it==3){ auxType=2; auxN=7680; aA=X2; aB=wfold; aC=cvec; aO=hbuf; }
    else if (it==4){ auxType=1; auxN=3840; aA=hbuf; aB=b13; aO=X3; }
    else if (it==5){ auxType=3; auxN=192;  aA=X1; aB=X2; aC=X3; }
    k_colsum<<<384+auxN,256,0,stream>>>(cur, partCS, rp_in, col_in,
        auxType, aA, aB, aC, aO, gS, gQ, dinv, sfcAll, conv);
    // field + bnw fold (folds at it 0,2; scale-only at it 4)
    int fold = (it==0||it==2)? 1 : ((it==4)? 0 : -1);
    const float* gg = (it==0)? g11 : ((it==2)? g12 : g13);
    const float* bb = (it==0)? be11: ((it==2)? be12: be13);
    const float* wn = (it==0)? w12 : ((it==2)? w13 : nullptr);
    float* sfc = (it==0)? sfcAll : ((it==2)? sfcAll+64 : sfcAll+128);
    k_field<<<2,384,0,stream>>>(partCS, betas, fieldv, fold, gS, gQ, 65536.f,
                                gg, bb, wn, sfc, wfold, cvec);
    int fin = (it==9);
    float* stepNxt = fin ? catT : nxt;          // fin writes transposed psi
    k_bp_step<<<8192,256,0,stream>>>(stepNxt, lcur, lnxt, rp_in, col_in, fieldv, betas, fin);
    float* tp = cur;  cur = nxt;   nxt = tp;
    float* tl = lcur; lcur = lnxt; lnxt = tl;
  }
  // final psi now in catT ([126][NN] layout, == logA)

  // ---- diff-pool ----
  k_s1t<<<512,256,0,stream>>>(catT, poolw, poolb, bufB);
  k_T<<<6400,256,0,stream>>>(bufB, rp_out, col_out, bufA);
  k_p1ax<<<512,512,0,stream>>>(bufB, bufA, X3, sfcAll+128, pAdjPart, pPxPart);
  k_anpx<<<814,256,0,stream>>>(pAdjPart, pPxPart, An, px);

  // ---- stage 2: dense GCN x3 with folded BN ----
  k_mm30<30><<<750,256,0,stream>>>(px, w21, h2, NBG*100);
  k_y2<<<750,256,0,stream>>>(An, h2, b21, X21, gS, gQ);
  k_bnw<1><<<1,256,0,stream>>>(gS, gQ, 6400.f, g21, be21, w22, sfcAll+3*64, wfold, cvec);
  k_mm30c<<<750,256,0,stream>>>(X21, wfold, cvec, h2, NBG*100);
  k_y2<<<750,256,0,stream>>>(An, h2, b22, X22, gS, gQ);
  k_bnw<1><<<1,256,0,stream>>>(gS, gQ, 6400.f, g22, be22, w23, sfcAll+4*64, wfold, cvec);
  k_mm30c<<<750,256,0,stream>>>(X22, wfold, cvec, h2, NBG*100);
  k_y2<<<750,256,0,stream>>>(An, h2, b23, X23, gS, gQ);
  k_bnw<0><<<1,256,0,stream>>>(gS, gQ, 6400.f, g23, be23, nullptr, sfcAll+5*64, nullptr, nullptr);
  k_pool2<<<dim3(NBG,3),256,0,stream>>>(X21, X22, X23, sfcAll+3*64, 100, conv, 90);

  // ---- FC head ----
  k_fc<<<64,64,0,stream>>>(conv, fc1w, fc1b, fc2w, fc2b, out);
}

// Round 17
// 1154.668 us; speedup vs baseline: 1.6971x; 1.0236x over previous
//
#include <hip/hip_runtime.h>
#include <stdint.h>
#include <float.h>

// ---------------------------------------------------------------------------
// Net_57604101374728: GCN(x3)+BN -> maxpool | 6x belief-prop -> diffpool ->
// dense GCN(x3)+BN -> maxpool -> FC. Full fp32 port of the JAX reference.
//
// R17 = R16 + occupancy micro-bundle: __launch_bounds__(256,8) on the BP
// kernels (pins RA <=64 VGPR, hints 8 waves/EU) and field-load hoisted above
// the gather loop. No FP change anywhere; BP bit-identical to R16.
// ---------------------------------------------------------------------------

constexpr int NN    = 65536;    // total nodes
constexpr int NEDGE = 524288;   // edges
constexpr int NBG   = 64;       // graphs

__constant__ int cQS[6]   = {2,4,8,16,32,64};

// ---------------- threefry2x32 (20 rounds) ----------------
__device__ __forceinline__ void tf2x32(uint32_t k0, uint32_t k1, uint32_t x0, uint32_t x1,
                                       uint32_t& o0, uint32_t& o1){
  uint32_t ks[3] = {k0, k1, k0 ^ k1 ^ 0x1BD11BDAu};
  x0 += ks[0]; x1 += ks[1];
  const int RA[4] = {13,15,26,6}, RB[4] = {17,29,16,24};
  #pragma unroll
  for (int i=0;i<5;i++){
    const int* r = (i&1)? RB : RA;
    #pragma unroll
    for (int j=0;j<4;j++){
      x0 += x1;
      x1 = (x1 << r[j]) | (x1 >> (32 - r[j]));
      x1 ^= x0;
    }
    x0 += ks[(i+1)%3];
    x1 += ks[(i+2)%3] + (uint32_t)(i+1);
  }
  o0 = x0; o1 = x1;
}

// ---------------- XLA ErfInv32 (Giles), contraction off ----------------
__device__ __forceinline__ float erfinv32(float xx){
  #pragma clang fp contract(off)
  float w = -log1pf(-xx*xx);
  float p;
  if (w < 5.0f){
    w = w - 2.5f;
    p = 2.81022636e-08f;
    p = 3.43273939e-07f  + p*w;
    p = -3.5233877e-06f  + p*w;
    p = -4.39150654e-06f + p*w;
    p = 0.00021858087f   + p*w;
    p = -0.00125372503f  + p*w;
    p = -0.00417768164f  + p*w;
    p = 0.246640727f     + p*w;
    p = 1.50140941f      + p*w;
  } else {
    w = sqrtf(w) - 3.0f;
    p = -0.000200214257f;
    p = 0.000100950558f  + p*w;
    p = 0.00134934322f   + p*w;
    p = -0.00367342844f  + p*w;
    p = 0.00573950773f   + p*w;
    p = -0.0076224613f   + p*w;
    p = 0.00943887047f   + p*w;
    p = 1.00167406f      + p*w;
    p = 2.83297682f      + p*w;
  }
  return p*xx;
}

// ---------------- CSR construction (fused pairs via blockIdx.y) ----------
__global__ __launch_bounds__(256) void k_count(const int* __restrict__ src, const int* __restrict__ dst,
                                               int* __restrict__ degi, int* __restrict__ dego){
  int e = blockIdx.x*256 + threadIdx.x;
  if (e >= NEDGE) return;
  atomicAdd(&degi[dst[e]], 1);
  atomicAdd(&dego[src[e]], 1);
}

__global__ __launch_bounds__(256) void k_scan1(const int* __restrict__ degi, const int* __restrict__ dego,
                                               int* __restrict__ rpi, int* __restrict__ rpo,
                                               int* __restrict__ bsum){
  __shared__ int lds[256];
  const int* deg = blockIdx.y? dego : degi;
  int* rp = blockIdx.y? rpo : rpi;
  int* bs = bsum + blockIdx.y*256;
  int b = blockIdx.x, t = threadIdx.x;
  lds[t] = deg[b*256 + t];
  __syncthreads();
  for (int s=1;s<256;s<<=1){
    int add = (t>=s)? lds[t-s] : 0;
    __syncthreads();
    lds[t] += add;
    __syncthreads();
  }
  rp[b*256 + t + 1] = lds[t];
  if (t==0 && b==0) rp[0] = 0;
  if (t==255) bs[b] = lds[255];
}

__global__ __launch_bounds__(256) void k_scan2(int* __restrict__ bsum){
  __shared__ int lds[256];
  int* bs = bsum + blockIdx.x*256;
  int t = threadIdx.x;
  lds[t] = bs[t];
  __syncthreads();
  for (int s=1;s<256;s<<=1){
    int add = (t>=s)? lds[t-s] : 0;
    __syncthreads();
    lds[t] += add;
    __syncthreads();
  }
  bs[t] = (t==0)? 0 : lds[t-1];
}

__global__ __launch_bounds__(256) void k_scan3(int* __restrict__ rpi, int* __restrict__ rpo,
                                               const int* __restrict__ bsum){
  int* rp = blockIdx.y? rpo : rpi;
  const int* bs = bsum + blockIdx.y*256;
  int b = blockIdx.x, t = threadIdx.x;
  rp[b*256 + t + 1] += bs[b];
}

__global__ __launch_bounds__(256) void k_fill(const int* __restrict__ src, const int* __restrict__ dst,
                                              const int* __restrict__ rpi, const int* __restrict__ rpo,
                                              int* __restrict__ cntA, int* __restrict__ cntB,
                                              int* __restrict__ colI, int* __restrict__ colO){
  int e = blockIdx.x*256 + threadIdx.x;
  if (e >= NEDGE) return;
  if (blockIdx.y == 0){
    int d = dst[e];
    int p = atomicAdd(&cntA[d], 1);
    colI[rpi[d] + p] = e;
  } else {
    int d = src[e];
    int p = atomicAdd(&cntB[d], 1);
    colO[rpo[d] + p] = e;
  }
}

__global__ __launch_bounds__(256) void k_sortrow(const int* __restrict__ rpi, const int* __restrict__ rpo,
                                                 int* __restrict__ colI, int* __restrict__ colO,
                                                 const int* __restrict__ src, const int* __restrict__ dst,
                                                 const int* __restrict__ degi, float* __restrict__ dinv){
  const int* rp = blockIdx.y? rpo : rpi;
  int* colbuf   = blockIdx.y? colO : colI;
  const int* other = blockIdx.y? dst : src;
  int v = blockIdx.x*256 + threadIdx.x;
  if (v >= NN) return;
  int s0 = rp[v], s1 = rp[v+1];
  for (int i=s0+1;i<s1;i++){
    int key = colbuf[i]; int j = i-1;
    while (j>=s0 && colbuf[j]>key){ colbuf[j+1]=colbuf[j]; j--; }
    colbuf[j+1] = key;
  }
  for (int i=s0;i<s1;i++) colbuf[i] = other[colbuf[i]];
  if (blockIdx.y == 0) dinv[v] = 1.0f / sqrtf((float)(degi[v] + 1));
}

// ---------------- stage-2 GEMM helpers (standalone) ----------------
template<int CIN>
__global__ __launch_bounds__(256) void k_mm30(const float* __restrict__ x, const float* __restrict__ w,
                                              float* __restrict__ h, int nrow){
  __shared__ float ws[CIN*30];
  int t = threadIdx.x;
  for (int i=t;i<CIN*30;i+=256) ws[i] = w[i];
  __syncthreads();
  int id = blockIdx.x*256 + t;
  if (id >= nrow*30) return;
  int v = id/30, j = id - v*30;
  const float* xr = x + v*CIN;
  float acc = 0.f;
  #pragma unroll
  for (int k=0;k<CIN;k++) acc += xr[k]*ws[k*30+j];
  h[id] = acc;
}

__global__ __launch_bounds__(256) void k_mm30c(const float* __restrict__ x, const float* __restrict__ wfold,
                                               const float* __restrict__ cvec, float* __restrict__ h, int nrow){
  __shared__ float ws[900];
  __shared__ float cl[30];
  int t = threadIdx.x;
  for (int i=t;i<900;i+=256) ws[i] = wfold[i];
  if (t < 30) cl[t] = cvec[t];
  __syncthreads();
  int id = blockIdx.x*256 + t;
  if (id >= nrow*30) return;
  int v = id/30, j = id - v*30;
  const float* xr = x + v*30;
  float acc = cl[j];
  #pragma unroll
  for (int k=0;k<30;k++) acc += xr[k]*ws[k*30+j];
  h[id] = acc;
}

// BN finalize (standalone, stage-2)
template<int FOLD>
__global__ __launch_bounds__(256) void k_bnw(float* __restrict__ gS, float* __restrict__ gQ, float n,
    const float* __restrict__ g, const float* __restrict__ be,
    const float* __restrict__ wnext, float* __restrict__ sfc,
    float* __restrict__ wfold, float* __restrict__ cvec){
  __shared__ float s_l[30], c_l[30];
  int t = threadIdx.x;
  if (t < 30){
    float s=0.f, q=0.f;
    for (int u=0;u<64;u++){ s += gS[u*30+t]; q += gQ[u*30+t]; }
    float m = s/n;
    float var = q/n - m*m;
    float sc = g[t]*(1.0f/sqrtf(var+1e-5f));
    float c0 = be[t] - sc*m;
    s_l[t]=sc; c_l[t]=c0;
    sfc[t]=sc; sfc[32+t]=c0;
    for (int u=0;u<64;u++){ gS[u*30+t]=0.f; gQ[u*30+t]=0.f; }
  }
  __syncthreads();
  if (FOLD){
    for (int i=t;i<900;i+=256) wfold[i] = s_l[i/30]*wnext[i];
    if (t<30){
      float c=0.f;
      for (int k=0;k<30;k++) c += c_l[k]*wnext[k*30+t];
      cvec[t]=c;
    }
  }
}

// ---------------- belief propagation (col-vectorized, XCD-resident) -------
__device__ __forceinline__ void bp_decode2(int b, int& graph, int& run, int& jj){
  int xcd = b & 7, i = b >> 3;
  int gs = i >> 7, j = i & 127;
  if      (j <   4){ run=0; jj=j;    }
  else if (j <   8){ run=1; jj=j-4;  }
  else if (j <  16){ run=2; jj=j-8;  }
  else if (j <  32){ run=3; jj=j-16; }
  else if (j <  64){ run=4; jj=j-32; }
  else             { run=5; jj=j-64; }
  graph = gs*8 + xcd;
}

template<int TPR>
__device__ __forceinline__ void bfly_max4(float& m0, float& m1, float& m2, float& m3){
  if constexpr (TPR > 1){
    #pragma unroll
    for (int lm = TPR>>1; lm; lm >>= 1){
      float p0=__shfl_xor(m0,lm,64), p1=__shfl_xor(m1,lm,64);
      float p2=__shfl_xor(m2,lm,64), p3=__shfl_xor(m3,lm,64);
      m0=fmaxf(m0,p0); m1=fmaxf(m1,p1); m2=fmaxf(m2,p2); m3=fmaxf(m3,p3);
    }
  }
  { float t0=fmaxf(m0,m2), t1=fmaxf(m1,m3), t2=fmaxf(m2,m0), t3=fmaxf(m3,m1);
    m0=t0; m1=t1; m2=t2; m3=t3; }
  { float t0=fmaxf(m0,m1), t1=fmaxf(m1,m0), t2=fmaxf(m2,m3), t3=fmaxf(m3,m2);
    m0=t0; m1=t1; m2=t2; m3=t3; }
}

template<int TPR>
__device__ __forceinline__ void bfly_sum4(float& s0, float& s1, float& s2, float& s3){
  if constexpr (TPR > 1){
    #pragma unroll
    for (int lm = TPR>>1; lm; lm >>= 1){
      float p0=__shfl_xor(s0,lm,64), p1=__shfl_xor(s1,lm,64);
      float p2=__shfl_xor(s2,lm,64), p3=__shfl_xor(s3,lm,64);
      s0 += p0; s1 += p1; s2 += p2; s3 += p3;
    }
  }
  { float t0=s0+s2, t1=s1+s3, t2=s2+s0, t3=s3+s1;
    s0=t0; s1=t1; s2=t2; s3=t3; }
  { float t0=s0+s1, t1=s1+s0, t2=s2+s3, t3=s3+s2;
    s0=t0; s1=t1; s2=t2; s3=t3; }
}

template<int Q, int CO, int TPR, int L2T>
__device__ __forceinline__ void bp_first_elem2(int graph, int jj, float* __restrict__ psi_pk,
                                               float* __restrict__ lg, float eb,
                                               uint32_t k0, uint32_t k1){
  int idx = jj*256 + (int)threadIdx.x;
  if constexpr (Q == 2){
    int row = graph*1024 + idx;
    float z[2];
    #pragma unroll
    for (int r=0;r<2;r++){
      uint32_t b0,b1;
      tf2x32(k0,k1, 0u, (uint32_t)(row*2 + r), b0,b1);
      uint32_t bits = b0 ^ b1;
      float f = __uint_as_float((bits>>9) | 0x3F800000u) - 1.0f;
      const float lo = __uint_as_float(0xBF7FFFFFu);
      float u = fmaxf(lo, f*2.0f + lo);
      z[r] = __uint_as_float(0x3FB504F3u) * erfinv32(u);
    }
    float m0=fmaxf(z[0],z[1]), m1=fmaxf(z[1],z[0]);
    float e0=expf(z[0]-m0), e1=expf(z[1]-m1);
    float s0=e0+e1, s1=e1+e0;
    float p0=e0/s0, p1=e1/s1;
    ((float2*)(psi_pk + (size_t)NN*CO))[row] = make_float2(p0,p1);
    ((float2*)(lg     + (size_t)NN*CO))[row] = make_float2(log1pf(eb*p0), log1pf(eb*p1));
  } else {
    int rw = idx >> L2T, ct = idx & (TPR-1);
    int row = graph*1024 + rw;
    float z[4];
    #pragma unroll
    for (int r=0;r<4;r++){
      uint32_t b0,b1;
      tf2x32(k0,k1, 0u, (uint32_t)(row*Q + 4*ct + r), b0,b1);
      uint32_t bits = b0 ^ b1;
      float f = __uint_as_float((bits>>9) | 0x3F800000u) - 1.0f;
      const float lo = __uint_as_float(0xBF7FFFFFu);
      float u = fmaxf(lo, f*2.0f + lo);
      z[r] = __uint_as_float(0x3FB504F3u) * erfinv32(u);
    }
    float m0=z[0],m1=z[1],m2=z[2],m3=z[3];
    bfly_max4<TPR>(m0,m1,m2,m3);
    float e0=expf(z[0]-m0), e1=expf(z[1]-m1), e2=expf(z[2]-m2), e3=expf(z[3]-m3);
    float s0=e0,s1=e1,s2=e2,s3=e3;
    bfly_sum4<TPR>(s0,s1,s2,s3);
    float p0=e0/s0, p1=e1/s1, p2=e2/s2, p3=e3/s3;
    ((float4*)(psi_pk + (size_t)NN*CO))[(size_t)row*TPR + ct] = make_float4(p0,p1,p2,p3);
    ((float4*)(lg     + (size_t)NN*CO))[(size_t)row*TPR + ct] =
        make_float4(log1pf(eb*p0), log1pf(eb*p1), log1pf(eb*p2), log1pf(eb*p3));
  }
}

// bp_first + aux mm30<3> (blocks >= 8192)
__global__ __launch_bounds__(256, 8) void k_bp_first(float* __restrict__ psi_pk, float* __restrict__ lg,
                                                  const float* __restrict__ betas,
                                                  const float* __restrict__ xin,
                                                  const float* __restrict__ w11,
                                                  float* __restrict__ hbuf){
  if (blockIdx.x >= 8192){
    __shared__ float ws[90];
    int t = threadIdx.x;
    for (int i=t;i<90;i+=256) ws[i] = w11[i];
    __syncthreads();
    int id = ((int)blockIdx.x - 8192)*256 + t;
    if (id >= NN*30) return;
    int v = id/30, j = id - v*30;
    const float* xr = xin + v*3;
    float acc = 0.f;
    #pragma unroll
    for (int k=0;k<3;k++) acc += xr[k]*ws[k*30+j];
    hbuf[id] = acc;
    return;
  }
  int graph, run, jj;
  bp_decode2(blockIdx.x, graph, run, jj);
  uint32_t k0, k1;
  tf2x32(0u, 42u, 0u, (uint32_t)run, k0, k1);
  float eb = expm1f(betas[run]);
  switch(run){
    case 0: bp_first_elem2< 2, 0, 1,0>(graph, jj, psi_pk, lg, eb, k0, k1); break;
    case 1: bp_first_elem2< 4, 2, 1,0>(graph, jj, psi_pk, lg, eb, k0, k1); break;
    case 2: bp_first_elem2< 8, 6, 2,1>(graph, jj, psi_pk, lg, eb, k0, k1); break;
    case 3: bp_first_elem2<16,14, 4,2>(graph, jj, psi_pk, lg, eb, k0, k1); break;
    case 4: bp_first_elem2<32,30, 8,3>(graph, jj, psi_pk, lg, eb, k0, k1); break;
    default:bp_first_elem2<64,62,16,4>(graph, jj, psi_pk, lg, eb, k0, k1); break;
  }
}

// fin==1: write psi TRANSPOSED (catT [126][NN] layout) into nxt
template<int Q, int CO, int TPR, int L2T>
__device__ __forceinline__ void bp_step_elem2(int graph, int run, int jj,
    const float* __restrict__ lcur, float* __restrict__ nxt, float* __restrict__ lnxt,
    const int* __restrict__ rp, const int* __restrict__ col,
    const float* __restrict__ field, float eb, int fin){
  int idx = jj*256 + (int)threadIdx.x;
  if constexpr (Q == 2){
    int row = graph*1024 + idx;
    const float2* B2 = (const float2*)(lcur + (size_t)NN*CO);
    // hoist field load above the gather loop (read-only, same value)
    float f0 = field[run*64 + 0];
    float f1 = field[run*64 + 1];
    float a0=0.f, a1=0.f;
    int a = rp[row], b2 = rp[row+1];
    for (; a+8<=b2; a+=8){
      int s0=col[a],s1=col[a+1],s2=col[a+2],s3=col[a+3];
      int s4=col[a+4],s5=col[a+5],s6=col[a+6],s7=col[a+7];
      float2 u0=B2[s0], u1=B2[s1], u2=B2[s2], u3=B2[s3];
      float2 u4=B2[s4], u5=B2[s5], u6=B2[s6], u7=B2[s7];
      a0+=u0.x; a1+=u0.y; a0+=u1.x; a1+=u1.y;
      a0+=u2.x; a1+=u2.y; a0+=u3.x; a1+=u3.y;
      a0+=u4.x; a1+=u4.y; a0+=u5.x; a1+=u5.y;
      a0+=u6.x; a1+=u6.y; a0+=u7.x; a1+=u7.y;
    }
    for (; a+4<=b2; a+=4){
      int s0=col[a],s1=col[a+1],s2=col[a+2],s3=col[a+3];
      float2 u0=B2[s0], u1=B2[s1], u2=B2[s2], u3=B2[s3];
      a0+=u0.x; a1+=u0.y; a0+=u1.x; a1+=u1.y;
      a0+=u2.x; a1+=u2.y; a0+=u3.x; a1+=u3.y;
    }
    for (; a<b2; ++a){ float2 u=B2[col[a]]; a0+=u.x; a1+=u.y; }
    float v0 = a0 - f0;
    float v1 = a1 - f1;
    float m0=fmaxf(v0,v1), m1=fmaxf(v1,v0);
    float e0=expf(v0-m0), e1=expf(v1-m1);
    float s0=e0+e1, s1=e1+e0;
    float p0=e0/s0, p1=e1/s1;
    if (fin){
      nxt[(size_t)(CO+0)*NN + row] = p0;
      nxt[(size_t)(CO+1)*NN + row] = p1;
    } else {
      ((float2*)(nxt  + (size_t)NN*CO))[row] = make_float2(p0,p1);
      ((float2*)(lnxt + (size_t)NN*CO))[row] = make_float2(log1pf(eb*p0), log1pf(eb*p1));
    }
  } else {
    int rw = idx >> L2T, ct = idx & (TPR-1);
    int row = graph*1024 + rw;
    const float4* B4 = (const float4*)(lcur + (size_t)NN*CO);
    const float4 fld = *(const float4*)(field + run*64 + 4*ct);   // hoisted
    float a0=0.f,a1=0.f,a2=0.f,a3=0.f;
    int a = rp[row], b2 = rp[row+1];
    for (; a+8<=b2; a+=8){
      int s0=col[a],s1=col[a+1],s2=col[a+2],s3=col[a+3];
      int s4=col[a+4],s5=col[a+5],s6=col[a+6],s7=col[a+7];
      float4 u0=B4[(size_t)s0*TPR+ct], u1=B4[(size_t)s1*TPR+ct];
      float4 u2=B4[(size_t)s2*TPR+ct], u3=B4[(size_t)s3*TPR+ct];
      float4 u4=B4[(size_t)s4*TPR+ct], u5=B4[(size_t)s5*TPR+ct];
      float4 u6=B4[(size_t)s6*TPR+ct], u7=B4[(size_t)s7*TPR+ct];
      a0+=u0.x; a1+=u0.y; a2+=u0.z; a3+=u0.w;
      a0+=u1.x; a1+=u1.y; a2+=u1.z; a3+=u1.w;
      a0+=u2.x; a1+=u2.y; a2+=u2.z; a3+=u2.w;
      a0+=u3.x; a1+=u3.y; a2+=u3.z; a3+=u3.w;
      a0+=u4.x; a1+=u4.y; a2+=u4.z; a3+=u4.w;
      a0+=u5.x; a1+=u5.y; a2+=u5.z; a3+=u5.w;
      a0+=u6.x; a1+=u6.y; a2+=u6.z; a3+=u6.w;
      a0+=u7.x; a1+=u7.y; a2+=u7.z; a3+=u7.w;
    }
    for (; a+4<=b2; a+=4){
      int s0=col[a],s1=col[a+1],s2=col[a+2],s3=col[a+3];
      float4 u0=B4[(size_t)s0*TPR+ct], u1=B4[(size_t)s1*TPR+ct];
      float4 u2=B4[(size_t)s2*TPR+ct], u3=B4[(size_t)s3*TPR+ct];
      a0+=u0.x; a1+=u0.y; a2+=u0.z; a3+=u0.w;
      a0+=u1.x; a1+=u1.y; a2+=u1.z; a3+=u1.w;
      a0+=u2.x; a1+=u2.y; a2+=u2.z; a3+=u2.w;
      a0+=u3.x; a1+=u3.y; a2+=u3.z; a3+=u3.w;
    }
    for (; a<b2; ++a){
      float4 u = B4[(size_t)col[a]*TPR+ct];
      a0+=u.x; a1+=u.y; a2+=u.z; a3+=u.w;
    }
    float v0 = a0 - fld.x, v1 = a1 - fld.y, v2 = a2 - fld.z, v3 = a3 - fld.w;
    float m0=v0,m1=v1,m2=v2,m3=v3;
    bfly_max4<TPR>(m0,m1,m2,m3);
    float e0=expf(v0-m0), e1=expf(v1-m1), e2=expf(v2-m2), e3=expf(v3-m3);
    float s0=e0,s1=e1,s2=e2,s3=e3;
    bfly_sum4<TPR>(s0,s1,s2,s3);
    float p0=e0/s0, p1=e1/s1, p2=e2/s2, p3=e3/s3;
    if (fin){
      int kb = CO + 4*ct;
      nxt[(size_t)(kb+0)*NN + row] = p0;
      nxt[(size_t)(kb+1)*NN + row] = p1;
      nxt[(size_t)(kb+2)*NN + row] = p2;
      nxt[(size_t)(kb+3)*NN + row] = p3;
    } else {
      ((float4*)(nxt  + (size_t)NN*CO))[(size_t)row*TPR+ct] = make_float4(p0,p1,p2,p3);
      ((float4*)(lnxt + (size_t)NN*CO))[(size_t)row*TPR+ct] =
          make_float4(log1pf(eb*p0), log1pf(eb*p1), log1pf(eb*p2), log1pf(eb*p3));
    }
  }
}

// pure bp_step (no aux)
__global__ __launch_bounds__(256, 8) void k_bp_step(
    float* __restrict__ nxt, const float* __restrict__ lcur, float* __restrict__ lnxt,
    const int* __restrict__ rp, const int* __restrict__ col,
    const float* __restrict__ field, const float* __restrict__ betas, int fin){
  int graph, run, jj;
  bp_decode2(blockIdx.x, graph, run, jj);
  float eb = expm1f(betas[run]);
  switch(run){
    case 0: bp_step_elem2< 2, 0, 1,0>(graph, run, jj, lcur, nxt, lnxt, rp, col, field, eb, fin); break;
    case 1: bp_step_elem2< 4, 2, 1,0>(graph, run, jj, lcur, nxt, lnxt, rp, col, field, eb, fin); break;
    case 2: bp_step_elem2< 8, 6, 2,1>(graph, run, jj, lcur, nxt, lnxt, rp, col, field, eb, fin); break;
    case 3: bp_step_elem2<16,14, 4,2>(graph, run, jj, lcur, nxt, lnxt, rp, col, field, eb, fin); break;
    case 4: bp_step_elem2<32,30, 8,3>(graph, run, jj, lcur, nxt, lnxt, rp, col, field, eb, fin); break;
    default:bp_step_elem2<64,62,16,4>(graph, run, jj, lcur, nxt, lnxt, rp, col, field, eb, fin); break;
  }
}

// colsum (blocks 0..383, 4 chunks/block, per-chunk sums bit-identical)
// + aux blocks >= 384: 1=gcn_agg, 2=mm30c, 3=pool(stage-1)
__global__ __launch_bounds__(256, 8) void k_colsum(const float* __restrict__ psi_pk,
    float* __restrict__ part, const int* __restrict__ rp, const int* __restrict__ col,
    int auxType, const float* __restrict__ aA, const float* __restrict__ aB,
    const float* __restrict__ aC, float* __restrict__ aO,
    float* __restrict__ agS, float* __restrict__ agQ,
    const float* __restrict__ adinv, const float* __restrict__ asfc,
    float* __restrict__ aconv){
  __shared__ float smem[960];
  int t = threadIdx.x;
  if (blockIdx.x < 384){
    int grp = t >> 6, c = t & 63;
    int b = blockIdx.x*4 + grp;            // virtual chunk-block id (== R15 b)
    int xcd = b & 7, i = b >> 3;
    int gs = i/24, rem = i - gs*24;
    int run = rem >> 2, cg = rem & 3;
    int graph = gs*8 + xcd;
    int chunk = graph*4 + cg;
    int q = cQS[run];
    int co = (run==0)?0:(run==1)?2:(run==2)?6:(run==3)?14:(run==4)?30:62;
    if (q >= 4){
      int nq = q >> 2;
      if (c >= nq) return;
      const float4* p4 = (const float4*)(psi_pk + (size_t)NN*co + (size_t)chunk*256*q) + c;
      float s0=0.f,s1=0.f,s2=0.f,s3=0.f;
      #pragma unroll 8
      for (int r=0;r<256;r++){
        float4 u = p4[(size_t)r*nq];
        s0+=u.x; s1+=u.y; s2+=u.z; s3+=u.w;
      }
      float* o = part + (run*256 + chunk)*64 + 4*c;
      o[0]=s0; o[1]=s1; o[2]=s2; o[3]=s3;
    } else {
      if (c >= q) return;
      float s = 0.f;
      const float* p = psi_pk + (size_t)NN*co + (size_t)chunk*256*q + c;
      #pragma unroll 8
      for (int r=0;r<256;r++) s += p[r*q];
      part[(run*256 + chunk)*64 + c] = s;
    }
    return;
  }
  int ab = (int)blockIdx.x - 384;
  if (auxType == 1){
    float* binS = smem; float* binQ = smem + 32;
    if (t < 30){ binS[t]=0.f; binQ[t]=0.f; }
    __syncthreads();
    int xcd = ab & 7, i = ab >> 3;
    int gs = i/60, j = i - gs*60;
    int graph = gs*8 + xcd;
    int idwg = j*256 + t;
    int rw = idwg/15, pr = idwg - rw*15;
    int v = graph*1024 + rw;
    float dv = adinv[v];
    float accx = 0.f, accy = 0.f;
    int a = rp[v], e = rp[v+1];
    for (; a+4<=e; a+=4){
      int s0=col[a], s1=col[a+1], s2=col[a+2], s3=col[a+3];
      float d0=adinv[s0], d1=adinv[s1], d2=adinv[s2], d3=adinv[s3];
      float2 h0=*(const float2*)(aA+s0*30+2*pr), h1=*(const float2*)(aA+s1*30+2*pr);
      float2 h2=*(const float2*)(aA+s2*30+2*pr), h3=*(const float2*)(aA+s3*30+2*pr);
      accx += h0.x*(d0*dv); accy += h0.y*(d0*dv);
      accx += h1.x*(d1*dv); accy += h1.y*(d1*dv);
      accx += h2.x*(d2*dv); accy += h2.y*(d2*dv);
      accx += h3.x*(d3*dv); accy += h3.y*(d3*dv);
    }
    for (; a<e; ++a){
      int s = col[a];
      float w = adinv[s]*dv;
      float2 hv = *(const float2*)(aA+s*30+2*pr);
      accx += hv.x*w; accy += hv.y*w;
    }
    float2 hs = *(const float2*)(aA + v*30 + 2*pr);
    float w2 = dv*dv;
    accx += hs.x*w2; accy += hs.y*w2;   // self loop last (JAX concat order)
    float2 o; o.x = accx + aB[2*pr]; o.y = accy + aB[2*pr+1];
    *(float2*)(aO + v*30 + 2*pr) = o;
    atomicAdd(&binS[2*pr],   o.x); atomicAdd(&binQ[2*pr],   o.x*o.x);
    atomicAdd(&binS[2*pr+1], o.y); atomicAdd(&binQ[2*pr+1], o.y*o.y);
    __syncthreads();
    if (t < 30){
      int slot = (ab & 63)*30 + t;
      atomicAdd(&agS[slot], binS[t]);
      atomicAdd(&agQ[slot], binQ[t]);
    }
  } else if (auxType == 2){
    float* ws = smem; float* cl = smem + 904;
    for (int i=t;i<900;i+=256) ws[i] = aB[i];
    if (t < 30) cl[t] = aC[t];
    __syncthreads();
    int id = ab*256 + t;
    if (id < NN*30){
      int v = id/30, j = id - v*30;
      const float* xr = aA + v*30;
      float acc = cl[j];
      #pragma unroll
      for (int k=0;k<30;k++) acc += xr[k]*ws[k*30+j];
      aO[id] = acc;
    }
  } else if (auxType == 3){
    int b2 = ab & 63, a = ab >> 6;
    const float* X = (a==0)? aA : ((a==1)? aB : aC);
    const float* sf = asfc + a*64;
    float acc[30];
    #pragma unroll
    for (int f=0;f<30;f++) acc[f] = -FLT_MAX;
    for (int r=t; r<1024; r+=256){
      const float* xr = X + (size_t)(b2*1024 + r)*30;
      #pragma unroll
      for (int f=0;f<30;f++) acc[f] = fmaxf(acc[f], sf[f]*xr[f] + sf[32+f]);
    }
    #pragma unroll
    for (int off=32; off; off>>=1){
      #pragma unroll
      for (int f=0;f<30;f++) acc[f] = fmaxf(acc[f], __shfl_xor(acc[f], off, 64));
    }
    int w = t>>6, lane = t&63;
    if (lane == 0){
      #pragma unroll
      for (int f=0;f<30;f++) smem[w*30+f] = acc[f];
    }
    __syncthreads();
    if (t < 30)
      aconv[b2*180 + a*30 + t] =
        fmaxf(fmaxf(smem[t], smem[30+t]), fmaxf(smem[60+t], smem[90+t]));
  }
}

// field (block 0) + optional bnw aux (block 1). 2 blocks x 384 thr.
__global__ void k_field(const float* __restrict__ part, const float* __restrict__ betas,
                        float* __restrict__ field,
                        int auxFold, float* __restrict__ gS, float* __restrict__ gQ, float n,
                        const float* __restrict__ g, const float* __restrict__ be,
                        const float* __restrict__ wnext, float* __restrict__ sfc,
                        float* __restrict__ wfold, float* __restrict__ cvec){
  if (blockIdx.x == 1){
    if (auxFold < 0) return;
    __shared__ float s_l[30], c_l[30];
    int t = threadIdx.x;
    if (t < 30){
      float s=0.f, q=0.f;
      for (int u=0;u<64;u++){ s += gS[u*30+t]; q += gQ[u*30+t]; }
      float m = s/n;
      float var = q/n - m*m;
      float sc = g[t]*(1.0f/sqrtf(var+1e-5f));
      float c0 = be[t] - sc*m;
      s_l[t]=sc; c_l[t]=c0;
      sfc[t]=sc; sfc[32+t]=c0;
      for (int u=0;u<64;u++){ gS[u*30+t]=0.f; gQ[u*30+t]=0.f; }
    }
    __syncthreads();
    if (auxFold == 1){
      for (int i=t;i<900;i+=384) wfold[i] = s_l[i/30]*wnext[i];
      if (t<30){
        float c=0.f;
        for (int k=0;k<30;k++) c += c_l[k]*wnext[k*30+t];
        cvec[t]=c;
      }
    }
    return;
  }
  int id = threadIdx.x;
  int run = id >> 6, c = id & 63;
  if (c >= cQS[run]) return;
  float s = 0.f;
  for (int b=0;b<256;b++) s += part[(run*256 + b)*64 + c];
  float beta = betas[run];
  field[id] = s * (3.8f*beta/65536.0f);
}

// ---------------- diff-pool ----------------
__global__ __launch_bounds__(256) void k_s1t(const float* __restrict__ catT, const float* __restrict__ pw,
                                             const float* __restrict__ pb, float* __restrict__ s1){
  __shared__ float wl[12600];
  __shared__ float pbl[100];
  __shared__ float redM[2][128];
  __shared__ float redS[2][128];
  int t = threadIdx.x;
  for (int i=t;i<12600;i+=256) wl[i] = pw[i];
  if (t < 100) pbl[t] = pb[t];
  int w = t>>6, lane = t&63;
  int rh = w&1, chh = w>>1;
  int ch = chh*50;
  int row = blockIdx.x*128 + rh*64 + lane;
  __syncthreads();
  float acc[50];
  #pragma unroll
  for (int j=0;j<50;j++) acc[j] = pbl[ch+j];
  for (int k=0;k<126;k++){
    float xv = catT[(size_t)k*65536 + row];
    const float* wr = &wl[k*100 + ch];
    #pragma unroll
    for (int j=0;j<50;j+=2){
      float2 wv = *(const float2*)&wr[j];
      acc[j]   += xv*wv.x;
      acc[j+1] += xv*wv.y;
    }
  }
  float m = acc[0];
  #pragma unroll
  for (int j=1;j<50;j++) m = fmaxf(m, acc[j]);
  redM[chh][rh*64 + lane] = m;
  __syncthreads();
  float mm = fmaxf(redM[0][rh*64 + lane], redM[1][rh*64 + lane]);
  float s = 0.f;
  #pragma unroll
  for (int j=0;j<50;j++){ acc[j] = expf(acc[j]-mm); s += acc[j]; }
  redS[chh][rh*64 + lane] = s;
  __syncthreads();
  float tot = redS[0][rh*64 + lane] + redS[1][rh*64 + lane];
  float* o = s1 + (size_t)row*100 + ch;
  #pragma unroll
  for (int j=0;j<50;j+=2){
    float2 ov; ov.x = acc[j]/tot; ov.y = acc[j+1]/tot;
    *(float2*)&o[j] = ov;
  }
}

__global__ __launch_bounds__(256) void k_T(const float* __restrict__ s1, const int* __restrict__ rp,
                                           const int* __restrict__ col, float* __restrict__ T){
  int b = blockIdx.x;
  int xcd = b & 7, i = b >> 3;
  int gs = i/100, j = i - gs*100;
  int graph = gs*8 + xcd;
  int idwg = j*256 + threadIdx.x;
  int rw = idwg/25, quad = idwg - rw*25;
  int v = graph*1024 + rw;
  float a0=0.f,a1=0.f,a2=0.f,a3=0.f;
  const float4* S4 = (const float4*)s1;
  int a = rp[v], e = rp[v+1];
  for (; a+8<=e; a+=8){
    int s0=col[a], s1_=col[a+1], s2=col[a+2], s3=col[a+3];
    int s4=col[a+4], s5=col[a+5], s6=col[a+6], s7=col[a+7];
    float4 u0=S4[(size_t)s0*25+quad], u1=S4[(size_t)s1_*25+quad];
    float4 u2=S4[(size_t)s2*25+quad], u3=S4[(size_t)s3*25+quad];
    float4 u4=S4[(size_t)s4*25+quad], u5=S4[(size_t)s5*25+quad];
    float4 u6=S4[(size_t)s6*25+quad], u7=S4[(size_t)s7*25+quad];
    a0+=u0.x; a1+=u0.y; a2+=u0.z; a3+=u0.w;
    a0+=u1.x; a1+=u1.y; a2+=u1.z; a3+=u1.w;
    a0+=u2.x; a1+=u2.y; a2+=u2.z; a3+=u2.w;
    a0+=u3.x; a1+=u3.y; a2+=u3.z; a3+=u3.w;
    a0+=u4.x; a1+=u4.y; a2+=u4.z; a3+=u4.w;
    a0+=u5.x; a1+=u5.y; a2+=u5.z; a3+=u5.w;
    a0+=u6.x; a1+=u6.y; a2+=u6.z; a3+=u6.w;
    a0+=u7.x; a1+=u7.y; a2+=u7.z; a3+=u7.w;
  }
  for (; a+4<=e; a+=4){
    int s0=col[a], s1_=col[a+1], s2=col[a+2], s3=col[a+3];
    float4 u0=S4[(size_t)s0*25+quad], u1=S4[(size_t)s1_*25+quad];
    float4 u2=S4[(size_t)s2*25+quad], u3=S4[(size_t)s3*25+quad];
    a0+=u0.x; a1+=u0.y; a2+=u0.z; a3+=u0.w;
    a0+=u1.x; a1+=u1.y; a2+=u1.z; a3+=u1.w;
    a0+=u2.x; a1+=u2.y; a2+=u2.z; a3+=u2.w;
    a0+=u3.x; a1+=u3.y; a2+=u3.z; a3+=u3.w;
  }
  for (; a<e; ++a){
    float4 u = S4[(size_t)col[a]*25+quad];
    a0+=u.x; a1+=u.y; a2+=u.z; a3+=u.w;
  }
  ((float4*)T)[(size_t)v*25 + quad] = make_float4(a0,a1,a2,a3);
}

// merged split-K: blocks 0..255 = p1adj, 256..511 = p1x (BN affine on fill)
__global__ __launch_bounds__(512) void k_p1ax(const float* __restrict__ s1, const float* __restrict__ T,
                                              const float* __restrict__ y3, const float* __restrict__ sfc,
                                              float* __restrict__ partA, float* __restrict__ partX){
  __shared__ float sS[6400];
  __shared__ float sT[6400];
  int t = threadIdx.x;
  if (blockIdx.x < 256){
    int blk = blockIdx.x;
    int b = blk >> 2, qtr = blk & 3;
    int tk = t/20, tl = t - tk*20;
    bool act = t < 500;
    int k0 = tk*4, l0 = tl*5;
    float acc[4][5];
    #pragma unroll
    for (int i=0;i<4;i++)
      #pragma unroll
      for (int j=0;j<5;j++) acc[i][j] = 0.f;
    const float* s1b = s1 + (size_t)b*102400;
    const float* Tb  = T  + (size_t)b*102400;
    for (int c=qtr*4; c<qtr*4+4; c++){
      for (int i=t;i<6400;i+=512){ sS[i] = s1b[c*6400+i]; sT[i] = Tb[c*6400+i]; }
      __syncthreads();
      if (act){
        #pragma unroll 2
        for (int n=0;n<64;n++){
          const float* sr = &sS[n*100 + k0];
          const float* tr = &sT[n*100 + l0];
          float s0=sr[0], s1v=sr[1], s2=sr[2], s3=sr[3];
          float t0=tr[0], t1=tr[1], t2=tr[2], t3=tr[3], t4=tr[4];
          acc[0][0]+=s0*t0; acc[0][1]+=s0*t1; acc[0][2]+=s0*t2; acc[0][3]+=s0*t3; acc[0][4]+=s0*t4;
          acc[1][0]+=s1v*t0; acc[1][1]+=s1v*t1; acc[1][2]+=s1v*t2; acc[1][3]+=s1v*t3; acc[1][4]+=s1v*t4;
          acc[2][0]+=s2*t0; acc[2][1]+=s2*t1; acc[2][2]+=s2*t2; acc[2][3]+=s2*t3; acc[2][4]+=s2*t4;
          acc[3][0]+=s3*t0; acc[3][1]+=s3*t1; acc[3][2]+=s3*t2; acc[3][3]+=s3*t3; acc[3][4]+=s3*t4;
        }
      }
      __syncthreads();
    }
    if (act){
      float* pp = partA + (size_t)qtr*640000 + (size_t)b*10000;
      #pragma unroll
      for (int i=0;i<4;i++){
        float* o = pp + (k0+i)*100 + l0;
        #pragma unroll
        for (int j=0;j<5;j++) o[j] = acc[i][j];
      }
    }
  } else {
    int blk = blockIdx.x - 256;
    int b = blk >> 2, qtr = blk & 3;
    float* sX = sT;
    int tk = t/10, tl = t - tk*10;
    bool act = t < 250;
    int k0 = tk*4, d0 = tl*3;
    float acc[4][3];
    #pragma unroll
    for (int i=0;i<4;i++)
      #pragma unroll
      for (int j=0;j<3;j++) acc[i][j] = 0.f;
    const float* s1b = s1 + (size_t)b*102400;
    const float* xb  = y3 + (size_t)b*30720;
    for (int c=qtr*4; c<qtr*4+4; c++){
      for (int i=t;i<6400;i+=512) sS[i] = s1b[c*6400+i];
      for (int i=t;i<1920;i+=512){
        int f = i % 30;
        sX[i] = sfc[f]*xb[c*1920+i] + sfc[32+f];
      }
      __syncthreads();
      if (act){
        #pragma unroll 2
        for (int n=0;n<64;n++){
          const float* sr = &sS[n*100 + k0];
          const float* xr = &sX[n*30 + d0];
          float s0=sr[0], s1v=sr[1], s2=sr[2], s3=sr[3];
          float x0=xr[0], x1=xr[1], x2=xr[2];
          acc[0][0]+=s0*x0; acc[0][1]+=s0*x1; acc[0][2]+=s0*x2;
          acc[1][0]+=s1v*x0; acc[1][1]+=s1v*x1; acc[1][2]+=s1v*x2;
          acc[2][0]+=s2*x0; acc[2][1]+=s2*x1; acc[2][2]+=s2*x2;
          acc[3][0]+=s3*x0; acc[3][1]+=s3*x1; acc[3][2]+=s3*x2;
        }
      }
      __syncthreads();
    }
    if (act){
      float* pp = partX + (size_t)qtr*192000 + (size_t)b*3000;
      #pragma unroll
      for (int i=0;i<4;i++){
        float* o = pp + (k0+i)*30 + d0;
        #pragma unroll
        for (int j=0;j<3;j++) o[j] = acc[i][j];
      }
    }
  }
}

// blocks 0..63: reduce padj parts + normalize -> An; 64..813: px reduce
__global__ __launch_bounds__(256) void k_anpx(const float* __restrict__ pA, const float* __restrict__ pX,
                                              float* __restrict__ An, float* __restrict__ px){
  if (blockIdx.x < 64){
    __shared__ float pj[10000];
    __shared__ float dv[100];
    int b = blockIdx.x, t = threadIdx.x;
    size_t base = (size_t)b*10000;
    for (int i=t;i<10000;i+=256)
      pj[i] = pA[base+i] + pA[640000+base+i] + pA[1280000+base+i] + pA[1920000+base+i];
    __syncthreads();
    if (t < 100){
      const float* r = pj + t*100;
      float s = 0.f;
      for (int l=0;l<100;l++){
        float v = r[l];
        if (l==t) v += 1.0f;
        s += v;
      }
      dv[t] = 1.0f/sqrtf(s);
    }
    __syncthreads();
    for (int i=t;i<10000;i+=256){
      int k = i/100, l = i - k*100;
      float a = pj[i] + ((k==l)? 1.0f : 0.0f);
      An[base + i] = (dv[k]*a)*dv[l];
    }
  } else {
    int id = ((int)blockIdx.x - 64)*256 + threadIdx.x;
    if (id < 192000)
      px[id] = pX[id] + pX[192000+id] + pX[384000+id] + pX[576000+id];
  }
}

// ---------------- stage-2 dense GCN ----------------
__global__ __launch_bounds__(256) void k_y2(const float* __restrict__ An, const float* __restrict__ h,
    const float* __restrict__ bias, float* __restrict__ y,
    float* __restrict__ gS, float* __restrict__ gQ){
  __shared__ float binS[30], binQ[30];
  int t = threadIdx.x;
  if (t < 30){ binS[t]=0.f; binQ[t]=0.f; }
  __syncthreads();
  int id = blockIdx.x*256 + t;
  if (id < NBG*100*30){
    int d = id % 30;
    int bk = id / 30;
    int b = bk / 100;
    const float* Ar = An + bk*100;
    const float* hb = h + b*100*30;
    float acc = 0.f;
    for (int l=0;l<100;l++) acc += Ar[l]*hb[l*30+d];
    float val = acc + bias[d];
    y[id] = val;
    atomicAdd(&binS[d], val);
    atomicAdd(&binQ[d], val*val);
  }
  __syncthreads();
  if (t < 30){
    int slot = (blockIdx.x & 63)*30 + t;
    atomicAdd(&gS[slot], binS[t]);
    atomicAdd(&gQ[slot], binQ[t]);
  }
}

// stage-2 pool (big-LDS variant, separate launch)
__global__ __launch_bounds__(256) void k_pool2(const float* __restrict__ A,
    const float* __restrict__ Bv, const float* __restrict__ Cv,
    const float* __restrict__ sfcBase,
    int rows, float* __restrict__ conv, int coff){
  __shared__ float lds[256*31];
  int b = blockIdx.x, a = blockIdx.y, t = threadIdx.x;
  const float* X = (a==0)? A : ((a==1)? Bv : Cv);
  const float* sf = sfcBase + a*64;
  float acc[30];
  #pragma unroll
  for (int f=0;f<30;f++) acc[f] = -FLT_MAX;
  for (int r=t; r<rows; r+=256){
    const float* xr = X + (size_t)(b*rows + r)*30;
    #pragma unroll
    for (int f=0;f<30;f++) acc[f] = fmaxf(acc[f], sf[f]*xr[f] + sf[32+f]);
  }
  #pragma unroll
  for (int f=0;f<30;f++) lds[t*31+f] = acc[f];
  __syncthreads();
  for (int s=128;s>0;s>>=1){
    if (t<s){
      #pragma unroll
      for (int f=0;f<30;f++) lds[t*31+f] = fmaxf(lds[t*31+f], lds[(t+s)*31+f]);
    }
    __syncthreads();
  }
  if (t<30) conv[b*180 + coff + a*30 + t] = lds[t];
}

__global__ __launch_bounds__(64) void k_fc(const float* __restrict__ conv,
    const float* __restrict__ w1, const float* __restrict__ b1,
    const float* __restrict__ w2, const float* __restrict__ b2, float* __restrict__ out){
  __shared__ float row[180];
  __shared__ float hid[50];
  int b = blockIdx.x, t = threadIdx.x;
  for (int i=t;i<180;i+=64) row[i] = conv[b*180+i];
  __syncthreads();
  if (t < 50){
    float a = b1[t];
    for (int i=0;i<180;i++) a += row[i]*w1[i*50+t];
    hid[t] = fmaxf(a, 0.f);
  }
  __syncthreads();
  if (t < 6){
    float a = b2[t];
    for (int i=0;i<50;i++) a += hid[i]*w2[i*6+t];
    out[b*6+t] = a;
  }
  if (b==0 && t==63) out[NBG*6] = 0.0f;
}

// ---------------------------------------------------------------------------
extern "C" void kernel_launch(void* const* d_in, const int* in_sizes, int n_in,
                              void* d_out, int out_size, void* d_ws, size_t ws_size,
                              hipStream_t stream)
{
  (void)in_sizes; (void)n_in; (void)out_size; (void)ws_size;
  const float* x   = (const float*)d_in[0];
  const int*   src = (const int*)d_in[1];
  const int*   dst = src + NEDGE;
  const float* w11=(const float*)d_in[3],  *b11=(const float*)d_in[4],  *g11=(const float*)d_in[5],  *be11=(const float*)d_in[6];
  const float* w12=(const float*)d_in[7],  *b12=(const float*)d_in[8],  *g12=(const float*)d_in[9],  *be12=(const float*)d_in[10];
  const float* w13=(const float*)d_in[11], *b13=(const float*)d_in[12], *g13=(const float*)d_in[13], *be13=(const float*)d_in[14];
  const float* w21=(const float*)d_in[15], *b21=(const float*)d_in[16], *g21=(const float*)d_in[17], *be21=(const float*)d_in[18];
  const float* w22=(const float*)d_in[19], *b22=(const float*)d_in[20], *g22=(const float*)d_in[21], *be22=(const float*)d_in[22];
  const float* w23=(const float*)d_in[23], *b23=(const float*)d_in[24], *g23=(const float*)d_in[25], *be23=(const float*)d_in[26];
  const float* betas=(const float*)d_in[27];
  const float* poolw=(const float*)d_in[28], *poolb=(const float*)d_in[29];
  const float* fc1w=(const float*)d_in[30], *fc1b=(const float*)d_in[31];
  const float* fc2w=(const float*)d_in[32], *fc2b=(const float*)d_in[33];
  float* out = (float*)d_out;

  uint8_t* basep = (uint8_t*)d_ws;
  size_t off = 0;
  auto take = [&](size_t bytes)->void*{
    void* p = basep + off;
    off = (off + bytes + 255) & ~(size_t)255;
    return p;
  };
  int* degi    = (int*)take((size_t)NN*4);
  int* dego    = (int*)take((size_t)NN*4);
  int* cntA    = (int*)take((size_t)NN*4);
  int* cntB    = (int*)take((size_t)NN*4);
  float* gS    = (float*)take(64*30*4);     // BN stat slots (zeroed by memset)
  float* gQ    = (float*)take(64*30*4);
  int* rp_in   = (int*)take((size_t)(NN+1)*4);
  int* rp_out  = (int*)take((size_t)(NN+1)*4);
  int* bsum    = (int*)take(512*4);
  int* col_in  = (int*)take((size_t)NEDGE*4);
  int* col_out = (int*)take((size_t)NEDGE*4);
  float* dinv  = (float*)take((size_t)NN*4);
  float* hbuf  = (float*)take((size_t)NN*30*4);
  float* X1    = (float*)take((size_t)NN*30*4);   // pre-BN y1
  float* X2    = (float*)take((size_t)NN*30*4);   // pre-BN y2
  float* X3    = (float*)take((size_t)NN*30*4);   // pre-BN y3
  float* bufA  = (float*)take((size_t)NN*126*4);
  float* bufB  = (float*)take((size_t)NN*126*4);
  float* logA  = (float*)take((size_t)NN*126*4);
  float* logB  = (float*)take((size_t)NN*126*4);
  float* partCS= (float*)take((size_t)6*256*64*4);
  float* fieldv= (float*)take(384*4);
  float* sfcAll= (float*)take(6*64*4);
  float* wfold = (float*)take(960*4);
  float* cvec  = (float*)take(32*4);
  float* px    = (float*)take(192000*4);
  float* An    = (float*)take(640000*4);
  float* h2    = (float*)take(192000*4);
  float* X21   = (float*)take(192000*4);  // pre-BN
  float* X22   = (float*)take(192000*4);
  float* X23   = (float*)take(192000*4);
  float* conv  = (float*)take(64*180*4);

  // post-BP scratch reuse: catT -> logA (dead at it9); split-K -> logB
  float* catT     = logA;
  float* pAdjPart = logB;               // 4*640000 floats
  float* pPxPart  = logB + 2560000;     // 4*192000 floats

  // ---- CSR + stat zero (degi..gQ contiguous -> single memset) ----
  hipMemsetAsync(degi, 0, (size_t)4*NN*4 + 2*64*30*4, stream);
  k_count<<<2048,256,0,stream>>>(src,dst,degi,dego);
  k_scan1<<<dim3(256,2),256,0,stream>>>(degi, dego, rp_in, rp_out, bsum);
  k_scan2<<<2,256,0,stream>>>(bsum);
  k_scan3<<<dim3(256,2),256,0,stream>>>(rp_in, rp_out, bsum);
  k_fill<<<dim3(2048,2),256,0,stream>>>(src, dst, rp_in, rp_out, cntA, cntB, col_in, col_out);
  k_sortrow<<<dim3(256,2),256,0,stream>>>(rp_in, rp_out, col_in, col_out, src, dst, degi, dinv);

  // ---- BP; stage-1 rides colsum launches (aux), bp_first carries mm30<3> --
  k_bp_first<<<15872,256,0,stream>>>(bufA, logA, betas, x, w11, hbuf);

  float* cur = bufA;  float* nxt = bufB;
  float* lcur = logA; float* lnxt = logB;
  for (int it=0; it<10; ++it){
    // colsum + stage-1 aux
    int auxType = 0, auxN = 0;
    const float *aA=nullptr, *aB=nullptr, *aC=nullptr; float *aO=nullptr;
    if      (it==0){ auxType=1; auxN=3840; aA=hbuf; aB=b11; aO=X1; }
    else if (it==1){ auxType=2; auxN=7680; aA=X1; aB=wfold; aC=cvec; aO=hbuf; }
    else if (it==2){ auxType=1; auxN=3840; aA=hbuf; aB=b12; aO=X2; }
    else if (it==3){ auxType=2; auxN=7680; aA=X2; aB=wfold; aC=cvec; aO=hbuf; }
    else if (it==4){ auxType=1; auxN=3840; aA=hbuf; aB=b13; aO=X3; }
    else if (it==5){ auxType=3; auxN=192;  aA=X1; aB=X2; aC=X3; }
    k_colsum<<<384+auxN,256,0,stream>>>(cur, partCS, rp_in, col_in,
        auxType, aA, aB, aC, aO, gS, gQ, dinv, sfcAll, conv);
    // field + bnw fold (folds at it 0,2; scale-only at it 4)
    int fold = (it==0||it==2)? 1 : ((it==4)? 0 : -1);
    const float* gg = (it==0)? g11 : ((it==2)? g12 : g13);
    const float* bb = (it==0)? be11: ((it==2)? be12: be13);
    const float* wn = (it==0)? w12 : ((it==2)? w13 : nullptr);
    float* sfc = (it==0)? sfcAll : ((it==2)? sfcAll+64 : sfcAll+128);
    k_field<<<2,384,0,stream>>>(partCS, betas, fieldv, fold, gS, gQ, 65536.f,
                                gg, bb, wn, sfc, wfold, cvec);
    int fin = (it==9);
    float* stepNxt = fin ? catT : nxt;          // fin writes transposed psi
    k_bp_step<<<8192,256,0,stream>>>(stepNxt, lcur, lnxt, rp_in, col_in, fieldv, betas, fin);
    float* tp = cur;  cur = nxt;   nxt = tp;
    float* tl = lcur; lcur = lnxt; lnxt = tl;
  }
  // final psi now in catT ([126][NN] layout, == logA)

  // ---- diff-pool ----
  k_s1t<<<512,256,0,stream>>>(catT, poolw, poolb, bufB);
  k_T<<<6400,256,0,stream>>>(bufB, rp_out, col_out, bufA);
  k_p1ax<<<512,512,0,stream>>>(bufB, bufA, X3, sfcAll+128, pAdjPart, pPxPart);
  k_anpx<<<814,256,0,stream>>>(pAdjPart, pPxPart, An, px);

  // ---- stage 2: dense GCN x3 with folded BN ----
  k_mm30<30><<<750,256,0,stream>>>(px, w21, h2, NBG*100);
  k_y2<<<750,256,0,stream>>>(An, h2, b21, X21, gS, gQ);
  k_bnw<1><<<1,256,0,stream>>>(gS, gQ, 6400.f, g21, be21, w22, sfcAll+3*64, wfold, cvec);
  k_mm30c<<<750,256,0,stream>>>(X21, wfold, cvec, h2, NBG*100);
  k_y2<<<750,256,0,stream>>>(An, h2, b22, X22, gS, gQ);
  k_bnw<1><<<1,256,0,stream>>>(gS, gQ, 6400.f, g22, be22, w23, sfcAll+4*64, wfold, cvec);
  k_mm30c<<<750,256,0,stream>>>(X22, wfold, cvec, h2, NBG*100);
  k_y2<<<750,256,0,stream>>>(An, h2, b23, X23, gS, gQ);
  k_bnw<0><<<1,256,0,stream>>>(gS, gQ, 6400.f, g23, be23, nullptr, sfcAll+5*64, nullptr, nullptr);
  k_pool2<<<dim3(NBG,3),256,0,stream>>>(X21, X22, X23, sfcAll+3*64, 100, conv, 90);

  // ---- FC head ----
  k_fc<<<64,64,0,stream>>>(conv, fc1w, fc1b, fc2w, fc2b, out);
}